// Round 1
// baseline (2720.385 us; speedup 1.0000x reference)
//
#include <hip/hip_runtime.h>

#define NN 16384      // nodes
#define NE 65536      // edges
#define NT 81920      // edges + self loops
#define NG 512        // graphs
#define NH 10         // heads
#define FX 78         // features per head
#define HD 780        // hidden = NH*FX
#define SEQ 1000
#define EMB 100
#define NF 32
#define KS 8
#define CLEN 93

// ---------------------------------------------------------------------------
// Generic fp32 tiled GEMM: C[M,ldc] = A[M,K] @ B[K,N] (+bias) (+relu)
// ---------------------------------------------------------------------------
template<int BM,int BN,int BK,int TM,int TN,bool BIAS,bool RELU>
__launch_bounds__(256)
__global__ void gemm_f32(const float* __restrict__ A, const float* __restrict__ B,
                         const float* __restrict__ bias, float* __restrict__ C,
                         int M, int N, int K, int ldc)
{
    __shared__ __align__(16) float As[BK][BM+4];
    __shared__ __align__(16) float Bs[BK][BN+4];
    const int tid = threadIdx.x;
    const int tn  = tid % (BN/TN);
    const int tm  = tid / (BN/TN);
    const int row0 = blockIdx.y * BM;
    const int col0 = blockIdx.x * BN;

    float acc[TM][TN];
#pragma unroll
    for (int i = 0; i < TM; i++)
#pragma unroll
        for (int j = 0; j < TN; j++) acc[i][j] = 0.f;

    for (int k0 = 0; k0 < K; k0 += BK) {
#pragma unroll
        for (int idx = tid; idx < BM*BK; idx += 256) {
            int r = idx / BK, c = idx % BK;
            int gr = row0 + r, gc = k0 + c;
            As[c][r] = (gr < M && gc < K) ? A[(size_t)gr*K + gc] : 0.f;
        }
#pragma unroll
        for (int idx = tid; idx < BK*BN; idx += 256) {
            int r = idx / BN, c = idx % BN;
            int gr = k0 + r, gc = col0 + c;
            Bs[r][c] = (gr < K && gc < N) ? B[(size_t)gr*N + gc] : 0.f;
        }
        __syncthreads();
#pragma unroll
        for (int k = 0; k < BK; k++) {
            float a[TM], b[TN];
#pragma unroll
            for (int i = 0; i < TM; i += 4)
                *(float4*)&a[i] = *(const float4*)&As[k][tm*TM + i];
#pragma unroll
            for (int j = 0; j < TN; j += 4)
                *(float4*)&b[j] = *(const float4*)&Bs[k][tn*TN + j];
#pragma unroll
            for (int i = 0; i < TM; i++)
#pragma unroll
                for (int j = 0; j < TN; j++)
                    acc[i][j] = fmaf(a[i], b[j], acc[i][j]);
        }
        __syncthreads();
    }

#pragma unroll
    for (int i = 0; i < TM; i++) {
        int r = row0 + tm*TM + i;
        if (r >= M) continue;
#pragma unroll
        for (int j = 0; j < TN; j++) {
            int c = col0 + tn*TN + j;
            if (c >= N) continue;
            float v = acc[i][j];
            if (BIAS) v += bias[c];
            if (RELU) v = v > 0.f ? v : 0.f;
            C[(size_t)r*ldc + c] = v;
        }
    }
}

// ---------------------------------------------------------------------------
// a_src[n,h], a_dst[n,h] from xh
// ---------------------------------------------------------------------------
__global__ __launch_bounds__(256)
void attn_logits(const float* __restrict__ xh, const float* __restrict__ att_s,
                 const float* __restrict__ att_d,
                 float* __restrict__ a_src, float* __restrict__ a_dst)
{
    int idx = blockIdx.x*256 + threadIdx.x;
    if (idx >= NN*NH) return;
    int n = idx / NH, h = idx % NH;
    const float* xr = xh + (size_t)n*HD + h*FX;
    const float* as = att_s + h*FX;
    const float* ad = att_d + h*FX;
    float s1 = 0.f, s2 = 0.f;
    for (int c = 0; c < FX; c++) {
        float v = xr[c];
        s1 = fmaf(v, as[c], s1);
        s2 = fmaf(v, ad[c], s2);
    }
    a_src[idx] = s1;
    a_dst[idx] = s2;
}

// ---------------------------------------------------------------------------
// CSR build: count -> scan -> scatter
// ---------------------------------------------------------------------------
__global__ void edge_count(const int* __restrict__ ei, int* __restrict__ deg)
{
    int e = blockIdx.x*256 + threadIdx.x;
    if (e >= NT) return;
    int dst = (e < NE) ? ei[NE + e] : (e - NE);
    atomicAdd(&deg[dst], 1);
}

__global__ __launch_bounds__(1024)
void scan_kernel(const int* __restrict__ deg, int* __restrict__ offs, int* __restrict__ cursor)
{
    __shared__ int part[1024];
    int tid = threadIdx.x;
    int base = tid*16;
    int v[16]; int ssum = 0;
#pragma unroll
    for (int j = 0; j < 16; j++) { v[j] = deg[base+j]; ssum += v[j]; }
    part[tid] = ssum;
    __syncthreads();
    for (int d = 1; d < 1024; d <<= 1) {
        int t = (tid >= d) ? part[tid-d] : 0;
        __syncthreads();
        part[tid] += t;
        __syncthreads();
    }
    int run = (tid == 0) ? 0 : part[tid-1];
#pragma unroll
    for (int j = 0; j < 16; j++) { offs[base+j] = run; cursor[base+j] = run; run += v[j]; }
    if (tid == 1023) offs[NN] = run;
}

__global__ void edge_scatter(const int* __restrict__ ei, int* __restrict__ cursor,
                             int* __restrict__ csr)
{
    int e = blockIdx.x*256 + threadIdx.x;
    if (e >= NT) return;
    int src, dst;
    if (e < NE) { src = ei[e]; dst = ei[NE + e]; }
    else        { src = e - NE; dst = e - NE; }
    int pos = atomicAdd(&cursor[dst], 1);
    csr[pos] = src;
}

__global__ void dinv_kernel(const int* __restrict__ offs, float* __restrict__ dinv)
{
    int n = blockIdx.x*256 + threadIdx.x;
    if (n >= NN) return;
    int d = offs[n+1] - offs[n];
    dinv[n] = rsqrtf((float)(d > 0 ? d : 1));
}

// ---------------------------------------------------------------------------
// GAT aggregation: one wave per node. 6 lanes per head x 13 contiguous chans.
// h[n] = relu( (sum_e exp(ev-m)*xh[src]) / (sum_e exp(ev-m)) + b )
// ---------------------------------------------------------------------------
__global__ __launch_bounds__(256)
void gat_agg(const float* __restrict__ xh, const float* __restrict__ a_src,
             const float* __restrict__ a_dst, const float* __restrict__ gat_b,
             const int* __restrict__ offs, const int* __restrict__ csr,
             float* __restrict__ hout)
{
    int n = blockIdx.x*4 + (threadIdx.x >> 6);
    if (n >= NN) return;
    int lane = threadIdx.x & 63;
    bool act = lane < 60;
    int h   = act ? (lane / 6) : 0;
    int sub = act ? (lane % 6) : 0;
    int cbase = h*FX + sub*13;
    int off = offs[n], end = offs[n+1];
    float adn = a_dst[n*NH + h];

    float m = -3.0e38f;
    for (int i = off; i < end; i++) {
        int s = csr[i];
        float ev = a_src[s*NH + h] + adn;
        ev = ev > 0.f ? ev : 0.2f*ev;
        m = fmaxf(m, ev);
    }
    float den = 0.f;
    float acc[13];
#pragma unroll
    for (int j = 0; j < 13; j++) acc[j] = 0.f;
    for (int i = off; i < end; i++) {
        int s = csr[i];
        float ev = a_src[s*NH + h] + adn;
        ev = ev > 0.f ? ev : 0.2f*ev;
        float ee = __expf(ev - m);
        den += ee;
        const float* xr = xh + (size_t)s*HD + cbase;
#pragma unroll
        for (int j = 0; j < 13; j++) acc[j] = fmaf(xr[j], ee, acc[j]);
    }
    if (act) {
        float inv = 1.f / den;
        const float* bb = gat_b + cbase;
        float* op = hout + (size_t)n*HD + cbase;
#pragma unroll
        for (int j = 0; j < 13; j++) {
            float v = fmaf(acc[j], inv, bb[j]);
            op[j] = v > 0.f ? v : 0.f;
        }
    }
}

// ---------------------------------------------------------------------------
// GCN aggregation: one wave per node, lane-strided channels (coalesced).
// ---------------------------------------------------------------------------
__global__ __launch_bounds__(256)
void gcn_agg(const float* __restrict__ hw, const float* __restrict__ dinv,
             const float* __restrict__ gcn_b, const int* __restrict__ offs,
             const int* __restrict__ csr, float* __restrict__ g)
{
    int n = blockIdx.x*4 + (threadIdx.x >> 6);
    if (n >= NN) return;
    int lane = threadIdx.x & 63;
    int off = offs[n], end = offs[n+1];
    float dn = dinv[n];
    float acc[13];
#pragma unroll
    for (int j = 0; j < 13; j++) acc[j] = 0.f;
    for (int i = off; i < end; i++) {
        int s = csr[i];
        float w = dinv[s] * dn;
        const float* r = hw + (size_t)s*HD;
#pragma unroll
        for (int j = 0; j < 13; j++) {
            int c = lane + 64*j;
            if (c < HD) acc[j] = fmaf(r[c], w, acc[j]);
        }
    }
    float* op = g + (size_t)n*HD;
#pragma unroll
    for (int j = 0; j < 13; j++) {
        int c = lane + 64*j;
        if (c < HD) {
            float v = acc[j] + gcn_b[c];
            op[c] = v > 0.f ? v : 0.f;
        }
    }
}

// ---------------------------------------------------------------------------
// Per-graph boundaries via binary search on sorted batch
// ---------------------------------------------------------------------------
__global__ void gstart_kernel(const int* __restrict__ batch, int* __restrict__ goffs)
{
    int b = blockIdx.x*256 + threadIdx.x;
    if (b > NG) return;
    if (b == NG) { goffs[NG] = NN; return; }
    int lo = 0, hi = NN;
    while (lo < hi) { int mid = (lo+hi) >> 1; if (batch[mid] < b) lo = mid+1; else hi = mid; }
    goffs[b] = lo;
}

// max-pool + mean-pool per graph -> d[b, 0:780]=max, d[b,780:1560]=mean
__global__ __launch_bounds__(256)
void pool_kernel(const float* __restrict__ g, const int* __restrict__ goffs,
                 float* __restrict__ d)
{
    int b = blockIdx.x;
    int tid = threadIdx.x;
    int s = goffs[b], e = goffs[b+1];
    float mx[4], sm[4];
#pragma unroll
    for (int j = 0; j < 4; j++) { mx[j] = -3.0e38f; sm[j] = 0.f; }
    for (int n = s; n < e; n++) {
        const float* r = g + (size_t)n*HD;
#pragma unroll
        for (int j = 0; j < 4; j++) {
            int c = tid + 256*j;
            if (c < HD) { float v = r[c]; mx[j] = fmaxf(mx[j], v); sm[j] += v; }
        }
    }
    int cnt = e - s;
    float inv = 1.f / (float)(cnt > 0 ? cnt : 1);
#pragma unroll
    for (int j = 0; j < 4; j++) {
        int c = tid + 256*j;
        if (c < HD) {
            d[(size_t)b*1560 + c]      = mx[j];
            d[(size_t)b*1560 + HD + c] = sm[j] * inv;
        }
    }
}

// ---------------------------------------------------------------------------
// Protein conv: block per graph; emb_w row (100 f) double-buffered in LDS.
// Thread owns (o = tid>>3, t0 = (tid&7)*12): 12 outputs, 96 FMA per row.
// c[b,o,t] = sum_i sum_k emb_w[target[b,i], t+k] * conv_w[o,i,k]
// ---------------------------------------------------------------------------
__global__ __launch_bounds__(256)
void conv_kernel(const int* __restrict__ target, const float* __restrict__ emb_w,
                 const float* __restrict__ conv_w, const float* __restrict__ conv_b,
                 float* __restrict__ cout)
{
    __shared__ __align__(16) float ebuf[2][112];
    int b = blockIdx.x;
    int tid = threadIdx.x;
    int o  = tid >> 3;
    int s  = tid & 7;
    int t0 = s * 12;

    if (tid < 12) { ebuf[0][100+tid] = 0.f; ebuf[1][100+tid] = 0.f; }
    if (tid < 25) {
        int v0 = target[b*SEQ];
        ((float4*)&ebuf[0][0])[tid] = ((const float4*)(emb_w + (size_t)v0*EMB))[tid];
    }
    const float* wbase = conv_w + (size_t)o*SEQ*KS;
    float acc[12];
#pragma unroll
    for (int j = 0; j < 12; j++) acc[j] = 0.f;

    int cur = 0;
    for (int i = 0; i < SEQ; i++) {
        __syncthreads();
        if (i+1 < SEQ && tid < 25) {
            int v = target[b*SEQ + i + 1];
            ((float4*)&ebuf[cur^1][0])[tid] = ((const float4*)(emb_w + (size_t)v*EMB))[tid];
        }
        float4 wa = *(const float4*)(wbase + i*KS);
        float4 wb = *(const float4*)(wbase + i*KS + 4);
        float wk[8] = {wa.x, wa.y, wa.z, wa.w, wb.x, wb.y, wb.z, wb.w};
        float ew[20];
        const float* eb = &ebuf[cur][0];
#pragma unroll
        for (int q = 0; q < 5; q++)
            *(float4*)&ew[4*q] = *(const float4*)(eb + t0 + 4*q);
#pragma unroll
        for (int j = 0; j < 12; j++) {
            float a = acc[j];
#pragma unroll
            for (int k = 0; k < 8; k++) a = fmaf(ew[j+k], wk[k], a);
            acc[j] = a;
        }
        cur ^= 1;
    }
    float cb = conv_b[o];
#pragma unroll
    for (int j = 0; j < 12; j++) {
        int t = t0 + j;
        if (t < CLEN) cout[(size_t)b*(NF*CLEN) + o*CLEN + t] = acc[j] + cb;
    }
}

// ---------------------------------------------------------------------------
extern "C" void kernel_launch(void* const* d_in, const int* in_sizes, int n_in,
                              void* d_out, int out_size, void* d_ws, size_t ws_size,
                              hipStream_t stream)
{
    const float* x      = (const float*)d_in[0];
    const int*   ei     = (const int*)  d_in[1];
    const int*   batch  = (const int*)  d_in[2];
    const int*   target = (const int*)  d_in[3];
    const float* gat_w  = (const float*)d_in[4];
    const float* att_s  = (const float*)d_in[5];
    const float* att_d  = (const float*)d_in[6];
    const float* gat_b  = (const float*)d_in[7];
    const float* gcn_w  = (const float*)d_in[8];
    const float* gcn_b  = (const float*)d_in[9];
    const float* fcg1_w = (const float*)d_in[10];
    const float* fcg1_b = (const float*)d_in[11];
    const float* fcg2_w = (const float*)d_in[12];
    const float* fcg2_b = (const float*)d_in[13];
    const float* emb_w  = (const float*)d_in[14];
    const float* conv_w = (const float*)d_in[15];
    const float* conv_b = (const float*)d_in[16];
    const float* fcxt_w = (const float*)d_in[17];
    const float* fcxt_b = (const float*)d_in[18];
    const float* mlp1_w = (const float*)d_in[19];
    const float* mlp1_b = (const float*)d_in[20];
    const float* mlp2_w = (const float*)d_in[21];
    const float* mlp2_b = (const float*)d_in[22];
    const float* mlp3_w = (const float*)d_in[23];
    const float* mlp3_b = (const float*)d_in[24];
    float* out = (float*)d_out;

    char* ws = (char*)d_ws;
    size_t off = 0;
    auto alloc = [&](size_t bytes) -> char* {
        char* p = ws + off;
        off = (off + bytes + 255) & ~(size_t)255;
        return p;
    };
    float* xh    = (float*)alloc((size_t)NN*HD*4);   // reused as hw
    float* hbuf  = (float*)alloc((size_t)NN*HD*4);   // reused as g
    float* a_src = (float*)alloc((size_t)NN*NH*4);
    float* a_dst = (float*)alloc((size_t)NN*NH*4);
    int*   deg    = (int*)alloc((size_t)NN*4);
    int*   offs   = (int*)alloc((size_t)(NN+1)*4);
    int*   cursor = (int*)alloc((size_t)NN*4);
    int*   csr    = (int*)alloc((size_t)NT*4);
    float* dinv   = (float*)alloc((size_t)NN*4);
    int*   goffs  = (int*)alloc((size_t)(NG+1)*4);
    float* dpool  = (float*)alloc((size_t)NG*1560*4);
    float* d1     = (float*)alloc((size_t)NG*1500*4);
    float* cbuf   = (float*)alloc((size_t)NG*NF*CLEN*4);
    float* obuf   = (float*)alloc((size_t)NG*256*4);
    float* o1     = (float*)alloc((size_t)NG*1024*4);
    float* o2     = (float*)alloc((size_t)NG*512*4);

    float* hw = xh;    // xh dead after gat_agg
    float* g  = hbuf;  // h dead after gcn gemm

    hipMemsetAsync(deg, 0, (size_t)NN*4, stream);

    // GAT: xh = x @ gat_w   (16384 x 78 x 780)
    gemm_f32<128,128,16,8,8,false,false>
        <<<dim3((HD+127)/128, (NN+127)/128), 256, 0, stream>>>(x, gat_w, nullptr, xh, NN, HD, FX, HD);
    attn_logits<<<dim3((NN*NH+255)/256), 256, 0, stream>>>(xh, att_s, att_d, a_src, a_dst);

    // CSR over dst (edges + self loops)
    edge_count  <<<dim3(NT/256), 256, 0, stream>>>(ei, deg);
    scan_kernel <<<1, 1024, 0, stream>>>(deg, offs, cursor);
    edge_scatter<<<dim3(NT/256), 256, 0, stream>>>(ei, cursor, csr);
    dinv_kernel <<<dim3(NN/256), 256, 0, stream>>>(offs, dinv);

    // GAT aggregate -> h
    gat_agg<<<dim3(NN/4), 256, 0, stream>>>(xh, a_src, a_dst, gat_b, offs, csr, hbuf);

    // GCN: hw = h @ gcn_w  (16384 x 780 x 780), then aggregate -> g
    gemm_f32<128,128,16,8,8,false,false>
        <<<dim3((HD+127)/128, (NN+127)/128), 256, 0, stream>>>(hbuf, gcn_w, nullptr, hw, NN, HD, HD, HD);
    gcn_agg<<<dim3(NN/4), 256, 0, stream>>>(hw, dinv, gcn_b, offs, csr, g);

    // pooling -> d (512 x 1560)
    gstart_kernel<<<3, 256, 0, stream>>>(batch, goffs);
    pool_kernel<<<NG, 256, 0, stream>>>(g, goffs, dpool);

    // graph FC: d1 = relu(d@fcg1_w+b); obuf[:,0:128] = d1@fcg2_w+b
    gemm_f32<64,64,16,4,4,true,true>
        <<<dim3((1500+63)/64, (NG+63)/64), 256, 0, stream>>>(dpool, fcg1_w, fcg1_b, d1, NG, 1500, 1560, 1500);
    gemm_f32<64,64,16,4,4,true,false>
        <<<dim3(2, 8), 256, 0, stream>>>(d1, fcg2_w, fcg2_b, obuf, NG, 128, 1500, 256);

    // protein branch: conv -> cbuf; obuf[:,128:256] = cbuf@fcxt_w+b
    conv_kernel<<<NG, 256, 0, stream>>>(target, emb_w, conv_w, conv_b, cbuf);
    gemm_f32<64,64,16,4,4,true,false>
        <<<dim3(2, 8), 256, 0, stream>>>(cbuf, fcxt_w, fcxt_b, obuf + 128, NG, 128, NF*CLEN, 256);

    // MLP head
    gemm_f32<64,64,16,4,4,true,true>
        <<<dim3(16, 8), 256, 0, stream>>>(obuf, mlp1_w, mlp1_b, o1, NG, 1024, 256, 1024);
    gemm_f32<64,64,16,4,4,true,true>
        <<<dim3(8, 8), 256, 0, stream>>>(o1, mlp2_w, mlp2_b, o2, NG, 512, 1024, 512);
    gemm_f32<64,64,16,4,4,true,false>
        <<<dim3(1, 8), 256, 0, stream>>>(o2, mlp3_w, mlp3_b, out, NG, 1, 512, 1);
}

// Round 2
// 1928.165 us; speedup vs baseline: 1.4109x; 1.4109x over previous
//
#include <hip/hip_runtime.h>

#define NN 16384      // nodes
#define NE 65536      // edges
#define NT 81920      // edges + self loops
#define NG 512        // graphs
#define NH 10         // heads
#define FX 78         // features per head
#define HD 780        // hidden = NH*FX
#define SEQ 1000
#define EMB 100
#define NF 32
#define KS 8
#define CLEN 93

typedef __bf16 bf16x8 __attribute__((ext_vector_type(8)));
typedef float  f32x4  __attribute__((ext_vector_type(4)));

// ---------------------------------------------------------------------------
// bf16 cast + pad helpers
// ---------------------------------------------------------------------------
__global__ __launch_bounds__(256)
void cast_pad_a(const float* __restrict__ in, __bf16* __restrict__ out,
                int M, int K, int Kp)
{
    size_t idx = (size_t)blockIdx.x*256 + threadIdx.x;
    if (idx >= (size_t)M*Kp) return;
    int r = idx / Kp, c = idx % Kp;
    out[idx] = (c < K) ? (__bf16)in[(size_t)r*K + c] : (__bf16)0.f;
}

__global__ __launch_bounds__(256)
void cast_pad_bt(const float* __restrict__ B, __bf16* __restrict__ out,
                 int K, int N, int Kp, int Np)
{
    size_t idx = (size_t)blockIdx.x*256 + threadIdx.x;
    if (idx >= (size_t)Np*Kp) return;
    int n = idx / Kp, k = idx % Kp;
    out[idx] = (n < N && k < K) ? (__bf16)B[(size_t)k*N + n] : (__bf16)0.f;
}

// ---------------------------------------------------------------------------
// bf16 MFMA GEMM: C[M,ldc] = A[M,Kp] @ Bt[Np,Kp]^T
// 128x128 tile, 4 waves, each wave 64x64 (4x4 fragments of 16x16x32).
// LDS rows padded to 40 bf16 (80B) -> fragment reads are 2-way (free).
// ---------------------------------------------------------------------------
#define BKP 40
__global__ __launch_bounds__(256)
void gemm_mfma_bf16(const __bf16* __restrict__ A, const __bf16* __restrict__ Bt,
                    float* __restrict__ C, int M, int N, int Kp, int ldc)
{
    __shared__ __align__(16) __bf16 As[128*BKP];
    __shared__ __align__(16) __bf16 Bs[128*BKP];
    const int tid = threadIdx.x;
    const int row0 = blockIdx.y*128, col0 = blockIdx.x*128;
    const int lane = tid & 63, wid = tid >> 6;
    const int wm = wid & 1, wn = wid >> 1;
    const int l15 = lane & 15, lk = lane >> 4;

    f32x4 acc[4][4];
#pragma unroll
    for (int i = 0; i < 4; i++)
#pragma unroll
        for (int j = 0; j < 4; j++) acc[i][j] = (f32x4){0.f,0.f,0.f,0.f};

    for (int k0 = 0; k0 < Kp; k0 += 32) {
        __syncthreads();
#pragma unroll
        for (int it = 0; it < 2; ++it) {
            int c = tid + it*256;
            int r = c >> 2, c16 = c & 3;
            uint4 va = *(const uint4*)(A  + (size_t)(row0+r)*Kp + k0 + c16*8);
            *(uint4*)&As[r*BKP + c16*8] = va;
            uint4 vb = *(const uint4*)(Bt + (size_t)(col0+r)*Kp + k0 + c16*8);
            *(uint4*)&Bs[r*BKP + c16*8] = vb;
        }
        __syncthreads();
        bf16x8 af[4], bfr[4];
#pragma unroll
        for (int i = 0; i < 4; i++) {
            af[i]  = *(const bf16x8*)&As[(wm*64 + i*16 + l15)*BKP + lk*8];
            bfr[i] = *(const bf16x8*)&Bs[(wn*64 + i*16 + l15)*BKP + lk*8];
        }
#pragma unroll
        for (int i = 0; i < 4; i++)
#pragma unroll
            for (int j = 0; j < 4; j++)
                acc[i][j] = __builtin_amdgcn_mfma_f32_16x16x32_bf16(af[i], bfr[j], acc[i][j], 0, 0, 0);
    }

#pragma unroll
    for (int i = 0; i < 4; i++) {
        int rbase = row0 + wm*64 + i*16 + lk*4;
#pragma unroll
        for (int j = 0; j < 4; j++) {
            int cc = col0 + wn*64 + j*16 + l15;
            if (cc >= N) continue;
#pragma unroll
            for (int r = 0; r < 4; r++)
                C[(size_t)(rbase + r)*ldc + cc] = acc[i][j][r];
        }
    }
}

// ---------------------------------------------------------------------------
// Generic fp32 tiled GEMM (small FC stack): C[M,ldc] = A@B (+bias)(+relu)
// ---------------------------------------------------------------------------
template<int BM,int BN,int BK,int TM,int TN,bool BIAS,bool RELU>
__launch_bounds__(256)
__global__ void gemm_f32(const float* __restrict__ A, const float* __restrict__ B,
                         const float* __restrict__ bias, float* __restrict__ C,
                         int M, int N, int K, int ldc)
{
    __shared__ __align__(16) float As[BK][BM+4];
    __shared__ __align__(16) float Bs[BK][BN+4];
    const int tid = threadIdx.x;
    const int tn  = tid % (BN/TN);
    const int tm  = tid / (BN/TN);
    const int row0 = blockIdx.y * BM;
    const int col0 = blockIdx.x * BN;

    float acc[TM][TN];
#pragma unroll
    for (int i = 0; i < TM; i++)
#pragma unroll
        for (int j = 0; j < TN; j++) acc[i][j] = 0.f;

    for (int k0 = 0; k0 < K; k0 += BK) {
#pragma unroll
        for (int idx = tid; idx < BM*BK; idx += 256) {
            int r = idx / BK, c = idx % BK;
            int gr = row0 + r, gc = k0 + c;
            As[c][r] = (gr < M && gc < K) ? A[(size_t)gr*K + gc] : 0.f;
        }
#pragma unroll
        for (int idx = tid; idx < BK*BN; idx += 256) {
            int r = idx / BN, c = idx % BN;
            int gr = k0 + r, gc = col0 + c;
            Bs[r][c] = (gr < K && gc < N) ? B[(size_t)gr*N + gc] : 0.f;
        }
        __syncthreads();
#pragma unroll
        for (int k = 0; k < BK; k++) {
            float a[TM], b[TN];
#pragma unroll
            for (int i = 0; i < TM; i += 4)
                *(float4*)&a[i] = *(const float4*)&As[k][tm*TM + i];
#pragma unroll
            for (int j = 0; j < TN; j += 4)
                *(float4*)&b[j] = *(const float4*)&Bs[k][tn*TN + j];
#pragma unroll
            for (int i = 0; i < TM; i++)
#pragma unroll
                for (int j = 0; j < TN; j++)
                    acc[i][j] = fmaf(a[i], b[j], acc[i][j]);
        }
        __syncthreads();
    }

#pragma unroll
    for (int i = 0; i < TM; i++) {
        int r = row0 + tm*TM + i;
        if (r >= M) continue;
#pragma unroll
        for (int j = 0; j < TN; j++) {
            int c = col0 + tn*TN + j;
            if (c >= N) continue;
            float v = acc[i][j];
            if (BIAS) v += bias[c];
            if (RELU) v = v > 0.f ? v : 0.f;
            C[(size_t)r*ldc + c] = v;
        }
    }
}

// ---------------------------------------------------------------------------
// a_src[n,h], a_dst[n,h] from xh
// ---------------------------------------------------------------------------
__global__ __launch_bounds__(256)
void attn_logits(const float* __restrict__ xh, const float* __restrict__ att_s,
                 const float* __restrict__ att_d,
                 float* __restrict__ a_src, float* __restrict__ a_dst)
{
    int idx = blockIdx.x*256 + threadIdx.x;
    if (idx >= NN*NH) return;
    int n = idx / NH, h = idx % NH;
    const float* xr = xh + (size_t)n*HD + h*FX;
    const float* as = att_s + h*FX;
    const float* ad = att_d + h*FX;
    float s1 = 0.f, s2 = 0.f;
    for (int c = 0; c < FX; c++) {
        float v = xr[c];
        s1 = fmaf(v, as[c], s1);
        s2 = fmaf(v, ad[c], s2);
    }
    a_src[idx] = s1;
    a_dst[idx] = s2;
}

// ---------------------------------------------------------------------------
// CSR build: count -> scan -> scatter
// ---------------------------------------------------------------------------
__global__ void edge_count(const int* __restrict__ ei, int* __restrict__ deg)
{
    int e = blockIdx.x*256 + threadIdx.x;
    if (e >= NT) return;
    int dst = (e < NE) ? ei[NE + e] : (e - NE);
    atomicAdd(&deg[dst], 1);
}

__global__ __launch_bounds__(1024)
void scan_kernel(const int* __restrict__ deg, int* __restrict__ offs, int* __restrict__ cursor)
{
    __shared__ int part[1024];
    int tid = threadIdx.x;
    int base = tid*16;
    int v[16]; int ssum = 0;
#pragma unroll
    for (int j = 0; j < 16; j++) { v[j] = deg[base+j]; ssum += v[j]; }
    part[tid] = ssum;
    __syncthreads();
    for (int d = 1; d < 1024; d <<= 1) {
        int t = (tid >= d) ? part[tid-d] : 0;
        __syncthreads();
        part[tid] += t;
        __syncthreads();
    }
    int run = (tid == 0) ? 0 : part[tid-1];
#pragma unroll
    for (int j = 0; j < 16; j++) { offs[base+j] = run; cursor[base+j] = run; run += v[j]; }
    if (tid == 1023) offs[NN] = run;
}

__global__ void edge_scatter(const int* __restrict__ ei, int* __restrict__ cursor,
                             int* __restrict__ csr)
{
    int e = blockIdx.x*256 + threadIdx.x;
    if (e >= NT) return;
    int src, dst;
    if (e < NE) { src = ei[e]; dst = ei[NE + e]; }
    else        { src = e - NE; dst = e - NE; }
    int pos = atomicAdd(&cursor[dst], 1);
    csr[pos] = src;
}

__global__ void dinv_kernel(const int* __restrict__ offs, float* __restrict__ dinv)
{
    int n = blockIdx.x*256 + threadIdx.x;
    if (n >= NN) return;
    int d = offs[n+1] - offs[n];
    dinv[n] = rsqrtf((float)(d > 0 ? d : 1));
}

// ---------------------------------------------------------------------------
// GAT aggregation: one wave per node. 6 lanes per head x 13 contiguous chans.
// ---------------------------------------------------------------------------
__global__ __launch_bounds__(256)
void gat_agg(const float* __restrict__ xh, const float* __restrict__ a_src,
             const float* __restrict__ a_dst, const float* __restrict__ gat_b,
             const int* __restrict__ offs, const int* __restrict__ csr,
             float* __restrict__ hout)
{
    int n = blockIdx.x*4 + (threadIdx.x >> 6);
    if (n >= NN) return;
    int lane = threadIdx.x & 63;
    bool act = lane < 60;
    int h   = act ? (lane / 6) : 0;
    int sub = act ? (lane % 6) : 0;
    int cbase = h*FX + sub*13;
    int off = offs[n], end = offs[n+1];
    float adn = a_dst[n*NH + h];

    float m = -3.0e38f;
    for (int i = off; i < end; i++) {
        int s = csr[i];
        float ev = a_src[s*NH + h] + adn;
        ev = ev > 0.f ? ev : 0.2f*ev;
        m = fmaxf(m, ev);
    }
    float den = 0.f;
    float acc[13];
#pragma unroll
    for (int j = 0; j < 13; j++) acc[j] = 0.f;
    for (int i = off; i < end; i++) {
        int s = csr[i];
        float ev = a_src[s*NH + h] + adn;
        ev = ev > 0.f ? ev : 0.2f*ev;
        float ee = __expf(ev - m);
        den += ee;
        const float* xr = xh + (size_t)s*HD + cbase;
#pragma unroll
        for (int j = 0; j < 13; j++) acc[j] = fmaf(xr[j], ee, acc[j]);
    }
    if (act) {
        float inv = 1.f / den;
        const float* bb = gat_b + cbase;
        float* op = hout + (size_t)n*HD + cbase;
#pragma unroll
        for (int j = 0; j < 13; j++) {
            float v = fmaf(acc[j], inv, bb[j]);
            op[j] = v > 0.f ? v : 0.f;
        }
    }
}

// ---------------------------------------------------------------------------
// GCN aggregation: one wave per node, lane-strided channels (coalesced).
// ---------------------------------------------------------------------------
__global__ __launch_bounds__(256)
void gcn_agg(const float* __restrict__ hw, const float* __restrict__ dinv,
             const float* __restrict__ gcn_b, const int* __restrict__ offs,
             const int* __restrict__ csr, float* __restrict__ g)
{
    int n = blockIdx.x*4 + (threadIdx.x >> 6);
    if (n >= NN) return;
    int lane = threadIdx.x & 63;
    int off = offs[n], end = offs[n+1];
    float dn = dinv[n];
    float acc[13];
#pragma unroll
    for (int j = 0; j < 13; j++) acc[j] = 0.f;
    for (int i = off; i < end; i++) {
        int s = csr[i];
        float w = dinv[s] * dn;
        const float* r = hw + (size_t)s*HD;
#pragma unroll
        for (int j = 0; j < 13; j++) {
            int c = lane + 64*j;
            if (c < HD) acc[j] = fmaf(r[c], w, acc[j]);
        }
    }
    float* op = g + (size_t)n*HD;
#pragma unroll
    for (int j = 0; j < 13; j++) {
        int c = lane + 64*j;
        if (c < HD) {
            float v = acc[j] + gcn_b[c];
            op[c] = v > 0.f ? v : 0.f;
        }
    }
}

// ---------------------------------------------------------------------------
__global__ void gstart_kernel(const int* __restrict__ batch, int* __restrict__ goffs)
{
    int b = blockIdx.x*256 + threadIdx.x;
    if (b > NG) return;
    if (b == NG) { goffs[NG] = NN; return; }
    int lo = 0, hi = NN;
    while (lo < hi) { int mid = (lo+hi) >> 1; if (batch[mid] < b) lo = mid+1; else hi = mid; }
    goffs[b] = lo;
}

__global__ __launch_bounds__(256)
void pool_kernel(const float* __restrict__ g, const int* __restrict__ goffs,
                 float* __restrict__ d)
{
    int b = blockIdx.x;
    int tid = threadIdx.x;
    int s = goffs[b], e = goffs[b+1];
    float mx[4], sm[4];
#pragma unroll
    for (int j = 0; j < 4; j++) { mx[j] = -3.0e38f; sm[j] = 0.f; }
    for (int n = s; n < e; n++) {
        const float* r = g + (size_t)n*HD;
#pragma unroll
        for (int j = 0; j < 4; j++) {
            int c = tid + 256*j;
            if (c < HD) { float v = r[c]; mx[j] = fmaxf(mx[j], v); sm[j] += v; }
        }
    }
    int cnt = e - s;
    float inv = 1.f / (float)(cnt > 0 ? cnt : 1);
#pragma unroll
    for (int j = 0; j < 4; j++) {
        int c = tid + 256*j;
        if (c < HD) {
            d[(size_t)b*1560 + c]      = mx[j];
            d[(size_t)b*1560 + HD + c] = sm[j] * inv;
        }
    }
}

// ---------------------------------------------------------------------------
// Protein conv: 4 embedding rows per double-buffered phase (1 barrier/phase).
// Thread owns (o = tid>>3, t0 = (tid&7)*12): 12 outputs, 384 FMA per phase.
// ---------------------------------------------------------------------------
__global__ __launch_bounds__(256)
void conv_kernel(const int* __restrict__ target, const float* __restrict__ emb_w,
                 const float* __restrict__ conv_w, const float* __restrict__ conv_b,
                 float* __restrict__ cout)
{
    __shared__ __align__(16) float ebuf[2][4][112];
    int b = blockIdx.x;
    int tid = threadIdx.x;
    int o  = tid >> 3;
    int t0 = (tid & 7) * 12;

    if (tid < 96) {   // zero the pad region of both buffers once
        int bb = tid/48, rr = (tid/12)%4, cc = 100 + tid%12;
        ebuf[bb][rr][cc] = 0.f;
    }
    if (tid < 100) {  // prologue: rows 0..3
        int rr = tid/25, c4 = tid%25;
        int v = target[b*SEQ + rr];
        ((float4*)&ebuf[0][rr][0])[c4] = ((const float4*)(emb_w + (size_t)v*EMB))[c4];
    }
    const float* wbase = conv_w + (size_t)o*SEQ*KS;
    float acc[12];
#pragma unroll
    for (int j = 0; j < 12; j++) acc[j] = 0.f;

    int cur = 0;
    for (int p = 0; p < SEQ/4; ++p) {
        __syncthreads();
        if (p+1 < SEQ/4 && tid < 100) {
            int rr = tid/25, c4 = tid%25;
            int v = target[b*SEQ + (p+1)*4 + rr];
            ((float4*)&ebuf[cur^1][rr][0])[c4] = ((const float4*)(emb_w + (size_t)v*EMB))[c4];
        }
#pragma unroll
        for (int rr = 0; rr < 4; ++rr) {
            int i = p*4 + rr;
            float4 wa = *(const float4*)(wbase + i*KS);
            float4 wb = *(const float4*)(wbase + i*KS + 4);
            float wk[8] = {wa.x, wa.y, wa.z, wa.w, wb.x, wb.y, wb.z, wb.w};
            float ew[20];
            const float* eb = &ebuf[cur][rr][0];
#pragma unroll
            for (int q = 0; q < 5; q++)
                *(float4*)&ew[4*q] = *(const float4*)(eb + t0 + 4*q);
#pragma unroll
            for (int j = 0; j < 12; j++) {
                float a = acc[j];
#pragma unroll
                for (int k = 0; k < 8; k++) a = fmaf(ew[j+k], wk[k], a);
                acc[j] = a;
            }
        }
        cur ^= 1;
    }
    float cb = conv_b[o];
#pragma unroll
    for (int j = 0; j < 12; j++) {
        int t = t0 + j;
        if (t < CLEN) cout[(size_t)b*(NF*CLEN) + o*CLEN + t] = acc[j] + cb;
    }
}

// ---------------------------------------------------------------------------
extern "C" void kernel_launch(void* const* d_in, const int* in_sizes, int n_in,
                              void* d_out, int out_size, void* d_ws, size_t ws_size,
                              hipStream_t stream)
{
    const float* x      = (const float*)d_in[0];
    const int*   ei     = (const int*)  d_in[1];
    const int*   batch  = (const int*)  d_in[2];
    const int*   target = (const int*)  d_in[3];
    const float* gat_w  = (const float*)d_in[4];
    const float* att_s  = (const float*)d_in[5];
    const float* att_d  = (const float*)d_in[6];
    const float* gat_b  = (const float*)d_in[7];
    const float* gcn_w  = (const float*)d_in[8];
    const float* gcn_b  = (const float*)d_in[9];
    const float* fcg1_w = (const float*)d_in[10];
    const float* fcg1_b = (const float*)d_in[11];
    const float* fcg2_w = (const float*)d_in[12];
    const float* fcg2_b = (const float*)d_in[13];
    const float* emb_w  = (const float*)d_in[14];
    const float* conv_w = (const float*)d_in[15];
    const float* conv_b = (const float*)d_in[16];
    const float* fcxt_w = (const float*)d_in[17];
    const float* fcxt_b = (const float*)d_in[18];
    const float* mlp1_w = (const float*)d_in[19];
    const float* mlp1_b = (const float*)d_in[20];
    const float* mlp2_w = (const float*)d_in[21];
    const float* mlp2_b = (const float*)d_in[22];
    const float* mlp3_w = (const float*)d_in[23];
    const float* mlp3_b = (const float*)d_in[24];
    float* out = (float*)d_out;

    char* ws = (char*)d_ws;
    size_t off = 0;
    auto alloc = [&](size_t bytes) -> char* {
        char* p = ws + off;
        off = (off + bytes + 255) & ~(size_t)255;
        return p;
    };
    float* xh    = (float*)alloc((size_t)NN*HD*4);   // reused as hw
    float* hbuf  = (float*)alloc((size_t)NN*HD*4);   // reused as g
    float* a_src = (float*)alloc((size_t)NN*NH*4);
    float* a_dst = (float*)alloc((size_t)NN*NH*4);
    int*   deg    = (int*)alloc((size_t)NN*4);
    int*   offs   = (int*)alloc((size_t)(NN+1)*4);
    int*   cursor = (int*)alloc((size_t)NN*4);
    int*   csr    = (int*)alloc((size_t)NT*4);
    float* dinv   = (float*)alloc((size_t)NN*4);
    int*   goffs  = (int*)alloc((size_t)(NG+1)*4);
    float* dpool  = (float*)alloc((size_t)NG*1560*4);
    float* d1     = (float*)alloc((size_t)NG*1500*4);
    float* cbuf   = (float*)alloc((size_t)NG*NF*CLEN*4);
    float* obuf   = (float*)alloc((size_t)NG*256*4);
    float* o1     = (float*)alloc((size_t)NG*1024*4);
    float* o2     = (float*)alloc((size_t)NG*512*4);
    __bf16* Abf   = (__bf16*)alloc((size_t)NN*800*2);    // shared by both big GEMMs
    __bf16* Btbf  = (__bf16*)alloc((size_t)896*800*2);

    float* hw = xh;    // xh dead after gat_agg
    float* g  = hbuf;  // h dead after gcn gemm

    hipMemsetAsync(deg, 0, (size_t)NN*4, stream);

    // --- GAT linear: xh = x @ gat_w  (16384 x 78 x 780), bf16 MFMA, Kp=96 ---
    cast_pad_a <<<dim3((NN*96)/256), 256, 0, stream>>>(x, Abf, NN, FX, 96);
    cast_pad_bt<<<dim3((896*96)/256), 256, 0, stream>>>(gat_w, Btbf, FX, HD, 96, 896);
    gemm_mfma_bf16<<<dim3(7, NN/128), 256, 0, stream>>>(Abf, Btbf, xh, NN, HD, 96, HD);
    attn_logits<<<dim3((NN*NH+255)/256), 256, 0, stream>>>(xh, att_s, att_d, a_src, a_dst);

    // --- CSR over dst (edges + self loops) ---
    edge_count  <<<dim3(NT/256), 256, 0, stream>>>(ei, deg);
    scan_kernel <<<1, 1024, 0, stream>>>(deg, offs, cursor);
    edge_scatter<<<dim3(NT/256), 256, 0, stream>>>(ei, cursor, csr);
    dinv_kernel <<<dim3(NN/256), 256, 0, stream>>>(offs, dinv);

    // --- GAT aggregate -> h ---
    gat_agg<<<dim3(NN/4), 256, 0, stream>>>(xh, a_src, a_dst, gat_b, offs, csr, hbuf);

    // --- GCN linear: hw = h @ gcn_w  (16384 x 780 x 780), bf16 MFMA, Kp=800 ---
    cast_pad_a <<<dim3((NN*800)/256), 256, 0, stream>>>(hbuf, Abf, NN, HD, 800);
    cast_pad_bt<<<dim3((896*800)/256), 256, 0, stream>>>(gcn_w, Btbf, HD, HD, 800, 896);
    gemm_mfma_bf16<<<dim3(7, NN/128), 256, 0, stream>>>(Abf, Btbf, hw, NN, HD, 800, HD);
    gcn_agg<<<dim3(NN/4), 256, 0, stream>>>(hw, dinv, gcn_b, offs, csr, g);

    // --- pooling -> d (512 x 1560) ---
    gstart_kernel<<<3, 256, 0, stream>>>(batch, goffs);
    pool_kernel<<<NG, 256, 0, stream>>>(g, goffs, dpool);

    // --- graph FC ---
    gemm_f32<64,64,16,4,4,true,true>
        <<<dim3((1500+63)/64, (NG+63)/64), 256, 0, stream>>>(dpool, fcg1_w, fcg1_b, d1, NG, 1500, 1560, 1500);
    gemm_f32<64,64,16,4,4,true,false>
        <<<dim3(2, 8), 256, 0, stream>>>(d1, fcg2_w, fcg2_b, obuf, NG, 128, 1500, 256);

    // --- protein branch ---
    conv_kernel<<<NG, 256, 0, stream>>>(target, emb_w, conv_w, conv_b, cbuf);
    gemm_f32<64,64,16,4,4,true,false>
        <<<dim3(2, 8), 256, 0, stream>>>(cbuf, fcxt_w, fcxt_b, obuf + 128, NG, 128, NF*CLEN, 256);

    // --- MLP head ---
    gemm_f32<64,64,16,4,4,true,true>
        <<<dim3(16, 8), 256, 0, stream>>>(obuf, mlp1_w, mlp1_b, o1, NG, 1024, 256, 1024);
    gemm_f32<64,64,16,4,4,true,true>
        <<<dim3(8, 8), 256, 0, stream>>>(o1, mlp2_w, mlp2_b, o2, NG, 512, 1024, 512);
    gemm_f32<64,64,16,4,4,true,false>
        <<<dim3(1, 8), 256, 0, stream>>>(o2, mlp3_w, mlp3_b, out, NG, 1, 512, 1);
}

// Round 3
// 758.724 us; speedup vs baseline: 3.5855x; 2.5413x over previous
//
#include <hip/hip_runtime.h>

#define NN 16384      // nodes
#define NE 65536      // edges
#define NT 81920      // edges + self loops
#define NG 512        // graphs
#define NH 10         // heads
#define FX 78         // features per head
#define HD 780        // hidden = NH*FX
#define SEQ 1000
#define EMB 100
#define NF 32
#define KS 8
#define CLEN 93

typedef __bf16 bf16x8 __attribute__((ext_vector_type(8)));
typedef float  f32x4  __attribute__((ext_vector_type(4)));

// ---------------------------------------------------------------------------
// bf16 cast + pad helpers
// ---------------------------------------------------------------------------
__global__ __launch_bounds__(256)
void cast_pad_a(const float* __restrict__ in, __bf16* __restrict__ out,
                int M, int K, int Kp)
{
    size_t idx = (size_t)blockIdx.x*256 + threadIdx.x;
    if (idx >= (size_t)M*Kp) return;
    int r = idx / Kp, c = idx % Kp;
    out[idx] = (c < K) ? (__bf16)in[(size_t)r*K + c] : (__bf16)0.f;
}

// B[K,N] -> Bt[Np][Kp] (transposed, zero-padded)
__global__ __launch_bounds__(256)
void cast_pad_bt(const float* __restrict__ B, __bf16* __restrict__ out,
                 int K, int N, int Kp, int Np)
{
    size_t idx = (size_t)blockIdx.x*256 + threadIdx.x;
    if (idx >= (size_t)Np*Kp) return;
    int n = idx / Kp, k = idx % Kp;
    out[idx] = (n < N && k < K) ? (__bf16)B[(size_t)k*N + n] : (__bf16)0.f;
}

// ---------------------------------------------------------------------------
// bf16 MFMA GEMM: C[M,ldc] = A[M,Kp] @ Bt[Np,Kp]^T  (+bias)(+relu)
// 128x128 tile, 4 waves. Store f32 or bf16. For bf16 store, cols [N,Nz)
// are written as ZERO (K-padding for the next layer).
// ---------------------------------------------------------------------------
#define BKP 40
template<bool BIAS, bool RELU, bool BF16OUT>
__global__ __launch_bounds__(256)
void gemm_mfma(const __bf16* __restrict__ A, const __bf16* __restrict__ Bt,
               const float* __restrict__ bias, void* __restrict__ Cv,
               int M, int N, int Kp, int ldc, int Nz)
{
    __shared__ __align__(16) __bf16 As[128*BKP];
    __shared__ __align__(16) __bf16 Bs[128*BKP];
    const int tid = threadIdx.x;
    const int row0 = blockIdx.y*128, col0 = blockIdx.x*128;
    const int lane = tid & 63, wid = tid >> 6;
    const int wm = wid & 1, wn = wid >> 1;
    const int l15 = lane & 15, lk = lane >> 4;

    f32x4 acc[4][4];
#pragma unroll
    for (int i = 0; i < 4; i++)
#pragma unroll
        for (int j = 0; j < 4; j++) acc[i][j] = (f32x4){0.f,0.f,0.f,0.f};

    for (int k0 = 0; k0 < Kp; k0 += 32) {
        __syncthreads();
#pragma unroll
        for (int it = 0; it < 2; ++it) {
            int c = tid + it*256;
            int r = c >> 2, c16 = c & 3;
            uint4 va = *(const uint4*)(A  + (size_t)(row0+r)*Kp + k0 + c16*8);
            *(uint4*)&As[r*BKP + c16*8] = va;
            uint4 vb = *(const uint4*)(Bt + (size_t)(col0+r)*Kp + k0 + c16*8);
            *(uint4*)&Bs[r*BKP + c16*8] = vb;
        }
        __syncthreads();
        bf16x8 af[4], bfr[4];
#pragma unroll
        for (int i = 0; i < 4; i++) {
            af[i]  = *(const bf16x8*)&As[(wm*64 + i*16 + l15)*BKP + lk*8];
            bfr[i] = *(const bf16x8*)&Bs[(wn*64 + i*16 + l15)*BKP + lk*8];
        }
#pragma unroll
        for (int i = 0; i < 4; i++)
#pragma unroll
            for (int j = 0; j < 4; j++)
                acc[i][j] = __builtin_amdgcn_mfma_f32_16x16x32_bf16(af[i], bfr[j], acc[i][j], 0, 0, 0);
    }

#pragma unroll
    for (int i = 0; i < 4; i++) {
        int rbase = row0 + wm*64 + i*16 + lk*4;
#pragma unroll
        for (int j = 0; j < 4; j++) {
            int cc = col0 + wn*64 + j*16 + l15;
            if (cc >= Nz) continue;
            bool real = cc < N;
            float bv = (BIAS && real) ? bias[cc] : 0.f;
#pragma unroll
            for (int r = 0; r < 4; r++) {
                float v = real ? (acc[i][j][r] + bv) : 0.f;
                if (RELU) v = v > 0.f ? v : 0.f;
                if (BF16OUT) ((__bf16*)Cv)[(size_t)(rbase + r)*ldc + cc] = (__bf16)v;
                else         ((float*) Cv)[(size_t)(rbase + r)*ldc + cc] = v;
            }
        }
    }
}

// ---------------------------------------------------------------------------
// a_src[n,h], a_dst[n,h] from xh
// ---------------------------------------------------------------------------
__global__ __launch_bounds__(256)
void attn_logits(const float* __restrict__ xh, const float* __restrict__ att_s,
                 const float* __restrict__ att_d,
                 float* __restrict__ a_src, float* __restrict__ a_dst)
{
    int idx = blockIdx.x*256 + threadIdx.x;
    if (idx >= NN*NH) return;
    int n = idx / NH, h = idx % NH;
    const float* xr = xh + (size_t)n*HD + h*FX;
    const float* as = att_s + h*FX;
    const float* ad = att_d + h*FX;
    float s1 = 0.f, s2 = 0.f;
    for (int c = 0; c < FX; c++) {
        float v = xr[c];
        s1 = fmaf(v, as[c], s1);
        s2 = fmaf(v, ad[c], s2);
    }
    a_src[idx] = s1;
    a_dst[idx] = s2;
}

// ---------------------------------------------------------------------------
// CSR build
// ---------------------------------------------------------------------------
__global__ void edge_count(const int* __restrict__ ei, int* __restrict__ deg)
{
    int e = blockIdx.x*256 + threadIdx.x;
    if (e >= NT) return;
    int dst = (e < NE) ? ei[NE + e] : (e - NE);
    atomicAdd(&deg[dst], 1);
}

__global__ __launch_bounds__(1024)
void scan_kernel(const int* __restrict__ deg, int* __restrict__ offs, int* __restrict__ cursor)
{
    __shared__ int part[1024];
    int tid = threadIdx.x;
    int base = tid*16;
    int v[16]; int ssum = 0;
#pragma unroll
    for (int j = 0; j < 16; j++) { v[j] = deg[base+j]; ssum += v[j]; }
    part[tid] = ssum;
    __syncthreads();
    for (int d = 1; d < 1024; d <<= 1) {
        int t = (tid >= d) ? part[tid-d] : 0;
        __syncthreads();
        part[tid] += t;
        __syncthreads();
    }
    int run = (tid == 0) ? 0 : part[tid-1];
#pragma unroll
    for (int j = 0; j < 16; j++) { offs[base+j] = run; cursor[base+j] = run; run += v[j]; }
    if (tid == 1023) offs[NN] = run;
}

__global__ void edge_scatter(const int* __restrict__ ei, int* __restrict__ cursor,
                             int* __restrict__ csr)
{
    int e = blockIdx.x*256 + threadIdx.x;
    if (e >= NT) return;
    int src, dst;
    if (e < NE) { src = ei[e]; dst = ei[NE + e]; }
    else        { src = e - NE; dst = e - NE; }
    int pos = atomicAdd(&cursor[dst], 1);
    csr[pos] = src;
}

__global__ void dinv_kernel(const int* __restrict__ offs, float* __restrict__ dinv)
{
    int n = blockIdx.x*256 + threadIdx.x;
    if (n >= NN) return;
    int d = offs[n+1] - offs[n];
    dinv[n] = rsqrtf((float)(d > 0 ? d : 1));
}

// ---------------------------------------------------------------------------
// GAT aggregation -> bf16 h (row stride 800, cols 780..799 zeroed)
// ---------------------------------------------------------------------------
__global__ __launch_bounds__(256)
void gat_agg(const float* __restrict__ xh, const float* __restrict__ a_src,
             const float* __restrict__ a_dst, const float* __restrict__ gat_b,
             const int* __restrict__ offs, const int* __restrict__ csr,
             __bf16* __restrict__ hbf)
{
    int n = blockIdx.x*4 + (threadIdx.x >> 6);
    if (n >= NN) return;
    int lane = threadIdx.x & 63;
    bool act = lane < 60;
    int h   = act ? (lane / 6) : 0;
    int sub = act ? (lane % 6) : 0;
    int cbase = h*FX + sub*13;
    int off = offs[n], end = offs[n+1];
    float adn = a_dst[n*NH + h];

    float m = -3.0e38f;
    for (int i = off; i < end; i++) {
        int s = csr[i];
        float ev = a_src[s*NH + h] + adn;
        ev = ev > 0.f ? ev : 0.2f*ev;
        m = fmaxf(m, ev);
    }
    float den = 0.f;
    float acc[13];
#pragma unroll
    for (int j = 0; j < 13; j++) acc[j] = 0.f;
    for (int i = off; i < end; i++) {
        int s = csr[i];
        float ev = a_src[s*NH + h] + adn;
        ev = ev > 0.f ? ev : 0.2f*ev;
        float ee = __expf(ev - m);
        den += ee;
        const float* xr = xh + (size_t)s*HD + cbase;
#pragma unroll
        for (int j = 0; j < 13; j++) acc[j] = fmaf(xr[j], ee, acc[j]);
    }
    if (act) {
        float inv = 1.f / den;
        const float* bb = gat_b + cbase;
        __bf16* op = hbf + (size_t)n*800 + cbase;
#pragma unroll
        for (int j = 0; j < 13; j++) {
            float v = fmaf(acc[j], inv, bb[j]);
            op[j] = (__bf16)(v > 0.f ? v : 0.f);
        }
    } else {
        // zero the K-pad cols 780..799 (20 cols, lanes 60..63 x 5)
        __bf16* op = hbf + (size_t)n*800 + 780 + (lane - 60)*5;
#pragma unroll
        for (int j = 0; j < 5; j++) op[j] = (__bf16)0.f;
    }
}

// ---------------------------------------------------------------------------
// GCN aggregation (f32 in/out, lane-strided channels)
// ---------------------------------------------------------------------------
__global__ __launch_bounds__(256)
void gcn_agg(const float* __restrict__ hw, const float* __restrict__ dinv,
             const float* __restrict__ gcn_b, const int* __restrict__ offs,
             const int* __restrict__ csr, float* __restrict__ g)
{
    int n = blockIdx.x*4 + (threadIdx.x >> 6);
    if (n >= NN) return;
    int lane = threadIdx.x & 63;
    int off = offs[n], end = offs[n+1];
    float dn = dinv[n];
    float acc[13];
#pragma unroll
    for (int j = 0; j < 13; j++) acc[j] = 0.f;
    for (int i = off; i < end; i++) {
        int s = csr[i];
        float w = dinv[s] * dn;
        const float* r = hw + (size_t)s*HD;
#pragma unroll
        for (int j = 0; j < 13; j++) {
            int c = lane + 64*j;
            if (c < HD) acc[j] = fmaf(r[c], w, acc[j]);
        }
    }
    float* op = g + (size_t)n*HD;
#pragma unroll
    for (int j = 0; j < 13; j++) {
        int c = lane + 64*j;
        if (c < HD) {
            float v = acc[j] + gcn_b[c];
            op[c] = v > 0.f ? v : 0.f;
        }
    }
}

// ---------------------------------------------------------------------------
__global__ void gstart_kernel(const int* __restrict__ batch, int* __restrict__ goffs)
{
    int b = blockIdx.x*256 + threadIdx.x;
    if (b > NG) return;
    if (b == NG) { goffs[NG] = NN; return; }
    int lo = 0, hi = NN;
    while (lo < hi) { int mid = (lo+hi) >> 1; if (batch[mid] < b) lo = mid+1; else hi = mid; }
    goffs[b] = lo;
}

// pool -> bf16 d[b][1568]: [0:780)=max, [780:1560)=mean, [1560:1568)=0
__global__ __launch_bounds__(256)
void pool_kernel(const float* __restrict__ g, const int* __restrict__ goffs,
                 __bf16* __restrict__ d)
{
    int b = blockIdx.x;
    int tid = threadIdx.x;
    int s = goffs[b], e = goffs[b+1];
    float mx[4], sm[4];
#pragma unroll
    for (int j = 0; j < 4; j++) { mx[j] = -3.0e38f; sm[j] = 0.f; }
    for (int n = s; n < e; n++) {
        const float* r = g + (size_t)n*HD;
#pragma unroll
        for (int j = 0; j < 4; j++) {
            int c = tid + 256*j;
            if (c < HD) { float v = r[c]; mx[j] = fmaxf(mx[j], v); sm[j] += v; }
        }
    }
    int cnt = e - s;
    float inv = 1.f / (float)(cnt > 0 ? cnt : 1);
#pragma unroll
    for (int j = 0; j < 4; j++) {
        int c = tid + 256*j;
        if (c < HD) {
            d[(size_t)b*1568 + c]      = (__bf16)mx[j];
            d[(size_t)b*1568 + HD + c] = (__bf16)(sm[j] * inv);
        }
    }
    if (tid < 8) d[(size_t)b*1568 + 1560 + tid] = (__bf16)0.f;
}

// ---------------------------------------------------------------------------
// Conv as implicit-GEMM MFMA. Block = 1 graph, 6 waves (wave = one 16-col
// t-tile). C[32x93] = W[32x8000] @ im2col[8000x93].
// A-frags: direct global bf16x8 from convw (contiguous, L2-hot).
// B-frags: 8 consecutive bf16 from LDS-staged emb rows (4 rows/K-step, dbuf).
// ---------------------------------------------------------------------------
__global__ __launch_bounds__(384)
void conv_mfma(const int* __restrict__ target, const float* __restrict__ emb_w,
               const __bf16* __restrict__ convw, const float* __restrict__ conv_b,
               __bf16* __restrict__ cout)
{
    __shared__ __align__(16) __bf16 ebuf[2][4][112];
    int b = blockIdx.x;
    int tid = threadIdx.x;
    int wid = tid >> 6, lane = tid & 63;
    int l15 = lane & 15, lk = lane >> 4;

    f32x4 acc0 = (f32x4){0.f,0.f,0.f,0.f};
    f32x4 acc1 = (f32x4){0.f,0.f,0.f,0.f};

    auto stage = [&](int buf, int p) {
        if (tid < 100) {
            int rr = tid / 25, q = tid % 25;
            int v = target[b*SEQ + p*4 + rr];
            float4 f = ((const float4*)(emb_w + (size_t)v*EMB))[q];
            __bf16 tmp[4] = {(__bf16)f.x, (__bf16)f.y, (__bf16)f.z, (__bf16)f.w};
            *(uint2*)&ebuf[buf][rr][q*4] = *(uint2*)tmp;
        }
    };

    stage(0, 0);
    const int t = wid*16 + l15;
    int cur = 0;
    for (int p = 0; p < SEQ/4; ++p) {
        __syncthreads();
        if (p+1 < SEQ/4) stage(cur^1, p+1);
        bf16x8 a0 = *(const bf16x8*)(convw + (size_t)l15*8000      + p*32 + lk*8);
        bf16x8 a1 = *(const bf16x8*)(convw + (size_t)(16+l15)*8000 + p*32 + lk*8);
        const __bf16* er = &ebuf[cur][lk][t];
        bf16x8 bb;
#pragma unroll
        for (int r = 0; r < 8; r++) bb[r] = er[r];
        acc0 = __builtin_amdgcn_mfma_f32_16x16x32_bf16(a0, bb, acc0, 0, 0, 0);
        acc1 = __builtin_amdgcn_mfma_f32_16x16x32_bf16(a1, bb, acc1, 0, 0, 0);
        cur ^= 1;
    }
    if (t < CLEN) {
#pragma unroll
        for (int r = 0; r < 4; r++) {
            int o = lk*4 + r;
            cout[(size_t)b*(NF*CLEN) + o*CLEN + t] = (__bf16)(acc0[r] + conv_b[o]);
        }
#pragma unroll
        for (int r = 0; r < 4; r++) {
            int o = 16 + lk*4 + r;
            cout[(size_t)b*(NF*CLEN) + o*CLEN + t] = (__bf16)(acc1[r] + conv_b[o]);
        }
    }
}

// ---------------------------------------------------------------------------
// mlp3: out[r] = dot(o2bf[r,0:512], w) + b   (wave per row)
// ---------------------------------------------------------------------------
__global__ __launch_bounds__(256)
void mlp3_dot(const __bf16* __restrict__ o2, const float* __restrict__ w,
              const float* __restrict__ bias, float* __restrict__ out)
{
    int row = blockIdx.x*4 + (threadIdx.x >> 6);
    int lane = threadIdx.x & 63;
    bf16x8 v = *(const bf16x8*)(o2 + (size_t)row*512 + lane*8);
    float4 w0 = *(const float4*)(w + lane*8);
    float4 w1 = *(const float4*)(w + lane*8 + 4);
    float s = (float)v[0]*w0.x + (float)v[1]*w0.y + (float)v[2]*w0.z + (float)v[3]*w0.w
            + (float)v[4]*w1.x + (float)v[5]*w1.y + (float)v[6]*w1.z + (float)v[7]*w1.w;
#pragma unroll
    for (int off = 32; off > 0; off >>= 1) s += __shfl_down(s, off);
    if (lane == 0) out[row] = s + bias[0];
}

// ---------------------------------------------------------------------------
extern "C" void kernel_launch(void* const* d_in, const int* in_sizes, int n_in,
                              void* d_out, int out_size, void* d_ws, size_t ws_size,
                              hipStream_t stream)
{
    const float* x      = (const float*)d_in[0];
    const int*   ei     = (const int*)  d_in[1];
    const int*   batch  = (const int*)  d_in[2];
    const int*   target = (const int*)  d_in[3];
    const float* gat_w  = (const float*)d_in[4];
    const float* att_s  = (const float*)d_in[5];
    const float* att_d  = (const float*)d_in[6];
    const float* gat_b  = (const float*)d_in[7];
    const float* gcn_w  = (const float*)d_in[8];
    const float* gcn_b  = (const float*)d_in[9];
    const float* fcg1_w = (const float*)d_in[10];
    const float* fcg1_b = (const float*)d_in[11];
    const float* fcg2_w = (const float*)d_in[12];
    const float* fcg2_b = (const float*)d_in[13];
    const float* emb_w  = (const float*)d_in[14];
    const float* conv_w = (const float*)d_in[15];
    const float* conv_b = (const float*)d_in[16];
    const float* fcxt_w = (const float*)d_in[17];
    const float* fcxt_b = (const float*)d_in[18];
    const float* mlp1_w = (const float*)d_in[19];
    const float* mlp1_b = (const float*)d_in[20];
    const float* mlp2_w = (const float*)d_in[21];
    const float* mlp2_b = (const float*)d_in[22];
    const float* mlp3_w = (const float*)d_in[23];
    const float* mlp3_b = (const float*)d_in[24];
    float* out = (float*)d_out;

    char* ws = (char*)d_ws;
    size_t off = 0;
    auto alloc = [&](size_t bytes) -> char* {
        char* p = ws + off;
        off = (off + bytes + 255) & ~(size_t)255;
        return p;
    };
    float* xh     = (float*)alloc((size_t)NN*HD*4);    // reused as hw
    float* g      = (float*)alloc((size_t)NN*HD*4);
    char*  hbf_rg = alloc((size_t)NN*800*2);           // Abf (x bf16) then hbf
    __bf16* Abf   = (__bf16*)hbf_rg;                   // NN*96 (subset, dead before hbf written)
    __bf16* hbf   = (__bf16*)hbf_rg;
    __bf16* Btbf  = (__bf16*)alloc((size_t)896*800*2); // gat/gcn weight (sequential reuse)
    __bf16* wbt   = (__bf16*)alloc((size_t)1536*1568*2); // FC weights (sequential reuse)
    __bf16* convwb= (__bf16*)alloc((size_t)NF*SEQ*KS*2);
    float* a_src  = (float*)alloc((size_t)NN*NH*4);
    float* a_dst  = (float*)alloc((size_t)NN*NH*4);
    int*   deg    = (int*)alloc((size_t)NN*4);
    int*   offs   = (int*)alloc((size_t)(NN+1)*4);
    int*   cursor = (int*)alloc((size_t)NN*4);
    int*   csr    = (int*)alloc((size_t)NT*4);
    float* dinv   = (float*)alloc((size_t)NN*4);
    int*   goffs  = (int*)alloc((size_t)(NG+1)*4);
    __bf16* dpool = (__bf16*)alloc((size_t)NG*1568*2);
    __bf16* d1bf  = (__bf16*)alloc((size_t)NG*1504*2);
    __bf16* cbuf  = (__bf16*)alloc((size_t)NG*NF*CLEN*2);
    __bf16* obuf  = (__bf16*)alloc((size_t)NG*256*2);
    __bf16* o1bf  = (__bf16*)alloc((size_t)NG*1024*2);
    __bf16* o2bf  = (__bf16*)alloc((size_t)NG*512*2);

    float* hw = xh;   // xh dead after gat_agg

    hipMemsetAsync(deg, 0, (size_t)NN*4, stream);

    // --- GAT linear: xh = x @ gat_w (bf16 MFMA, Kp=96), f32 out ---
    cast_pad_a <<<dim3((NN*96)/256), 256, 0, stream>>>(x, Abf, NN, FX, 96);
    cast_pad_bt<<<dim3((896*96)/256), 256, 0, stream>>>(gat_w, Btbf, FX, HD, 96, 896);
    gemm_mfma<false,false,false>
        <<<dim3(7, NN/128), 256, 0, stream>>>(Abf, Btbf, nullptr, xh, NN, HD, 96, HD, HD);
    attn_logits<<<dim3((NN*NH+255)/256), 256, 0, stream>>>(xh, att_s, att_d, a_src, a_dst);

    // --- CSR ---
    edge_count  <<<dim3(NT/256), 256, 0, stream>>>(ei, deg);
    scan_kernel <<<1, 1024, 0, stream>>>(deg, offs, cursor);
    edge_scatter<<<dim3(NT/256), 256, 0, stream>>>(ei, cursor, csr);
    dinv_kernel <<<dim3(NN/256), 256, 0, stream>>>(offs, dinv);

    // --- GAT aggregate -> hbf (bf16, stride 800) ---
    gat_agg<<<dim3(NN/4), 256, 0, stream>>>(xh, a_src, a_dst, gat_b, offs, csr, hbf);

    // --- GCN linear: hw = h @ gcn_w (Kp=800), f32 out; aggregate -> g ---
    cast_pad_bt<<<dim3((896*800)/256), 256, 0, stream>>>(gcn_w, Btbf, HD, HD, 800, 896);
    gemm_mfma<false,false,false>
        <<<dim3(7, NN/128), 256, 0, stream>>>(hbf, Btbf, nullptr, hw, NN, HD, 800, HD, HD);
    gcn_agg<<<dim3(NN/4), 256, 0, stream>>>(hw, dinv, gcn_b, offs, csr, g);

    // --- pooling -> dpool bf16 (stride 1568) ---
    gstart_kernel<<<3, 256, 0, stream>>>(batch, goffs);
    pool_kernel<<<NG, 256, 0, stream>>>(g, goffs, dpool);

    // --- graph FC: d1 = relu(d@fcg1+b) [bf16, stride 1504]; obuf[:,0:128] ---
    cast_pad_bt<<<dim3((1536*1568)/256), 256, 0, stream>>>(fcg1_w, wbt, 1560, 1500, 1568, 1536);
    gemm_mfma<true,true,true>
        <<<dim3(12, 4), 256, 0, stream>>>(dpool, wbt, fcg1_b, d1bf, NG, 1500, 1568, 1504, 1504);
    cast_pad_bt<<<dim3((128*1504)/256), 256, 0, stream>>>(fcg2_w, wbt, 1500, 128, 1504, 128);
    gemm_mfma<true,false,true>
        <<<dim3(1, 4), 256, 0, stream>>>(d1bf, wbt, fcg2_b, obuf, NG, 128, 1504, 256, 128);

    // --- protein branch: conv (MFMA) -> cbuf bf16; obuf[:,128:256] ---
    cast_pad_a<<<dim3((NF*SEQ*KS)/256), 256, 0, stream>>>(conv_w, convwb, NF, SEQ*KS, SEQ*KS);
    conv_mfma<<<NG, 384, 0, stream>>>(target, emb_w, convwb, conv_b, cbuf);
    cast_pad_bt<<<dim3((128*2976)/256), 256, 0, stream>>>(fcxt_w, wbt, NF*CLEN, 128, 2976, 128);
    gemm_mfma<true,false,true>
        <<<dim3(1, 4), 256, 0, stream>>>(cbuf, wbt, fcxt_b, obuf + 128, NG, 128, 2976, 256, 128);

    // --- MLP head ---
    cast_pad_bt<<<dim3((1024*256)/256), 256, 0, stream>>>(mlp1_w, wbt, 256, 1024, 256, 1024);
    gemm_mfma<true,true,true>
        <<<dim3(8, 4), 256, 0, stream>>>(obuf, wbt, mlp1_b, o1bf, NG, 1024, 256, 1024, 1024);
    cast_pad_bt<<<dim3((512*1024)/256), 256, 0, stream>>>(mlp2_w, wbt, 1024, 512, 1024, 512);
    gemm_mfma<true,true,true>
        <<<dim3(4, 4), 256, 0, stream>>>(o1bf, wbt, mlp2_b, o2bf, NG, 512, 1024, 512, 512);
    mlp3_dot<<<dim3(NG/4), 256, 0, stream>>>(o2bf, mlp3_w, mlp3_b, out);
}

// Round 4
// 622.542 us; speedup vs baseline: 4.3698x; 1.2188x over previous
//
#include <hip/hip_runtime.h>

#define NN 16384      // nodes
#define NE 65536      // edges
#define NT 81920      // edges + self loops
#define NG 512        // graphs
#define NH 10         // heads
#define FX 78         // features per head
#define HD 780        // hidden = NH*FX
#define SEQ 1000
#define EMB 100
#define NF 32
#define KS 8
#define CLEN 93

typedef __bf16 bf16x8 __attribute__((ext_vector_type(8)));
typedef float  f32x4  __attribute__((ext_vector_type(4)));

// ---------------------------------------------------------------------------
// bf16 cast + pad helpers
// ---------------------------------------------------------------------------
__global__ __launch_bounds__(256)
void cast_pad_a(const float* __restrict__ in, __bf16* __restrict__ out,
                int M, int K, int Kp)
{
    size_t idx = (size_t)blockIdx.x*256 + threadIdx.x;
    if (idx >= (size_t)M*Kp) return;
    int r = idx / Kp, c = idx % Kp;
    out[idx] = (c < K) ? (__bf16)in[(size_t)r*K + c] : (__bf16)0.f;
}

// B[K,N] -> Bt[Np][Kp] (transposed, zero-padded)
__global__ __launch_bounds__(256)
void cast_pad_bt(const float* __restrict__ B, __bf16* __restrict__ out,
                 int K, int N, int Kp, int Np)
{
    size_t idx = (size_t)blockIdx.x*256 + threadIdx.x;
    if (idx >= (size_t)Np*Kp) return;
    int n = idx / Kp, k = idx % Kp;
    out[idx] = (n < N && k < K) ? (__bf16)B[(size_t)k*N + n] : (__bf16)0.f;
}

// ---------------------------------------------------------------------------
// bf16 MFMA GEMM: C[M,ldc] = A[M,Kp] @ Bt[Np,Kp]^T  (+bias)(+relu)
// 128x128 tile, 4 waves. Store f32 or bf16. For bf16 store, cols [N,Nz)
// are written as ZERO (K-padding for the next layer).
// ---------------------------------------------------------------------------
#define BKP 40
template<bool BIAS, bool RELU, bool BF16OUT>
__global__ __launch_bounds__(256)
void gemm_mfma(const __bf16* __restrict__ A, const __bf16* __restrict__ Bt,
               const float* __restrict__ bias, void* __restrict__ Cv,
               int M, int N, int Kp, int ldc, int Nz)
{
    __shared__ __align__(16) __bf16 As[128*BKP];
    __shared__ __align__(16) __bf16 Bs[128*BKP];
    const int tid = threadIdx.x;
    const int row0 = blockIdx.y*128, col0 = blockIdx.x*128;
    const int lane = tid & 63, wid = tid >> 6;
    const int wm = wid & 1, wn = wid >> 1;
    const int l15 = lane & 15, lk = lane >> 4;

    f32x4 acc[4][4];
#pragma unroll
    for (int i = 0; i < 4; i++)
#pragma unroll
        for (int j = 0; j < 4; j++) acc[i][j] = (f32x4){0.f,0.f,0.f,0.f};

    for (int k0 = 0; k0 < Kp; k0 += 32) {
        __syncthreads();
#pragma unroll
        for (int it = 0; it < 2; ++it) {
            int c = tid + it*256;
            int r = c >> 2, c16 = c & 3;
            uint4 va = *(const uint4*)(A  + (size_t)(row0+r)*Kp + k0 + c16*8);
            *(uint4*)&As[r*BKP + c16*8] = va;
            uint4 vb = *(const uint4*)(Bt + (size_t)(col0+r)*Kp + k0 + c16*8);
            *(uint4*)&Bs[r*BKP + c16*8] = vb;
        }
        __syncthreads();
        bf16x8 af[4], bfr[4];
#pragma unroll
        for (int i = 0; i < 4; i++) {
            af[i]  = *(const bf16x8*)&As[(wm*64 + i*16 + l15)*BKP + lk*8];
            bfr[i] = *(const bf16x8*)&Bs[(wn*64 + i*16 + l15)*BKP + lk*8];
        }
#pragma unroll
        for (int i = 0; i < 4; i++)
#pragma unroll
            for (int j = 0; j < 4; j++)
                acc[i][j] = __builtin_amdgcn_mfma_f32_16x16x32_bf16(af[i], bfr[j], acc[i][j], 0, 0, 0);
    }

#pragma unroll
    for (int i = 0; i < 4; i++) {
        int rbase = row0 + wm*64 + i*16 + lk*4;
#pragma unroll
        for (int j = 0; j < 4; j++) {
            int cc = col0 + wn*64 + j*16 + l15;
            if (cc >= Nz) continue;
            bool real = cc < N;
            float bv = (BIAS && real) ? bias[cc] : 0.f;
#pragma unroll
            for (int r = 0; r < 4; r++) {
                float v = real ? (acc[i][j][r] + bv) : 0.f;
                if (RELU) v = v > 0.f ? v : 0.f;
                if (BF16OUT) ((__bf16*)Cv)[(size_t)(rbase + r)*ldc + cc] = (__bf16)v;
                else         ((float*) Cv)[(size_t)(rbase + r)*ldc + cc] = v;
            }
        }
    }
}

// ---------------------------------------------------------------------------
// a_src[n,h], a_dst[n,h] from xh
// ---------------------------------------------------------------------------
__global__ __launch_bounds__(256)
void attn_logits(const float* __restrict__ xh, const float* __restrict__ att_s,
                 const float* __restrict__ att_d,
                 float* __restrict__ a_src, float* __restrict__ a_dst)
{
    int idx = blockIdx.x*256 + threadIdx.x;
    if (idx >= NN*NH) return;
    int n = idx / NH, h = idx % NH;
    const float* xr = xh + (size_t)n*HD + h*FX;
    const float* as = att_s + h*FX;
    const float* ad = att_d + h*FX;
    float s1 = 0.f, s2 = 0.f;
    for (int c = 0; c < FX; c++) {
        float v = xr[c];
        s1 = fmaf(v, as[c], s1);
        s2 = fmaf(v, ad[c], s2);
    }
    a_src[idx] = s1;
    a_dst[idx] = s2;
}

// ---------------------------------------------------------------------------
// CSR build
// ---------------------------------------------------------------------------
__global__ void edge_count(const int* __restrict__ ei, int* __restrict__ deg)
{
    int e = blockIdx.x*256 + threadIdx.x;
    if (e >= NT) return;
    int dst = (e < NE) ? ei[NE + e] : (e - NE);
    atomicAdd(&deg[dst], 1);
}

__global__ __launch_bounds__(1024)
void scan_kernel(const int* __restrict__ deg, int* __restrict__ offs, int* __restrict__ cursor)
{
    __shared__ int part[1024];
    int tid = threadIdx.x;
    int base = tid*16;
    int v[16]; int ssum = 0;
#pragma unroll
    for (int j = 0; j < 16; j++) { v[j] = deg[base+j]; ssum += v[j]; }
    part[tid] = ssum;
    __syncthreads();
    for (int d = 1; d < 1024; d <<= 1) {
        int t = (tid >= d) ? part[tid-d] : 0;
        __syncthreads();
        part[tid] += t;
        __syncthreads();
    }
    int run = (tid == 0) ? 0 : part[tid-1];
#pragma unroll
    for (int j = 0; j < 16; j++) { offs[base+j] = run; cursor[base+j] = run; run += v[j]; }
    if (tid == 1023) offs[NN] = run;
}

__global__ void edge_scatter(const int* __restrict__ ei, int* __restrict__ cursor,
                             int* __restrict__ csr)
{
    int e = blockIdx.x*256 + threadIdx.x;
    if (e >= NT) return;
    int src, dst;
    if (e < NE) { src = ei[e]; dst = ei[NE + e]; }
    else        { src = e - NE; dst = e - NE; }
    int pos = atomicAdd(&cursor[dst], 1);
    csr[pos] = src;
}

__global__ void dinv_kernel(const int* __restrict__ offs, float* __restrict__ dinv)
{
    int n = blockIdx.x*256 + threadIdx.x;
    if (n >= NN) return;
    int d = offs[n+1] - offs[n];
    dinv[n] = rsqrtf((float)(d > 0 ? d : 1));
}

// ---------------------------------------------------------------------------
// GAT aggregation -> bf16 h (row stride 800, cols 780..799 zeroed)
// ---------------------------------------------------------------------------
__global__ __launch_bounds__(256)
void gat_agg(const float* __restrict__ xh, const float* __restrict__ a_src,
             const float* __restrict__ a_dst, const float* __restrict__ gat_b,
             const int* __restrict__ offs, const int* __restrict__ csr,
             __bf16* __restrict__ hbf)
{
    int n = blockIdx.x*4 + (threadIdx.x >> 6);
    if (n >= NN) return;
    int lane = threadIdx.x & 63;
    bool act = lane < 60;
    int h   = act ? (lane / 6) : 0;
    int sub = act ? (lane % 6) : 0;
    int cbase = h*FX + sub*13;
    int off = offs[n], end = offs[n+1];
    float adn = a_dst[n*NH + h];

    float m = -3.0e38f;
    for (int i = off; i < end; i++) {
        int s = csr[i];
        float ev = a_src[s*NH + h] + adn;
        ev = ev > 0.f ? ev : 0.2f*ev;
        m = fmaxf(m, ev);
    }
    float den = 0.f;
    float acc[13];
#pragma unroll
    for (int j = 0; j < 13; j++) acc[j] = 0.f;
    for (int i = off; i < end; i++) {
        int s = csr[i];
        float ev = a_src[s*NH + h] + adn;
        ev = ev > 0.f ? ev : 0.2f*ev;
        float ee = __expf(ev - m);
        den += ee;
        const float* xr = xh + (size_t)s*HD + cbase;
#pragma unroll
        for (int j = 0; j < 13; j++) acc[j] = fmaf(xr[j], ee, acc[j]);
    }
    if (act) {
        float inv = 1.f / den;
        const float* bb = gat_b + cbase;
        __bf16* op = hbf + (size_t)n*800 + cbase;
#pragma unroll
        for (int j = 0; j < 13; j++) {
            float v = fmaf(acc[j], inv, bb[j]);
            op[j] = (__bf16)(v > 0.f ? v : 0.f);
        }
    } else {
        // zero the K-pad cols 780..799 (20 cols, lanes 60..63 x 5)
        __bf16* op = hbf + (size_t)n*800 + 780 + (lane - 60)*5;
#pragma unroll
        for (int j = 0; j < 5; j++) op[j] = (__bf16)0.f;
    }
}

// ---------------------------------------------------------------------------
// GCN aggregation (f32 in/out, lane-strided channels)
// ---------------------------------------------------------------------------
__global__ __launch_bounds__(256)
void gcn_agg(const float* __restrict__ hw, const float* __restrict__ dinv,
             const float* __restrict__ gcn_b, const int* __restrict__ offs,
             const int* __restrict__ csr, float* __restrict__ g)
{
    int n = blockIdx.x*4 + (threadIdx.x >> 6);
    if (n >= NN) return;
    int lane = threadIdx.x & 63;
    int off = offs[n], end = offs[n+1];
    float dn = dinv[n];
    float acc[13];
#pragma unroll
    for (int j = 0; j < 13; j++) acc[j] = 0.f;
    for (int i = off; i < end; i++) {
        int s = csr[i];
        float w = dinv[s] * dn;
        const float* r = hw + (size_t)s*HD;
#pragma unroll
        for (int j = 0; j < 13; j++) {
            int c = lane + 64*j;
            if (c < HD) acc[j] = fmaf(r[c], w, acc[j]);
        }
    }
    float* op = g + (size_t)n*HD;
#pragma unroll
    for (int j = 0; j < 13; j++) {
        int c = lane + 64*j;
        if (c < HD) {
            float v = acc[j] + gcn_b[c];
            op[c] = v > 0.f ? v : 0.f;
        }
    }
}

// ---------------------------------------------------------------------------
__global__ void gstart_kernel(const int* __restrict__ batch, int* __restrict__ goffs)
{
    int b = blockIdx.x*256 + threadIdx.x;
    if (b > NG) return;
    if (b == NG) { goffs[NG] = NN; return; }
    int lo = 0, hi = NN;
    while (lo < hi) { int mid = (lo+hi) >> 1; if (batch[mid] < b) lo = mid+1; else hi = mid; }
    goffs[b] = lo;
}

// pool -> bf16 d[b][1568]: [0:780)=max, [780:1560)=mean, [1560:1568)=0
__global__ __launch_bounds__(256)
void pool_kernel(const float* __restrict__ g, const int* __restrict__ goffs,
                 __bf16* __restrict__ d)
{
    int b = blockIdx.x;
    int tid = threadIdx.x;
    int s = goffs[b], e = goffs[b+1];
    float mx[4], sm[4];
#pragma unroll
    for (int j = 0; j < 4; j++) { mx[j] = -3.0e38f; sm[j] = 0.f; }
    for (int n = s; n < e; n++) {
        const float* r = g + (size_t)n*HD;
#pragma unroll
        for (int j = 0; j < 4; j++) {
            int c = tid + 256*j;
            if (c < HD) { float v = r[c]; mx[j] = fmaxf(mx[j], v); sm[j] += v; }
        }
    }
    int cnt = e - s;
    float inv = 1.f / (float)(cnt > 0 ? cnt : 1);
#pragma unroll
    for (int j = 0; j < 4; j++) {
        int c = tid + 256*j;
        if (c < HD) {
            d[(size_t)b*1568 + c]      = (__bf16)mx[j];
            d[(size_t)b*1568 + HD + c] = (__bf16)(sm[j] * inv);
        }
    }
    if (tid < 8) d[(size_t)b*1568 + 1560 + tid] = (__bf16)0.f;
}

// ---------------------------------------------------------------------------
// Conv restructured: W'[(k*32+o), i] = conv_w[o,i,k], padded K 1000->1024.
// P_b[256,100] = W' @ emb_b ; then c[b,o,t] = sum_k P_b[k*32+o, t+k] + bias.
// ---------------------------------------------------------------------------
__global__ __launch_bounds__(256)
void conv_w_repack(const float* __restrict__ conv_w, __bf16* __restrict__ w2)
{
    int idx = blockIdx.x*256 + threadIdx.x;   // o'*1024 + i
    if (idx >= 256*1024) return;
    int op = idx >> 10, i = idx & 1023;
    int o = op & 31, k = op >> 5;
    w2[idx] = (i < SEQ) ? (__bf16)conv_w[((size_t)o*SEQ + i)*KS + k] : (__bf16)0.f;
}

// Block = 1 graph, 512 threads (8 waves). Wave w owns rows w*32..w*32+31.
// B staged in LDS as Bs[col=112][k=40(pad)] bf16, dbuf; B-frag = ds_read_b128.
// A-frags direct global bf16x8 (L2-hot 512KB), prefetched one phase ahead.
__global__ __launch_bounds__(512)
void conv_gemm(const int* __restrict__ target, const float* __restrict__ emb_w,
               const __bf16* __restrict__ w2, __bf16* __restrict__ P)
{
    __shared__ __align__(16) __bf16 Bs[2][112*40];
    const int b = blockIdx.x;
    const int tid = threadIdx.x;
    const int w = tid >> 6, lane = tid & 63;
    const int l15 = lane & 15, lk = lane >> 4;
    const int sr = tid & 31, sc0 = (tid >> 5) * 7;   // stage: row sr, cols sc0..sc0+6

    auto stage = [&](int buf, int p) {
        int i = p*32 + sr;
        const float* er = emb_w + (size_t)((i < SEQ) ? target[b*SEQ + i] : 0) * EMB;
        bool live = (i < SEQ);
#pragma unroll
        for (int q = 0; q < 7; q++) {
            int c = sc0 + q;
            float f = (live && c < EMB) ? er[c] : 0.f;
            Bs[buf][c*40 + sr] = (__bf16)f;
        }
    };

    f32x4 acc[2][7];
#pragma unroll
    for (int i = 0; i < 2; i++)
#pragma unroll
        for (int j = 0; j < 7; j++) acc[i][j] = (f32x4){0.f,0.f,0.f,0.f};

    const __bf16* arow0 = w2 + (size_t)(w*32 + l15)*1024 + lk*8;
    const __bf16* arow1 = arow0 + 16*1024;
    stage(0, 0);
    bf16x8 a0 = *(const bf16x8*)(arow0);
    bf16x8 a1 = *(const bf16x8*)(arow1);
    int cur = 0;
    for (int p = 0; p < 32; ++p) {
        __syncthreads();
        bf16x8 a0n = a0, a1n = a1;
        if (p+1 < 32) {
            stage(cur^1, p+1);
            a0n = *(const bf16x8*)(arow0 + (p+1)*32);
            a1n = *(const bf16x8*)(arow1 + (p+1)*32);
        }
        bf16x8 bfv[7];
#pragma unroll
        for (int j = 0; j < 7; j++)
            bfv[j] = *(const bf16x8*)&Bs[cur][(j*16 + l15)*40 + lk*8];
#pragma unroll
        for (int j = 0; j < 7; j++) {
            acc[0][j] = __builtin_amdgcn_mfma_f32_16x16x32_bf16(a0, bfv[j], acc[0][j], 0, 0, 0);
            acc[1][j] = __builtin_amdgcn_mfma_f32_16x16x32_bf16(a1, bfv[j], acc[1][j], 0, 0, 0);
        }
        a0 = a0n; a1 = a1n;
        cur ^= 1;
    }
#pragma unroll
    for (int i = 0; i < 2; i++) {
        int row = w*32 + i*16 + lk*4;
#pragma unroll
        for (int j = 0; j < 7; j++) {
            int col = j*16 + l15;
#pragma unroll
            for (int r = 0; r < 4; r++)
                P[((size_t)b*256 + row + r)*112 + col] = (__bf16)acc[i][j][r];
        }
    }
}

// c[b,o,t] = sum_k P[b][k*32+o][t+k] + conv_b[o]  -> cbuf[b][o*93+t] bf16
__global__ __launch_bounds__(256)
void shift_add(const __bf16* __restrict__ P, const float* __restrict__ conv_b,
               __bf16* __restrict__ cbuf)
{
    int b = blockIdx.x;
    int tid = threadIdx.x;
    int o = tid >> 3;
    int t0 = (tid & 7) * 12;
    float cb = conv_b[o];
#pragma unroll
    for (int j = 0; j < 12; j++) {
        int t = t0 + j;
        if (t >= CLEN) continue;
        float s = cb;
#pragma unroll
        for (int k = 0; k < 8; k++)
            s += (float)P[((size_t)b*256 + k*32 + o)*112 + t + k];
        cbuf[(size_t)b*2976 + o*CLEN + t] = (__bf16)s;
    }
}

// ---------------------------------------------------------------------------
// mlp3: out[r] = dot(o2bf[r,0:512], w) + b   (wave per row)
// ---------------------------------------------------------------------------
__global__ __launch_bounds__(256)
void mlp3_dot(const __bf16* __restrict__ o2, const float* __restrict__ w,
              const float* __restrict__ bias, float* __restrict__ out)
{
    int row = blockIdx.x*4 + (threadIdx.x >> 6);
    int lane = threadIdx.x & 63;
    bf16x8 v = *(const bf16x8*)(o2 + (size_t)row*512 + lane*8);
    float4 w0 = *(const float4*)(w + lane*8);
    float4 w1 = *(const float4*)(w + lane*8 + 4);
    float s = (float)v[0]*w0.x + (float)v[1]*w0.y + (float)v[2]*w0.z + (float)v[3]*w0.w
            + (float)v[4]*w1.x + (float)v[5]*w1.y + (float)v[6]*w1.z + (float)v[7]*w1.w;
#pragma unroll
    for (int off = 32; off > 0; off >>= 1) s += __shfl_down(s, off);
    if (lane == 0) out[row] = s + bias[0];
}

// ---------------------------------------------------------------------------
extern "C" void kernel_launch(void* const* d_in, const int* in_sizes, int n_in,
                              void* d_out, int out_size, void* d_ws, size_t ws_size,
                              hipStream_t stream)
{
    const float* x      = (const float*)d_in[0];
    const int*   ei     = (const int*)  d_in[1];
    const int*   batch  = (const int*)  d_in[2];
    const int*   target = (const int*)  d_in[3];
    const float* gat_w  = (const float*)d_in[4];
    const float* att_s  = (const float*)d_in[5];
    const float* att_d  = (const float*)d_in[6];
    const float* gat_b  = (const float*)d_in[7];
    const float* gcn_w  = (const float*)d_in[8];
    const float* gcn_b  = (const float*)d_in[9];
    const float* fcg1_w = (const float*)d_in[10];
    const float* fcg1_b = (const float*)d_in[11];
    const float* fcg2_w = (const float*)d_in[12];
    const float* fcg2_b = (const float*)d_in[13];
    const float* emb_w  = (const float*)d_in[14];
    const float* conv_w = (const float*)d_in[15];
    const float* conv_b = (const float*)d_in[16];
    const float* fcxt_w = (const float*)d_in[17];
    const float* fcxt_b = (const float*)d_in[18];
    const float* mlp1_w = (const float*)d_in[19];
    const float* mlp1_b = (const float*)d_in[20];
    const float* mlp2_w = (const float*)d_in[21];
    const float* mlp2_b = (const float*)d_in[22];
    const float* mlp3_w = (const float*)d_in[23];
    const float* mlp3_b = (const float*)d_in[24];
    float* out = (float*)d_out;

    char* ws = (char*)d_ws;
    size_t off = 0;
    auto alloc = [&](size_t bytes) -> char* {
        char* p = ws + off;
        off = (off + bytes + 255) & ~(size_t)255;
        return p;
    };
    float* xh     = (float*)alloc((size_t)NN*HD*4);    // reused as hw, then as P
    float* g      = (float*)alloc((size_t)NN*HD*4);
    char*  hbf_rg = alloc((size_t)NN*800*2);           // Abf (x bf16) then hbf
    __bf16* Abf   = (__bf16*)hbf_rg;                   // NN*96 (dead before hbf written)
    __bf16* hbf   = (__bf16*)hbf_rg;
    __bf16* Btbf  = (__bf16*)alloc((size_t)896*800*2); // gat/gcn weight (sequential reuse)
    __bf16* wbt   = (__bf16*)alloc((size_t)1536*1568*2); // FC weights (sequential reuse)
    __bf16* convw2= (__bf16*)alloc((size_t)256*1024*2);
    float* a_src  = (float*)alloc((size_t)NN*NH*4);
    float* a_dst  = (float*)alloc((size_t)NN*NH*4);
    int*   deg    = (int*)alloc((size_t)NN*4);
    int*   offs   = (int*)alloc((size_t)(NN+1)*4);
    int*   cursor = (int*)alloc((size_t)NN*4);
    int*   csr    = (int*)alloc((size_t)NT*4);
    float* dinv   = (float*)alloc((size_t)NN*4);
    int*   goffs  = (int*)alloc((size_t)(NG+1)*4);
    __bf16* dpool = (__bf16*)alloc((size_t)NG*1568*2);
    __bf16* d1bf  = (__bf16*)alloc((size_t)NG*1504*2);
    __bf16* cbuf  = (__bf16*)alloc((size_t)NG*NF*CLEN*2);
    __bf16* obuf  = (__bf16*)alloc((size_t)NG*256*2);
    __bf16* o1bf  = (__bf16*)alloc((size_t)NG*1024*2);
    __bf16* o2bf  = (__bf16*)alloc((size_t)NG*512*2);

    float* hw = xh;              // xh dead after gat_agg
    __bf16* Pbuf = (__bf16*)xh;  // hw dead after gcn_agg (NG*256*112*2 = 29MB < 51MB)

    hipMemsetAsync(deg, 0, (size_t)NN*4, stream);

    // --- GAT linear: xh = x @ gat_w (bf16 MFMA, Kp=96), f32 out ---
    cast_pad_a <<<dim3((NN*96)/256), 256, 0, stream>>>(x, Abf, NN, FX, 96);
    cast_pad_bt<<<dim3((896*96)/256), 256, 0, stream>>>(gat_w, Btbf, FX, HD, 96, 896);
    gemm_mfma<false,false,false>
        <<<dim3(7, NN/128), 256, 0, stream>>>(Abf, Btbf, nullptr, xh, NN, HD, 96, HD, HD);
    attn_logits<<<dim3((NN*NH+255)/256), 256, 0, stream>>>(xh, att_s, att_d, a_src, a_dst);

    // --- CSR ---
    edge_count  <<<dim3(NT/256), 256, 0, stream>>>(ei, deg);
    scan_kernel <<<1, 1024, 0, stream>>>(deg, offs, cursor);
    edge_scatter<<<dim3(NT/256), 256, 0, stream>>>(ei, cursor, csr);
    dinv_kernel <<<dim3(NN/256), 256, 0, stream>>>(offs, dinv);

    // --- GAT aggregate -> hbf (bf16, stride 800) ---
    gat_agg<<<dim3(NN/4), 256, 0, stream>>>(xh, a_src, a_dst, gat_b, offs, csr, hbf);

    // --- GCN linear: hw = h @ gcn_w (Kp=800), f32 out; aggregate -> g ---
    cast_pad_bt<<<dim3((896*800)/256), 256, 0, stream>>>(gcn_w, Btbf, HD, HD, 800, 896);
    gemm_mfma<false,false,false>
        <<<dim3(7, NN/128), 256, 0, stream>>>(hbf, Btbf, nullptr, hw, NN, HD, 800, HD, HD);
    gcn_agg<<<dim3(NN/4), 256, 0, stream>>>(hw, dinv, gcn_b, offs, csr, g);

    // --- pooling -> dpool bf16 (stride 1568) ---
    gstart_kernel<<<3, 256, 0, stream>>>(batch, goffs);
    pool_kernel<<<NG, 256, 0, stream>>>(g, goffs, dpool);

    // --- graph FC: d1 = relu(d@fcg1+b) [bf16, stride 1504]; obuf[:,0:128] ---
    cast_pad_bt<<<dim3((1536*1568)/256), 256, 0, stream>>>(fcg1_w, wbt, 1560, 1500, 1568, 1536);
    gemm_mfma<true,true,true>
        <<<dim3(12, 4), 256, 0, stream>>>(dpool, wbt, fcg1_b, d1bf, NG, 1500, 1568, 1504, 1504);
    cast_pad_bt<<<dim3((128*1504)/256), 256, 0, stream>>>(fcg2_w, wbt, 1500, 128, 1504, 128);
    gemm_mfma<true,false,true>
        <<<dim3(1, 4), 256, 0, stream>>>(d1bf, wbt, fcg2_b, obuf, NG, 128, 1504, 256, 128);

    // --- protein branch: conv as batched GEMM + shift-add (after gcn_agg: Pbuf aliases hw) ---
    conv_w_repack<<<dim3(1024), 256, 0, stream>>>(conv_w, convw2);
    conv_gemm<<<dim3(NG), 512, 0, stream>>>(target, emb_w, convw2, Pbuf);
    shift_add<<<dim3(NG), 256, 0, stream>>>(Pbuf, conv_b, cbuf);
    cast_pad_bt<<<dim3((128*2976)/256), 256, 0, stream>>>(fcxt_w, wbt, NF*CLEN, 128, 2976, 128);
    gemm_mfma<true,false,true>
        <<<dim3(1, 4), 256, 0, stream>>>(cbuf, wbt, fcxt_b, obuf + 128, NG, 128, 2976, 256, 128);

    // --- MLP head ---
    cast_pad_bt<<<dim3((1024*256)/256), 256, 0, stream>>>(mlp1_w, wbt, 256, 1024, 256, 1024);
    gemm_mfma<true,true,true>
        <<<dim3(8, 4), 256, 0, stream>>>(obuf, wbt, mlp1_b, o1bf, NG, 1024, 256, 1024, 1024);
    cast_pad_bt<<<dim3((512*1024)/256), 256, 0, stream>>>(mlp2_w, wbt, 1024, 512, 1024, 512);
    gemm_mfma<true,true,true>
        <<<dim3(4, 4), 256, 0, stream>>>(o1bf, wbt, mlp2_b, o2bf, NG, 512, 1024, 512, 512);
    mlp3_dot<<<dim3(NG/4), 256, 0, stream>>>(o2bf, mlp3_w, mlp3_b, out);
}

// Round 5
// 510.253 us; speedup vs baseline: 5.3314x; 1.2201x over previous
//
#include <hip/hip_runtime.h>

#define NN 16384      // nodes
#define NE 65536      // edges
#define NT 81920      // edges + self loops
#define NG 512        // graphs
#define NH 10         // heads
#define FX 78         // features per head
#define HD 780        // hidden = NH*FX
#define SEQ 1000
#define EMB 100
#define NF 32
#define KS 8
#define CLEN 93

typedef __bf16 bf16x8 __attribute__((ext_vector_type(8)));
typedef float  f32x4  __attribute__((ext_vector_type(4)));

// ---------------------------------------------------------------------------
// bf16 cast + pad helpers
// ---------------------------------------------------------------------------
__global__ __launch_bounds__(256)
void cast_pad_a(const float* __restrict__ in, __bf16* __restrict__ out,
                int M, int K, int Kp)
{
    size_t idx = (size_t)blockIdx.x*256 + threadIdx.x;
    if (idx >= (size_t)M*Kp) return;
    int r = idx / Kp, c = idx % Kp;
    out[idx] = (c < K) ? (__bf16)in[(size_t)r*K + c] : (__bf16)0.f;
}

// B[K,N] -> Bt[Np][Kp] (transposed, zero-padded)
__global__ __launch_bounds__(256)
void cast_pad_bt(const float* __restrict__ B, __bf16* __restrict__ out,
                 int K, int N, int Kp, int Np)
{
    size_t idx = (size_t)blockIdx.x*256 + threadIdx.x;
    if (idx >= (size_t)Np*Kp) return;
    int n = idx / Kp, k = idx % Kp;
    out[idx] = (n < N && k < K) ? (__bf16)B[(size_t)k*N + n] : (__bf16)0.f;
}

// ---------------------------------------------------------------------------
// bf16 MFMA GEMM (full-K): C[M,ldc] = A[M,Kp] @ Bt[Np,Kp]^T, f32 out
// ---------------------------------------------------------------------------
#define BKP 40
template<bool BIAS, bool RELU, bool BF16OUT>
__global__ __launch_bounds__(256)
void gemm_mfma(const __bf16* __restrict__ A, const __bf16* __restrict__ Bt,
               const float* __restrict__ bias, void* __restrict__ Cv,
               int M, int N, int Kp, int ldc, int Nz)
{
    __shared__ __align__(16) __bf16 As[128*BKP];
    __shared__ __align__(16) __bf16 Bs[128*BKP];
    const int tid = threadIdx.x;
    const int row0 = blockIdx.y*128, col0 = blockIdx.x*128;
    const int lane = tid & 63, wid = tid >> 6;
    const int wm = wid & 1, wn = wid >> 1;
    const int l15 = lane & 15, lk = lane >> 4;

    f32x4 acc[4][4];
#pragma unroll
    for (int i = 0; i < 4; i++)
#pragma unroll
        for (int j = 0; j < 4; j++) acc[i][j] = (f32x4){0.f,0.f,0.f,0.f};

    for (int k0 = 0; k0 < Kp; k0 += 32) {
        __syncthreads();
#pragma unroll
        for (int it = 0; it < 2; ++it) {
            int c = tid + it*256;
            int r = c >> 2, c16 = c & 3;
            uint4 va = *(const uint4*)(A  + (size_t)(row0+r)*Kp + k0 + c16*8);
            *(uint4*)&As[r*BKP + c16*8] = va;
            uint4 vb = *(const uint4*)(Bt + (size_t)(col0+r)*Kp + k0 + c16*8);
            *(uint4*)&Bs[r*BKP + c16*8] = vb;
        }
        __syncthreads();
        bf16x8 af[4], bfr[4];
#pragma unroll
        for (int i = 0; i < 4; i++) {
            af[i]  = *(const bf16x8*)&As[(wm*64 + i*16 + l15)*BKP + lk*8];
            bfr[i] = *(const bf16x8*)&Bs[(wn*64 + i*16 + l15)*BKP + lk*8];
        }
#pragma unroll
        for (int i = 0; i < 4; i++)
#pragma unroll
            for (int j = 0; j < 4; j++)
                acc[i][j] = __builtin_amdgcn_mfma_f32_16x16x32_bf16(af[i], bfr[j], acc[i][j], 0, 0, 0);
    }

#pragma unroll
    for (int i = 0; i < 4; i++) {
        int rbase = row0 + wm*64 + i*16 + lk*4;
#pragma unroll
        for (int j = 0; j < 4; j++) {
            int cc = col0 + wn*64 + j*16 + l15;
            if (cc >= Nz) continue;
            bool real = cc < N;
            float bv = (BIAS && real) ? bias[cc] : 0.f;
#pragma unroll
            for (int r = 0; r < 4; r++) {
                float v = real ? (acc[i][j][r] + bv) : 0.f;
                if (RELU) v = v > 0.f ? v : 0.f;
                if (BF16OUT) ((__bf16*)Cv)[(size_t)(rbase + r)*ldc + cc] = (__bf16)v;
                else         ((float*) Cv)[(size_t)(rbase + r)*ldc + cc] = v;
            }
        }
    }
}

// ---------------------------------------------------------------------------
// Split-K MFMA GEMM: partial[s][M][ldp] f32. Block z = split s, covers
// ksteps 32-wide K-steps starting at s*ksteps.
// ---------------------------------------------------------------------------
__global__ __launch_bounds__(256)
void gemm_mfma_splitk(const __bf16* __restrict__ A, const __bf16* __restrict__ Bt,
                      float* __restrict__ part, int M, int Kp, int ldp, int ksteps)
{
    __shared__ __align__(16) __bf16 As[128*BKP];
    __shared__ __align__(16) __bf16 Bs[128*BKP];
    const int tid = threadIdx.x;
    const int row0 = blockIdx.y*128, col0 = blockIdx.x*128;
    const int s = blockIdx.z;
    const int lane = tid & 63, wid = tid >> 6;
    const int wm = wid & 1, wn = wid >> 1;
    const int l15 = lane & 15, lk = lane >> 4;

    const int T = Kp >> 5;
    int kb = s*ksteps, ke = kb + ksteps;
    if (ke > T) ke = T;

    f32x4 acc[4][4];
#pragma unroll
    for (int i = 0; i < 4; i++)
#pragma unroll
        for (int j = 0; j < 4; j++) acc[i][j] = (f32x4){0.f,0.f,0.f,0.f};

    for (int kk = kb; kk < ke; kk++) {
        int k0 = kk*32;
        __syncthreads();
#pragma unroll
        for (int it = 0; it < 2; ++it) {
            int c = tid + it*256;
            int r = c >> 2, c16 = c & 3;
            uint4 va = *(const uint4*)(A  + (size_t)(row0+r)*Kp + k0 + c16*8);
            *(uint4*)&As[r*BKP + c16*8] = va;
            uint4 vb = *(const uint4*)(Bt + (size_t)(col0+r)*Kp + k0 + c16*8);
            *(uint4*)&Bs[r*BKP + c16*8] = vb;
        }
        __syncthreads();
        bf16x8 af[4], bfr[4];
#pragma unroll
        for (int i = 0; i < 4; i++) {
            af[i]  = *(const bf16x8*)&As[(wm*64 + i*16 + l15)*BKP + lk*8];
            bfr[i] = *(const bf16x8*)&Bs[(wn*64 + i*16 + l15)*BKP + lk*8];
        }
#pragma unroll
        for (int i = 0; i < 4; i++)
#pragma unroll
            for (int j = 0; j < 4; j++)
                acc[i][j] = __builtin_amdgcn_mfma_f32_16x16x32_bf16(af[i], bfr[j], acc[i][j], 0, 0, 0);
    }

#pragma unroll
    for (int i = 0; i < 4; i++) {
        int rbase = row0 + wm*64 + i*16 + lk*4;
#pragma unroll
        for (int j = 0; j < 4; j++) {
            int cc = col0 + wn*64 + j*16 + l15;
#pragma unroll
            for (int r = 0; r < 4; r++)
                part[((size_t)s*M + rbase + r)*ldp + cc] = acc[i][j][r];
        }
    }
}

// reduce S partials + bias (+relu) -> bf16 C (cols [N,Nz) zeroed)
template<bool RELU>
__global__ __launch_bounds__(256)
void reduce_splitk(const float* __restrict__ part, const float* __restrict__ bias,
                   __bf16* __restrict__ C, int M, int N, int ldp, int S,
                   int ldc, int Nz)
{
    int idx = blockIdx.x*256 + threadIdx.x;
    int nc4 = Nz >> 2;
    if (idx >= M*nc4) return;
    int r = idx / nc4, c = (idx - r*nc4)*4;
    float4 a = {0.f,0.f,0.f,0.f};
    for (int s = 0; s < S; s++) {
        float4 v = *(const float4*)(part + ((size_t)s*M + r)*ldp + c);
        a.x += v.x; a.y += v.y; a.z += v.z; a.w += v.w;
    }
    float vv[4] = {a.x, a.y, a.z, a.w};
    __bf16 o4[4];
#pragma unroll
    for (int j = 0; j < 4; j++) {
        float v = 0.f;
        if (c + j < N) {
            v = vv[j] + bias[c+j];
            if (RELU) v = v > 0.f ? v : 0.f;
        }
        o4[j] = (__bf16)v;
    }
    *(uint2*)&C[(size_t)r*ldc + c] = *(uint2*)o4;
}

// ---------------------------------------------------------------------------
// a_src[n,h], a_dst[n,h] from xh
// ---------------------------------------------------------------------------
__global__ __launch_bounds__(256)
void attn_logits(const float* __restrict__ xh, const float* __restrict__ att_s,
                 const float* __restrict__ att_d,
                 float* __restrict__ a_src, float* __restrict__ a_dst)
{
    int idx = blockIdx.x*256 + threadIdx.x;
    if (idx >= NN*NH) return;
    int n = idx / NH, h = idx % NH;
    const float* xr = xh + (size_t)n*HD + h*FX;
    const float* as = att_s + h*FX;
    const float* ad = att_d + h*FX;
    float s1 = 0.f, s2 = 0.f;
    for (int c = 0; c < FX; c++) {
        float v = xr[c];
        s1 = fmaf(v, as[c], s1);
        s2 = fmaf(v, ad[c], s2);
    }
    a_src[idx] = s1;
    a_dst[idx] = s2;
}

// ---------------------------------------------------------------------------
// CSR build
// ---------------------------------------------------------------------------
__global__ void edge_count(const int* __restrict__ ei, int* __restrict__ deg)
{
    int e = blockIdx.x*256 + threadIdx.x;
    if (e >= NT) return;
    int dst = (e < NE) ? ei[NE + e] : (e - NE);
    atomicAdd(&deg[dst], 1);
}

__global__ __launch_bounds__(1024)
void scan_kernel(const int* __restrict__ deg, int* __restrict__ offs, int* __restrict__ cursor)
{
    __shared__ int part[1024];
    int tid = threadIdx.x;
    int base = tid*16;
    int v[16]; int ssum = 0;
#pragma unroll
    for (int j = 0; j < 16; j++) { v[j] = deg[base+j]; ssum += v[j]; }
    part[tid] = ssum;
    __syncthreads();
    for (int d = 1; d < 1024; d <<= 1) {
        int t = (tid >= d) ? part[tid-d] : 0;
        __syncthreads();
        part[tid] += t;
        __syncthreads();
    }
    int run = (tid == 0) ? 0 : part[tid-1];
#pragma unroll
    for (int j = 0; j < 16; j++) { offs[base+j] = run; cursor[base+j] = run; run += v[j]; }
    if (tid == 1023) offs[NN] = run;
}

__global__ void edge_scatter(const int* __restrict__ ei, int* __restrict__ cursor,
                             int* __restrict__ csr)
{
    int e = blockIdx.x*256 + threadIdx.x;
    if (e >= NT) return;
    int src, dst;
    if (e < NE) { src = ei[e]; dst = ei[NE + e]; }
    else        { src = e - NE; dst = e - NE; }
    int pos = atomicAdd(&cursor[dst], 1);
    csr[pos] = src;
}

__global__ void dinv_kernel(const int* __restrict__ offs, float* __restrict__ dinv)
{
    int n = blockIdx.x*256 + threadIdx.x;
    if (n >= NN) return;
    int d = offs[n+1] - offs[n];
    dinv[n] = rsqrtf((float)(d > 0 ? d : 1));
}

// ---------------------------------------------------------------------------
// GAT aggregation -> bf16 h (row stride 800, cols 780..799 zeroed)
// ---------------------------------------------------------------------------
__global__ __launch_bounds__(256)
void gat_agg(const float* __restrict__ xh, const float* __restrict__ a_src,
             const float* __restrict__ a_dst, const float* __restrict__ gat_b,
             const int* __restrict__ offs, const int* __restrict__ csr,
             __bf16* __restrict__ hbf)
{
    int n = blockIdx.x*4 + (threadIdx.x >> 6);
    if (n >= NN) return;
    int lane = threadIdx.x & 63;
    bool act = lane < 60;
    int h   = act ? (lane / 6) : 0;
    int sub = act ? (lane % 6) : 0;
    int cbase = h*FX + sub*13;
    int off = offs[n], end = offs[n+1];
    float adn = a_dst[n*NH + h];

    float m = -3.0e38f;
    for (int i = off; i < end; i++) {
        int s = csr[i];
        float ev = a_src[s*NH + h] + adn;
        ev = ev > 0.f ? ev : 0.2f*ev;
        m = fmaxf(m, ev);
    }
    float den = 0.f;
    float acc[13];
#pragma unroll
    for (int j = 0; j < 13; j++) acc[j] = 0.f;
    for (int i = off; i < end; i++) {
        int s = csr[i];
        float ev = a_src[s*NH + h] + adn;
        ev = ev > 0.f ? ev : 0.2f*ev;
        float ee = __expf(ev - m);
        den += ee;
        const float* xr = xh + (size_t)s*HD + cbase;
#pragma unroll
        for (int j = 0; j < 13; j++) acc[j] = fmaf(xr[j], ee, acc[j]);
    }
    if (act) {
        float inv = 1.f / den;
        const float* bb = gat_b + cbase;
        __bf16* op = hbf + (size_t)n*800 + cbase;
#pragma unroll
        for (int j = 0; j < 13; j++) {
            float v = fmaf(acc[j], inv, bb[j]);
            op[j] = (__bf16)(v > 0.f ? v : 0.f);
        }
    } else {
        __bf16* op = hbf + (size_t)n*800 + 780 + (lane - 60)*5;
#pragma unroll
        for (int j = 0; j < 5; j++) op[j] = (__bf16)0.f;
    }
}

// ---------------------------------------------------------------------------
// GCN aggregation (f32 in/out, lane-strided channels)
// ---------------------------------------------------------------------------
__global__ __launch_bounds__(256)
void gcn_agg(const float* __restrict__ hw, const float* __restrict__ dinv,
             const float* __restrict__ gcn_b, const int* __restrict__ offs,
             const int* __restrict__ csr, float* __restrict__ g)
{
    int n = blockIdx.x*4 + (threadIdx.x >> 6);
    if (n >= NN) return;
    int lane = threadIdx.x & 63;
    int off = offs[n], end = offs[n+1];
    float dn = dinv[n];
    float acc[13];
#pragma unroll
    for (int j = 0; j < 13; j++) acc[j] = 0.f;
    for (int i = off; i < end; i++) {
        int s = csr[i];
        float w = dinv[s] * dn;
        const float* r = hw + (size_t)s*HD;
#pragma unroll
        for (int j = 0; j < 13; j++) {
            int c = lane + 64*j;
            if (c < HD) acc[j] = fmaf(r[c], w, acc[j]);
        }
    }
    float* op = g + (size_t)n*HD;
#pragma unroll
    for (int j = 0; j < 13; j++) {
        int c = lane + 64*j;
        if (c < HD) {
            float v = acc[j] + gcn_b[c];
            op[c] = v > 0.f ? v : 0.f;
        }
    }
}

// ---------------------------------------------------------------------------
__global__ void gstart_kernel(const int* __restrict__ batch, int* __restrict__ goffs)
{
    int b = blockIdx.x*256 + threadIdx.x;
    if (b > NG) return;
    if (b == NG) { goffs[NG] = NN; return; }
    int lo = 0, hi = NN;
    while (lo < hi) { int mid = (lo+hi) >> 1; if (batch[mid] < b) lo = mid+1; else hi = mid; }
    goffs[b] = lo;
}

// pool -> bf16 d[b][1568]: [0:780)=max, [780:1560)=mean, [1560:1568)=0
__global__ __launch_bounds__(256)
void pool_kernel(const float* __restrict__ g, const int* __restrict__ goffs,
                 __bf16* __restrict__ d)
{
    int b = blockIdx.x;
    int tid = threadIdx.x;
    int s = goffs[b], e = goffs[b+1];
    float mx[4], sm[4];
#pragma unroll
    for (int j = 0; j < 4; j++) { mx[j] = -3.0e38f; sm[j] = 0.f; }
    for (int n = s; n < e; n++) {
        const float* r = g + (size_t)n*HD;
#pragma unroll
        for (int j = 0; j < 4; j++) {
            int c = tid + 256*j;
            if (c < HD) { float v = r[c]; mx[j] = fmaxf(mx[j], v); sm[j] += v; }
        }
    }
    int cnt = e - s;
    float inv = 1.f / (float)(cnt > 0 ? cnt : 1);
#pragma unroll
    for (int j = 0; j < 4; j++) {
        int c = tid + 256*j;
        if (c < HD) {
            d[(size_t)b*1568 + c]      = (__bf16)mx[j];
            d[(size_t)b*1568 + HD + c] = (__bf16)(sm[j] * inv);
        }
    }
    if (tid < 8) d[(size_t)b*1568 + 1560 + tid] = (__bf16)0.f;
}

// ---------------------------------------------------------------------------
// Conv: W'[(k*32+o), i] = conv_w[o,i,k]; emb table pre-cast to bf16 padded
// [8001][112] (row 8000 = zeros, cols 100..111 = zeros).
// Pt[b][z][c=112][o'=256] = emb_colsT @ W'T over k-half z. No LDS, no barriers:
// A-frags = per-lane bf16 gathers from embbf (L2-hot), B-frags = contiguous
// bf16x8 from w2. Then c[b,o,t] = sum_z sum_k Pt[b][z][t+k][k*32+o] + bias.
// ---------------------------------------------------------------------------
__global__ __launch_bounds__(256)
void emb_cast(const float* __restrict__ emb_w, __bf16* __restrict__ embbf)
{
    int idx = blockIdx.x*256 + threadIdx.x;
    if (idx >= 8001*112) return;
    int r = idx / 112, c = idx - (idx/112)*112;
    float v = (r < 8000 && c < EMB) ? emb_w[(size_t)r*EMB + c] : 0.f;
    embbf[idx] = (__bf16)v;
}

__global__ __launch_bounds__(256)
void conv_w_repack(const float* __restrict__ conv_w, __bf16* __restrict__ w2)
{
    int idx = blockIdx.x*256 + threadIdx.x;   // o'*1024 + i
    if (idx >= 256*1024) return;
    int op = idx >> 10, i = idx & 1023;
    int o = op & 31, k = op >> 5;
    w2[idx] = (i < SEQ) ? (__bf16)conv_w[((size_t)o*SEQ + i)*KS + k] : (__bf16)0.f;
}

__global__ __launch_bounds__(256)
void conv_gemm(const int* __restrict__ target, const __bf16* __restrict__ embbf,
               const __bf16* __restrict__ w2, __bf16* __restrict__ Pt)
{
    const int b = blockIdx.x, z = blockIdx.y;
    const int tid = threadIdx.x;
    const int w = tid >> 6, lane = tid & 63;
    const int l15 = lane & 15, lk = lane >> 4;

    f32x4 acc[7][4];
#pragma unroll
    for (int i = 0; i < 7; i++)
#pragma unroll
        for (int j = 0; j < 4; j++) acc[i][j] = (f32x4){0.f,0.f,0.f,0.f};

    const int kbase0 = z*512;
    for (int p = 0; p < 16; ++p) {
        int kb = kbase0 + p*32;
        int ro[8];
#pragma unroll
        for (int r = 0; r < 8; r++) {
            int i = kb + lk*8 + r;
            int row = (i < SEQ) ? target[b*SEQ + i] : 8000;
            ro[r] = row * 112;
        }
        bf16x8 bfrag[4];
#pragma unroll
        for (int nt = 0; nt < 4; nt++) {
            int op = w*64 + nt*16 + l15;
            bfrag[nt] = *(const bf16x8*)(w2 + (size_t)op*1024 + kb + lk*8);
        }
#pragma unroll
        for (int mt = 0; mt < 7; mt++) {
            int c0 = mt*16 + l15;
            bf16x8 af;
#pragma unroll
            for (int r = 0; r < 8; r++) af[r] = embbf[ro[r] + c0];
#pragma unroll
            for (int nt = 0; nt < 4; nt++)
                acc[mt][nt] = __builtin_amdgcn_mfma_f32_16x16x32_bf16(af, bfrag[nt], acc[mt][nt], 0, 0, 0);
        }
    }
#pragma unroll
    for (int mt = 0; mt < 7; mt++) {
#pragma unroll
        for (int nt = 0; nt < 4; nt++) {
            int op = w*64 + nt*16 + l15;
#pragma unroll
            for (int rr = 0; rr < 4; rr++) {
                int c = mt*16 + lk*4 + rr;
                Pt[(((size_t)b*2 + z)*112 + c)*256 + op] = (__bf16)acc[mt][nt][rr];
            }
        }
    }
}

// c[b,o,t] = sum_z sum_k Pt[b][z][t+k][k*32+o] + conv_b[o] -> cbuf bf16
__global__ __launch_bounds__(256)
void shift_add(const __bf16* __restrict__ Pt, const float* __restrict__ conv_b,
               __bf16* __restrict__ cbuf)
{
    int b = blockIdx.x;
    int tid = threadIdx.x;
    int o = tid & 31, tg = tid >> 5;   // lanes = consecutive o (coalesced reads)
    float cb = conv_b[o];
    const __bf16* P0 = Pt + ((size_t)b*2    )*112*256;
    const __bf16* P1 = Pt + ((size_t)b*2 + 1)*112*256;
#pragma unroll
    for (int j = 0; j < 12; j++) {
        int t = tg*12 + j;
        if (t >= CLEN) continue;
        float s = cb;
#pragma unroll
        for (int k = 0; k < 8; k++) {
            int off = (t+k)*256 + k*32 + o;
            s += (float)P0[off] + (float)P1[off];
        }
        cbuf[(size_t)b*2976 + o*CLEN + t] = (__bf16)s;
    }
}

// ---------------------------------------------------------------------------
// mlp3: out[r] = dot(o2bf[r,0:512], w) + b   (wave per row)
// ---------------------------------------------------------------------------
__global__ __launch_bounds__(256)
void mlp3_dot(const __bf16* __restrict__ o2, const float* __restrict__ w,
              const float* __restrict__ bias, float* __restrict__ out)
{
    int row = blockIdx.x*4 + (threadIdx.x >> 6);
    int lane = threadIdx.x & 63;
    bf16x8 v = *(const bf16x8*)(o2 + (size_t)row*512 + lane*8);
    float4 w0 = *(const float4*)(w + lane*8);
    float4 w1 = *(const float4*)(w + lane*8 + 4);
    float s = (float)v[0]*w0.x + (float)v[1]*w0.y + (float)v[2]*w0.z + (float)v[3]*w0.w
            + (float)v[4]*w1.x + (float)v[5]*w1.y + (float)v[6]*w1.z + (float)v[7]*w1.w;
#pragma unroll
    for (int off = 32; off > 0; off >>= 1) s += __shfl_down(s, off);
    if (lane == 0) out[row] = s + bias[0];
}

// ---------------------------------------------------------------------------
extern "C" void kernel_launch(void* const* d_in, const int* in_sizes, int n_in,
                              void* d_out, int out_size, void* d_ws, size_t ws_size,
                              hipStream_t stream)
{
    const float* x      = (const float*)d_in[0];
    const int*   ei     = (const int*)  d_in[1];
    const int*   batch  = (const int*)  d_in[2];
    const int*   target = (const int*)  d_in[3];
    const float* gat_w  = (const float*)d_in[4];
    const float* att_s  = (const float*)d_in[5];
    const float* att_d  = (const float*)d_in[6];
    const float* gat_b  = (const float*)d_in[7];
    const float* gcn_w  = (const float*)d_in[8];
    const float* gcn_b  = (const float*)d_in[9];
    const float* fcg1_w = (const float*)d_in[10];
    const float* fcg1_b = (const float*)d_in[11];
    const float* fcg2_w = (const float*)d_in[12];
    const float* fcg2_b = (const float*)d_in[13];
    const float* emb_w  = (const float*)d_in[14];
    const float* conv_w = (const float*)d_in[15];
    const float* conv_b = (const float*)d_in[16];
    const float* fcxt_w = (const float*)d_in[17];
    const float* fcxt_b = (const float*)d_in[18];
    const float* mlp1_w = (const float*)d_in[19];
    const float* mlp1_b = (const float*)d_in[20];
    const float* mlp2_w = (const float*)d_in[21];
    const float* mlp2_b = (const float*)d_in[22];
    const float* mlp3_w = (const float*)d_in[23];
    const float* mlp3_b = (const float*)d_in[24];
    float* out = (float*)d_out;

    char* ws = (char*)d_ws;
    size_t off = 0;
    auto alloc = [&](size_t bytes) -> char* {
        char* p = ws + off;
        off = (off + bytes + 255) & ~(size_t)255;
        return p;
    };
    float* xh     = (float*)alloc((size_t)NN*HD*4);    // reused as hw, then Pt
    float* g      = (float*)alloc((size_t)NN*HD*4);
    char*  hbf_rg = alloc((size_t)NN*800*2);           // Abf -> hbf -> splitk partial
    __bf16* Abf   = (__bf16*)hbf_rg;
    __bf16* hbf   = (__bf16*)hbf_rg;
    float* partial= (float*)hbf_rg;                    // 12.6MB max, after hbf dead
    __bf16* Btbf  = (__bf16*)alloc((size_t)896*800*2); // gat/gcn weight (seq reuse)
    __bf16* wg1   = (__bf16*)alloc((size_t)1536*1568*2);
    __bf16* wg2   = (__bf16*)alloc((size_t)128*1504*2);
    __bf16* wxt   = (__bf16*)alloc((size_t)128*2976*2);
    __bf16* wm1   = (__bf16*)alloc((size_t)1024*256*2);
    __bf16* wm2   = (__bf16*)alloc((size_t)512*1024*2);
    __bf16* convw2= (__bf16*)alloc((size_t)256*1024*2);
    __bf16* embbf = (__bf16*)alloc((size_t)8001*112*2);
    float* a_src  = (float*)alloc((size_t)NN*NH*4);
    float* a_dst  = (float*)alloc((size_t)NN*NH*4);
    int*   deg    = (int*)alloc((size_t)NN*4);
    int*   offs   = (int*)alloc((size_t)(NN+1)*4);
    int*   cursor = (int*)alloc((size_t)NN*4);
    int*   csr    = (int*)alloc((size_t)NT*4);
    float* dinv   = (float*)alloc((size_t)NN*4);
    int*   goffs  = (int*)alloc((size_t)(NG+1)*4);
    __bf16* dpool = (__bf16*)alloc((size_t)NG*1568*2);
    __bf16* d1bf  = (__bf16*)alloc((size_t)NG*1504*2);
    __bf16* cbuf  = (__bf16*)alloc((size_t)NG*NF*CLEN*2);
    __bf16* obuf  = (__bf16*)alloc((size_t)NG*256*2);
    __bf16* o1bf  = (__bf16*)alloc((size_t)NG*1024*2);
    __bf16* o2bf  = (__bf16*)alloc((size_t)NG*512*2);

    float* hw = xh;              // xh dead after gat_agg
    __bf16* Pt = (__bf16*)xh;    // hw dead after gcn_agg (29.4MB < 51MB)

    hipMemsetAsync(deg, 0, (size_t)NN*4, stream);

    // --- weight preprocessing (inputs only) ---
    emb_cast     <<<dim3((8001*112+255)/256), 256, 0, stream>>>(emb_w, embbf);
    conv_w_repack<<<dim3(1024), 256, 0, stream>>>(conv_w, convw2);
    cast_pad_bt<<<dim3((1536*1568)/256), 256, 0, stream>>>(fcg1_w, wg1, 1560, 1500, 1568, 1536);
    cast_pad_bt<<<dim3((128*1504)/256), 256, 0, stream>>>(fcg2_w, wg2, 1500, 128, 1504, 128);
    cast_pad_bt<<<dim3((128*2976)/256), 256, 0, stream>>>(fcxt_w, wxt, NF*CLEN, 128, 2976, 128);
    cast_pad_bt<<<dim3((1024*256)/256), 256, 0, stream>>>(mlp1_w, wm1, 256, 1024, 256, 1024);
    cast_pad_bt<<<dim3((512*1024)/256), 256, 0, stream>>>(mlp2_w, wm2, 1024, 512, 1024, 512);

    // --- GAT linear: xh = x @ gat_w (Kp=96), f32 out ---
    cast_pad_a <<<dim3((NN*96)/256), 256, 0, stream>>>(x, Abf, NN, FX, 96);
    cast_pad_bt<<<dim3((896*96)/256), 256, 0, stream>>>(gat_w, Btbf, FX, HD, 96, 896);
    gemm_mfma<false,false,false>
        <<<dim3(7, NN/128), 256, 0, stream>>>(Abf, Btbf, nullptr, xh, NN, HD, 96, HD, HD);
    attn_logits<<<dim3((NN*NH+255)/256), 256, 0, stream>>>(xh, att_s, att_d, a_src, a_dst);

    // --- CSR ---
    edge_count  <<<dim3(NT/256), 256, 0, stream>>>(ei, deg);
    scan_kernel <<<1, 1024, 0, stream>>>(deg, offs, cursor);
    edge_scatter<<<dim3(NT/256), 256, 0, stream>>>(ei, cursor, csr);
    dinv_kernel <<<dim3(NN/256), 256, 0, stream>>>(offs, dinv);

    // --- GAT aggregate -> hbf ---
    gat_agg<<<dim3(NN/4), 256, 0, stream>>>(xh, a_src, a_dst, gat_b, offs, csr, hbf);

    // --- GCN linear + aggregate ---
    cast_pad_bt<<<dim3((896*800)/256), 256, 0, stream>>>(gcn_w, Btbf, HD, HD, 800, 896);
    gemm_mfma<false,false,false>
        <<<dim3(7, NN/128), 256, 0, stream>>>(hbf, Btbf, nullptr, hw, NN, HD, 800, HD, HD);
    gcn_agg<<<dim3(NN/4), 256, 0, stream>>>(hw, dinv, gcn_b, offs, csr, g);

    // --- pooling ---
    gstart_kernel<<<3, 256, 0, stream>>>(batch, goffs);
    pool_kernel<<<NG, 256, 0, stream>>>(g, goffs, dpool);

    // --- protein conv (Pt aliases xh/hw; both dead now) ---
    conv_gemm<<<dim3(NG, 2), 256, 0, stream>>>(target, embbf, convw2, Pt);
    shift_add<<<dim3(NG), 256, 0, stream>>>(Pt, conv_b, cbuf);

    // --- FC stack via split-K (partial aliases hbf; dead after gcn gemm) ---
    // fcg1: 512x1500, K=1568
    gemm_mfma_splitk<<<dim3(12, 4, 4), 256, 0, stream>>>(dpool, wg1, partial, NG, 1568, 1536, 13);
    reduce_splitk<true><<<dim3((NG*(1504/4)+255)/256), 256, 0, stream>>>(partial, fcg1_b, d1bf, NG, 1500, 1536, 4, 1504, 1504);
    // fcg2: 512x128, K=1504 -> obuf[:, 0:128]
    gemm_mfma_splitk<<<dim3(1, 4, 12), 256, 0, stream>>>(d1bf, wg2, partial, NG, 1504, 128, 4);
    reduce_splitk<false><<<dim3((NG*32+255)/256), 256, 0, stream>>>(partial, fcg2_b, obuf, NG, 128, 128, 12, 256, 128);
    // fcxt: 512x128, K=2976 -> obuf[:, 128:256]
    gemm_mfma_splitk<<<dim3(1, 4, 24), 256, 0, stream>>>(cbuf, wxt, partial, NG, 2976, 128, 4);
    reduce_splitk<false><<<dim3((NG*32+255)/256), 256, 0, stream>>>(partial, fcxt_b, obuf + 128, NG, 128, 128, 24, 256, 128);
    // mlp1: 512x1024, K=256
    gemm_mfma_splitk<<<dim3(8, 4, 2), 256, 0, stream>>>(obuf, wm1, partial, NG, 256, 1024, 4);
    reduce_splitk<true><<<dim3((NG*256+255)/256), 256, 0, stream>>>(partial, mlp1_b, o1bf, NG, 1024, 1024, 2, 1024, 1024);
    // mlp2: 512x512, K=1024
    gemm_mfma_splitk<<<dim3(4, 4, 8), 256, 0, stream>>>(o1bf, wm2, partial, NG, 1024, 512, 4);
    reduce_splitk<true><<<dim3((NG*128+255)/256), 256, 0, stream>>>(partial, mlp2_b, o2bf, NG, 512, 512, 8, 512, 512);

    mlp3_dot<<<dim3(NG/4), 256, 0, stream>>>(o2bf, mlp3_w, mlp3_b, out);
}

// Round 6
// 458.845 us; speedup vs baseline: 5.9288x; 1.1120x over previous
//
#include <hip/hip_runtime.h>

#define NN 16384      // nodes
#define NE 65536      // edges
#define NT 81920      // edges + self loops
#define NG 512        // graphs
#define NH 10         // heads
#define FX 78         // features per head
#define HD 780        // hidden = NH*FX
#define SEQ 1000
#define EMB 100
#define NF 32
#define KS 8
#define CLEN 93

typedef __bf16 bf16x8 __attribute__((ext_vector_type(8)));
typedef float  f32x4  __attribute__((ext_vector_type(4)));

// ---------------------------------------------------------------------------
// bf16 cast + pad helpers
// ---------------------------------------------------------------------------
__global__ __launch_bounds__(256)
void cast_pad_a(const float* __restrict__ in, __bf16* __restrict__ out,
                int M, int K, int Kp)
{
    size_t idx = (size_t)blockIdx.x*256 + threadIdx.x;
    if (idx >= (size_t)M*Kp) return;
    int r = idx / Kp, c = idx % Kp;
    out[idx] = (c < K) ? (__bf16)in[(size_t)r*K + c] : (__bf16)0.f;
}

// B[K,N] -> Bt[Np][Kp] (transposed, zero-padded)
__global__ __launch_bounds__(256)
void cast_pad_bt(const float* __restrict__ B, __bf16* __restrict__ out,
                 int K, int N, int Kp, int Np)
{
    size_t idx = (size_t)blockIdx.x*256 + threadIdx.x;
    if (idx >= (size_t)Np*Kp) return;
    int n = idx / Kp, k = idx % Kp;
    out[idx] = (n < N && k < K) ? (__bf16)B[(size_t)k*N + n] : (__bf16)0.f;
}

// ---------------------------------------------------------------------------
// bf16 MFMA GEMM (full-K): C[M,ldc] = A[M,Kp] @ Bt[Np,Kp]^T
// ---------------------------------------------------------------------------
#define BKP 40
template<bool BIAS, bool RELU, bool BF16OUT>
__global__ __launch_bounds__(256)
void gemm_mfma(const __bf16* __restrict__ A, const __bf16* __restrict__ Bt,
               const float* __restrict__ bias, void* __restrict__ Cv,
               int M, int N, int Kp, int ldc, int Nz)
{
    __shared__ __align__(16) __bf16 As[128*BKP];
    __shared__ __align__(16) __bf16 Bs[128*BKP];
    const int tid = threadIdx.x;
    const int row0 = blockIdx.y*128, col0 = blockIdx.x*128;
    const int lane = tid & 63, wid = tid >> 6;
    const int wm = wid & 1, wn = wid >> 1;
    const int l15 = lane & 15, lk = lane >> 4;

    f32x4 acc[4][4];
#pragma unroll
    for (int i = 0; i < 4; i++)
#pragma unroll
        for (int j = 0; j < 4; j++) acc[i][j] = (f32x4){0.f,0.f,0.f,0.f};

    for (int k0 = 0; k0 < Kp; k0 += 32) {
        __syncthreads();
#pragma unroll
        for (int it = 0; it < 2; ++it) {
            int c = tid + it*256;
            int r = c >> 2, c16 = c & 3;
            uint4 va = *(const uint4*)(A  + (size_t)(row0+r)*Kp + k0 + c16*8);
            *(uint4*)&As[r*BKP + c16*8] = va;
            uint4 vb = *(const uint4*)(Bt + (size_t)(col0+r)*Kp + k0 + c16*8);
            *(uint4*)&Bs[r*BKP + c16*8] = vb;
        }
        __syncthreads();
        bf16x8 af[4], bfr[4];
#pragma unroll
        for (int i = 0; i < 4; i++) {
            af[i]  = *(const bf16x8*)&As[(wm*64 + i*16 + l15)*BKP + lk*8];
            bfr[i] = *(const bf16x8*)&Bs[(wn*64 + i*16 + l15)*BKP + lk*8];
        }
#pragma unroll
        for (int i = 0; i < 4; i++)
#pragma unroll
            for (int j = 0; j < 4; j++)
                acc[i][j] = __builtin_amdgcn_mfma_f32_16x16x32_bf16(af[i], bfr[j], acc[i][j], 0, 0, 0);
    }

#pragma unroll
    for (int i = 0; i < 4; i++) {
        int rbase = row0 + wm*64 + i*16 + lk*4;
#pragma unroll
        for (int j = 0; j < 4; j++) {
            int cc = col0 + wn*64 + j*16 + l15;
            if (cc >= Nz) continue;
            bool real = cc < N;
            float bv = (BIAS && real) ? bias[cc] : 0.f;
#pragma unroll
            for (int r = 0; r < 4; r++) {
                float v = real ? (acc[i][j][r] + bv) : 0.f;
                if (RELU) v = v > 0.f ? v : 0.f;
                if (BF16OUT) ((__bf16*)Cv)[(size_t)(rbase + r)*ldc + cc] = (__bf16)v;
                else         ((float*) Cv)[(size_t)(rbase + r)*ldc + cc] = v;
            }
        }
    }
}

// ---------------------------------------------------------------------------
// Split-K MFMA GEMM: partial[s][M][ldp] f32.
// ---------------------------------------------------------------------------
__global__ __launch_bounds__(256)
void gemm_mfma_splitk(const __bf16* __restrict__ A, const __bf16* __restrict__ Bt,
                      float* __restrict__ part, int M, int Kp, int ldp, int ksteps)
{
    __shared__ __align__(16) __bf16 As[128*BKP];
    __shared__ __align__(16) __bf16 Bs[128*BKP];
    const int tid = threadIdx.x;
    const int row0 = blockIdx.y*128, col0 = blockIdx.x*128;
    const int s = blockIdx.z;
    const int lane = tid & 63, wid = tid >> 6;
    const int wm = wid & 1, wn = wid >> 1;
    const int l15 = lane & 15, lk = lane >> 4;

    const int T = Kp >> 5;
    int kb = s*ksteps, ke = kb + ksteps;
    if (ke > T) ke = T;

    f32x4 acc[4][4];
#pragma unroll
    for (int i = 0; i < 4; i++)
#pragma unroll
        for (int j = 0; j < 4; j++) acc[i][j] = (f32x4){0.f,0.f,0.f,0.f};

    for (int kk = kb; kk < ke; kk++) {
        int k0 = kk*32;
        __syncthreads();
#pragma unroll
        for (int it = 0; it < 2; ++it) {
            int c = tid + it*256;
            int r = c >> 2, c16 = c & 3;
            uint4 va = *(const uint4*)(A  + (size_t)(row0+r)*Kp + k0 + c16*8);
            *(uint4*)&As[r*BKP + c16*8] = va;
            uint4 vb = *(const uint4*)(Bt + (size_t)(col0+r)*Kp + k0 + c16*8);
            *(uint4*)&Bs[r*BKP + c16*8] = vb;
        }
        __syncthreads();
        bf16x8 af[4], bfr[4];
#pragma unroll
        for (int i = 0; i < 4; i++) {
            af[i]  = *(const bf16x8*)&As[(wm*64 + i*16 + l15)*BKP + lk*8];
            bfr[i] = *(const bf16x8*)&Bs[(wn*64 + i*16 + l15)*BKP + lk*8];
        }
#pragma unroll
        for (int i = 0; i < 4; i++)
#pragma unroll
            for (int j = 0; j < 4; j++)
                acc[i][j] = __builtin_amdgcn_mfma_f32_16x16x32_bf16(af[i], bfr[j], acc[i][j], 0, 0, 0);
    }

#pragma unroll
    for (int i = 0; i < 4; i++) {
        int rbase = row0 + wm*64 + i*16 + lk*4;
#pragma unroll
        for (int j = 0; j < 4; j++) {
            int cc = col0 + wn*64 + j*16 + l15;
#pragma unroll
            for (int r = 0; r < 4; r++)
                part[((size_t)s*M + rbase + r)*ldp + cc] = acc[i][j][r];
        }
    }
}

// reduce S partials + bias (+relu) -> bf16 C (cols [N,Nz) zeroed)
template<bool RELU>
__global__ __launch_bounds__(256)
void reduce_splitk(const float* __restrict__ part, const float* __restrict__ bias,
                   __bf16* __restrict__ C, int M, int N, int ldp, int S,
                   int ldc, int Nz)
{
    int idx = blockIdx.x*256 + threadIdx.x;
    int nc4 = Nz >> 2;
    if (idx >= M*nc4) return;
    int r = idx / nc4, c = (idx - r*nc4)*4;
    float4 a = {0.f,0.f,0.f,0.f};
    for (int s = 0; s < S; s++) {
        float4 v = *(const float4*)(part + ((size_t)s*M + r)*ldp + c);
        a.x += v.x; a.y += v.y; a.z += v.z; a.w += v.w;
    }
    float vv[4] = {a.x, a.y, a.z, a.w};
    __bf16 o4[4];
#pragma unroll
    for (int j = 0; j < 4; j++) {
        float v = 0.f;
        if (c + j < N) {
            v = vv[j] + bias[c+j];
            if (RELU) v = v > 0.f ? v : 0.f;
        }
        o4[j] = (__bf16)v;
    }
    *(uint2*)&C[(size_t)r*ldc + c] = *(uint2*)o4;
}

// ---------------------------------------------------------------------------
// a_src[n,h], a_dst[n,h] from xh
// ---------------------------------------------------------------------------
__global__ __launch_bounds__(256)
void attn_logits(const float* __restrict__ xh, const float* __restrict__ att_s,
                 const float* __restrict__ att_d,
                 float* __restrict__ a_src, float* __restrict__ a_dst)
{
    int idx = blockIdx.x*256 + threadIdx.x;
    if (idx >= NN*NH) return;
    int n = idx / NH, h = idx % NH;
    const float* xr = xh + (size_t)n*HD + h*FX;
    const float* as = att_s + h*FX;
    const float* ad = att_d + h*FX;
    float s1 = 0.f, s2 = 0.f;
    for (int c = 0; c < FX; c++) {
        float v = xr[c];
        s1 = fmaf(v, as[c], s1);
        s2 = fmaf(v, ad[c], s2);
    }
    a_src[idx] = s1;
    a_dst[idx] = s2;
}

// ---------------------------------------------------------------------------
// CSR build
// ---------------------------------------------------------------------------
__global__ void edge_count(const int* __restrict__ ei, int* __restrict__ deg)
{
    int e = blockIdx.x*256 + threadIdx.x;
    if (e >= NT) return;
    int dst = (e < NE) ? ei[NE + e] : (e - NE);
    atomicAdd(&deg[dst], 1);
}

__global__ __launch_bounds__(1024)
void scan_kernel(const int* __restrict__ deg, int* __restrict__ offs, int* __restrict__ cursor)
{
    __shared__ int part[1024];
    int tid = threadIdx.x;
    int base = tid*16;
    int v[16]; int ssum = 0;
#pragma unroll
    for (int j = 0; j < 16; j++) { v[j] = deg[base+j]; ssum += v[j]; }
    part[tid] = ssum;
    __syncthreads();
    for (int d = 1; d < 1024; d <<= 1) {
        int t = (tid >= d) ? part[tid-d] : 0;
        __syncthreads();
        part[tid] += t;
        __syncthreads();
    }
    int run = (tid == 0) ? 0 : part[tid-1];
#pragma unroll
    for (int j = 0; j < 16; j++) { offs[base+j] = run; cursor[base+j] = run; run += v[j]; }
    if (tid == 1023) offs[NN] = run;
}

__global__ void edge_scatter(const int* __restrict__ ei, int* __restrict__ cursor,
                             int* __restrict__ csr)
{
    int e = blockIdx.x*256 + threadIdx.x;
    if (e >= NT) return;
    int src, dst;
    if (e < NE) { src = ei[e]; dst = ei[NE + e]; }
    else        { src = e - NE; dst = e - NE; }
    int pos = atomicAdd(&cursor[dst], 1);
    csr[pos] = src;
}

__global__ void dinv_kernel(const int* __restrict__ offs, float* __restrict__ dinv)
{
    int n = blockIdx.x*256 + threadIdx.x;
    if (n >= NN) return;
    int d = offs[n+1] - offs[n];
    dinv[n] = rsqrtf((float)(d > 0 ? d : 1));
}

// ---------------------------------------------------------------------------
// GAT aggregation -> bf16 h (row stride 800, cols 780..799 zeroed)
// ---------------------------------------------------------------------------
__global__ __launch_bounds__(256)
void gat_agg(const float* __restrict__ xh, const float* __restrict__ a_src,
             const float* __restrict__ a_dst, const float* __restrict__ gat_b,
             const int* __restrict__ offs, const int* __restrict__ csr,
             __bf16* __restrict__ hbf)
{
    int n = blockIdx.x*4 + (threadIdx.x >> 6);
    if (n >= NN) return;
    int lane = threadIdx.x & 63;
    bool act = lane < 60;
    int h   = act ? (lane / 6) : 0;
    int sub = act ? (lane % 6) : 0;
    int cbase = h*FX + sub*13;
    int off = offs[n], end = offs[n+1];
    float adn = a_dst[n*NH + h];

    float m = -3.0e38f;
    for (int i = off; i < end; i++) {
        int s = csr[i];
        float ev = a_src[s*NH + h] + adn;
        ev = ev > 0.f ? ev : 0.2f*ev;
        m = fmaxf(m, ev);
    }
    float den = 0.f;
    float acc[13];
#pragma unroll
    for (int j = 0; j < 13; j++) acc[j] = 0.f;
    for (int i = off; i < end; i++) {
        int s = csr[i];
        float ev = a_src[s*NH + h] + adn;
        ev = ev > 0.f ? ev : 0.2f*ev;
        float ee = __expf(ev - m);
        den += ee;
        const float* xr = xh + (size_t)s*HD + cbase;
#pragma unroll
        for (int j = 0; j < 13; j++) acc[j] = fmaf(xr[j], ee, acc[j]);
    }
    if (act) {
        float inv = 1.f / den;
        const float* bb = gat_b + cbase;
        __bf16* op = hbf + (size_t)n*800 + cbase;
#pragma unroll
        for (int j = 0; j < 13; j++) {
            float v = fmaf(acc[j], inv, bb[j]);
            op[j] = (__bf16)(v > 0.f ? v : 0.f);
        }
    } else {
        __bf16* op = hbf + (size_t)n*800 + 780 + (lane - 60)*5;
#pragma unroll
        for (int j = 0; j < 5; j++) op[j] = (__bf16)0.f;
    }
}

// ---------------------------------------------------------------------------
// GCN aggregation (f32 in/out, lane-strided channels)
// ---------------------------------------------------------------------------
__global__ __launch_bounds__(256)
void gcn_agg(const float* __restrict__ hw, const float* __restrict__ dinv,
             const float* __restrict__ gcn_b, const int* __restrict__ offs,
             const int* __restrict__ csr, float* __restrict__ g)
{
    int n = blockIdx.x*4 + (threadIdx.x >> 6);
    if (n >= NN) return;
    int lane = threadIdx.x & 63;
    int off = offs[n], end = offs[n+1];
    float dn = dinv[n];
    float acc[13];
#pragma unroll
    for (int j = 0; j < 13; j++) acc[j] = 0.f;
    for (int i = off; i < end; i++) {
        int s = csr[i];
        float w = dinv[s] * dn;
        const float* r = hw + (size_t)s*HD;
#pragma unroll
        for (int j = 0; j < 13; j++) {
            int c = lane + 64*j;
            if (c < HD) acc[j] = fmaf(r[c], w, acc[j]);
        }
    }
    float* op = g + (size_t)n*HD;
#pragma unroll
    for (int j = 0; j < 13; j++) {
        int c = lane + 64*j;
        if (c < HD) {
            float v = acc[j] + gcn_b[c];
            op[c] = v > 0.f ? v : 0.f;
        }
    }
}

// ---------------------------------------------------------------------------
__global__ void gstart_kernel(const int* __restrict__ batch, int* __restrict__ goffs)
{
    int b = blockIdx.x*256 + threadIdx.x;
    if (b > NG) return;
    if (b == NG) { goffs[NG] = NN; return; }
    int lo = 0, hi = NN;
    while (lo < hi) { int mid = (lo+hi) >> 1; if (batch[mid] < b) lo = mid+1; else hi = mid; }
    goffs[b] = lo;
}

// pool -> bf16 d[b][1568]: [0:780)=max, [780:1560)=mean, [1560:1568)=0
__global__ __launch_bounds__(256)
void pool_kernel(const float* __restrict__ g, const int* __restrict__ goffs,
                 __bf16* __restrict__ d)
{
    int b = blockIdx.x;
    int tid = threadIdx.x;
    int s = goffs[b], e = goffs[b+1];
    float mx[4], sm[4];
#pragma unroll
    for (int j = 0; j < 4; j++) { mx[j] = -3.0e38f; sm[j] = 0.f; }
    for (int n = s; n < e; n++) {
        const float* r = g + (size_t)n*HD;
#pragma unroll
        for (int j = 0; j < 4; j++) {
            int c = tid + 256*j;
            if (c < HD) { float v = r[c]; mx[j] = fmaxf(mx[j], v); sm[j] += v; }
        }
    }
    int cnt = e - s;
    float inv = 1.f / (float)(cnt > 0 ? cnt : 1);
#pragma unroll
    for (int j = 0; j < 4; j++) {
        int c = tid + 256*j;
        if (c < HD) {
            d[(size_t)b*1568 + c]      = (__bf16)mx[j];
            d[(size_t)b*1568 + HD + c] = (__bf16)(sm[j] * inv);
        }
    }
    if (tid < 8) d[(size_t)b*1568 + 1560 + tid] = (__bf16)0.f;
}

// ---------------------------------------------------------------------------
// Protein conv, fully fused per graph:
//   W'[(k*32+o), i] = conv_w[o,i,k] (k-padded to 1024)
//   P[o'=256][c=112] = W' @ emb_b^T  computed as MFMA(A=emb cols, B=W' rows)
//   c[b,o,t] = sum_k P[k*32+o][t+k] + bias  (in-block shift-add from LDS)
// Staging: per k-step, 448 threads each gather 8 k's of one emb col (u16
// gathers, 4 rows x 32B segments/wave) and write one ds_write_b128. Double
// buffered, 1 barrier/step. A-frags = ds_read_b128 (2-way, free). B-frags =
// contiguous global bf16x8 from 512KB L2-hot W'. 14 MFMA/wave/step.
// ---------------------------------------------------------------------------
__global__ __launch_bounds__(256)
void emb_cast(const float* __restrict__ emb_w, __bf16* __restrict__ embbf)
{
    int idx = blockIdx.x*256 + threadIdx.x;
    if (idx >= 8001*112) return;
    int r = idx / 112, c = idx - (idx/112)*112;
    float v = (r < 8000 && c < EMB) ? emb_w[(size_t)r*EMB + c] : 0.f;
    embbf[idx] = (__bf16)v;
}

__global__ __launch_bounds__(256)
void conv_w_repack(const float* __restrict__ conv_w, __bf16* __restrict__ w2)
{
    int idx = blockIdx.x*256 + threadIdx.x;   // o'*1024 + i
    if (idx >= 256*1024) return;
    int op = idx >> 10, i = idx & 1023;
    int o = op & 31, k = op >> 5;
    w2[idx] = (i < SEQ) ? (__bf16)conv_w[((size_t)o*SEQ + i)*KS + k] : (__bf16)0.f;
}

#define CP 114          // P lds col stride
#define SB (112*40)     // one staging buffer, elements

__global__ __launch_bounds__(512)
void conv_gemm2(const int* __restrict__ target, const __bf16* __restrict__ embbf,
                const __bf16* __restrict__ w2, const float* __restrict__ conv_b,
                __bf16* __restrict__ cbuf)
{
    __shared__ int tg[1024];
    __shared__ __align__(16) __bf16 Pl[256*CP];   // 58.4 KB; first 17.9KB doubles as staging
    __bf16* Bs = Pl;                               // Bs[2][112*40]
    const int b = blockIdx.x;
    const int tid = threadIdx.x;
    const int w = tid >> 6, lane = tid & 63;
    const int l15 = lane & 15, lk = lane >> 4;

    for (int i = tid; i < 1024; i += 512)
        tg[i] = ((i < SEQ) ? target[b*SEQ + i] : 8000) * 112;
    __syncthreads();

    const bool st = tid < 448;
    const int sc = tid >> 2, skq = tid & 3;   // col 0..111, k-quarter 0..3

    ushort sv[8];
    auto stage_load = [&](int p) {
        if (!st) return;
        int kb = p*32 + skq*8;
        const ushort* eb = (const ushort*)embbf;
#pragma unroll
        for (int r = 0; r < 8; r++)
            sv[r] = eb[tg[kb + r] + sc];
    };
    auto stage_write = [&](int buf) {
        if (!st) return;
        *(uint4*)&Bs[buf*SB + sc*40 + skq*8] = *(uint4*)sv;
    };

    f32x4 acc[7][2];
#pragma unroll
    for (int i = 0; i < 7; i++) {
        acc[i][0] = (f32x4){0.f,0.f,0.f,0.f};
        acc[i][1] = (f32x4){0.f,0.f,0.f,0.f};
    }

    const __bf16* w2w0 = w2 + (size_t)(w*32 + l15)*1024 + lk*8;
    const __bf16* w2w1 = w2w0 + (size_t)16*1024;

    stage_load(0);
    stage_write(0);
    int cur = 0;
    for (int p = 0; p < 32; ++p) {
        __syncthreads();
        if (p+1 < 32) stage_load(p+1);
        bf16x8 bf0 = *(const bf16x8*)(w2w0 + p*32);
        bf16x8 bf1 = *(const bf16x8*)(w2w1 + p*32);
        const __bf16* bsc = Bs + cur*SB + lk*8;
#pragma unroll
        for (int mt = 0; mt < 7; mt++) {
            bf16x8 af = *(const bf16x8*)(bsc + (mt*16 + l15)*40);
            acc[mt][0] = __builtin_amdgcn_mfma_f32_16x16x32_bf16(af, bf0, acc[mt][0], 0, 0, 0);
            acc[mt][1] = __builtin_amdgcn_mfma_f32_16x16x32_bf16(af, bf1, acc[mt][1], 0, 0, 0);
        }
        if (p+1 < 32) stage_write(cur^1);
        cur ^= 1;
    }

    __syncthreads();   // staging region dead; write P over it
#pragma unroll
    for (int mt = 0; mt < 7; mt++) {
#pragma unroll
        for (int nt = 0; nt < 2; nt++) {
            int op = w*32 + nt*16 + l15;
            int c0 = mt*16 + lk*4;
            __bf16 o4[4];
#pragma unroll
            for (int rr = 0; rr < 4; rr++) o4[rr] = (__bf16)acc[mt][nt][rr];
            *(uint2*)&Pl[op*CP + c0] = *(uint2*)o4;
        }
    }
    __syncthreads();

    // shift-add: thread (o = tid&31, tg16 = tid>>5): 6 t's each
    {
        int o = tid & 31, tg16 = tid >> 5;
        float cb = conv_b[o];
#pragma unroll
        for (int j = 0; j < 6; j++) {
            int t = tg16*6 + j;
            if (t >= CLEN) continue;
            float s = cb;
#pragma unroll
            for (int k = 0; k < 8; k++)
                s += (float)Pl[(k*32 + o)*CP + t + k];
            cbuf[(size_t)b*2976 + o*CLEN + t] = (__bf16)s;
        }
    }
}

// ---------------------------------------------------------------------------
// mlp3: out[r] = dot(o2bf[r,0:512], w) + b   (wave per row)
// ---------------------------------------------------------------------------
__global__ __launch_bounds__(256)
void mlp3_dot(const __bf16* __restrict__ o2, const float* __restrict__ w,
              const float* __restrict__ bias, float* __restrict__ out)
{
    int row = blockIdx.x*4 + (threadIdx.x >> 6);
    int lane = threadIdx.x & 63;
    bf16x8 v = *(const bf16x8*)(o2 + (size_t)row*512 + lane*8);
    float4 w0 = *(const float4*)(w + lane*8);
    float4 w1 = *(const float4*)(w + lane*8 + 4);
    float s = (float)v[0]*w0.x + (float)v[1]*w0.y + (float)v[2]*w0.z + (float)v[3]*w0.w
            + (float)v[4]*w1.x + (float)v[5]*w1.y + (float)v[6]*w1.z + (float)v[7]*w1.w;
#pragma unroll
    for (int off = 32; off > 0; off >>= 1) s += __shfl_down(s, off);
    if (lane == 0) out[row] = s + bias[0];
}

// ---------------------------------------------------------------------------
extern "C" void kernel_launch(void* const* d_in, const int* in_sizes, int n_in,
                              void* d_out, int out_size, void* d_ws, size_t ws_size,
                              hipStream_t stream)
{
    const float* x      = (const float*)d_in[0];
    const int*   ei     = (const int*)  d_in[1];
    const int*   batch  = (const int*)  d_in[2];
    const int*   target = (const int*)  d_in[3];
    const float* gat_w  = (const float*)d_in[4];
    const float* att_s  = (const float*)d_in[5];
    const float* att_d  = (const float*)d_in[6];
    const float* gat_b  = (const float*)d_in[7];
    const float* gcn_w  = (const float*)d_in[8];
    const float* gcn_b  = (const float*)d_in[9];
    const float* fcg1_w = (const float*)d_in[10];
    const float* fcg1_b = (const float*)d_in[11];
    const float* fcg2_w = (const float*)d_in[12];
    const float* fcg2_b = (const float*)d_in[13];
    const float* emb_w  = (const float*)d_in[14];
    const float* conv_w = (const float*)d_in[15];
    const float* conv_b = (const float*)d_in[16];
    const float* fcxt_w = (const float*)d_in[17];
    const float* fcxt_b = (const float*)d_in[18];
    const float* mlp1_w = (const float*)d_in[19];
    const float* mlp1_b = (const float*)d_in[20];
    const float* mlp2_w = (const float*)d_in[21];
    const float* mlp2_b = (const float*)d_in[22];
    const float* mlp3_w = (const float*)d_in[23];
    const float* mlp3_b = (const float*)d_in[24];
    float* out = (float*)d_out;

    char* ws = (char*)d_ws;
    size_t off = 0;
    auto alloc = [&](size_t bytes) -> char* {
        char* p = ws + off;
        off = (off + bytes + 255) & ~(size_t)255;
        return p;
    };
    float* xh     = (float*)alloc((size_t)NN*HD*4);    // reused as hw
    float* g      = (float*)alloc((size_t)NN*HD*4);
    char*  hbf_rg = alloc((size_t)NN*800*2);           // Abf -> hbf -> splitk partial
    __bf16* Abf   = (__bf16*)hbf_rg;
    __bf16* hbf   = (__bf16*)hbf_rg;
    float* partial= (float*)hbf_rg;                    // after hbf dead
    __bf16* Btbf  = (__bf16*)alloc((size_t)896*800*2); // gat/gcn weight (seq reuse)
    __bf16* wg1   = (__bf16*)alloc((size_t)1536*1568*2);
    __bf16* wg2   = (__bf16*)alloc((size_t)128*1504*2);
    __bf16* wxt   = (__bf16*)alloc((size_t)128*2976*2);
    __bf16* wm1   = (__bf16*)alloc((size_t)1024*256*2);
    __bf16* wm2   = (__bf16*)alloc((size_t)512*1024*2);
    __bf16* convw2= (__bf16*)alloc((size_t)256*1024*2);
    __bf16* embbf = (__bf16*)alloc((size_t)8001*112*2);
    float* a_src  = (float*)alloc((size_t)NN*NH*4);
    float* a_dst  = (float*)alloc((size_t)NN*NH*4);
    int*   deg    = (int*)alloc((size_t)NN*4);
    int*   offs   = (int*)alloc((size_t)(NN+1)*4);
    int*   cursor = (int*)alloc((size_t)NN*4);
    int*   csr    = (int*)alloc((size_t)NT*4);
    float* dinv   = (float*)alloc((size_t)NN*4);
    int*   goffs  = (int*)alloc((size_t)(NG+1)*4);
    __bf16* dpool = (__bf16*)alloc((size_t)NG*1568*2);
    __bf16* d1bf  = (__bf16*)alloc((size_t)NG*1504*2);
    __bf16* cbuf  = (__bf16*)alloc((size_t)NG*NF*CLEN*2);
    __bf16* obuf  = (__bf16*)alloc((size_t)NG*256*2);
    __bf16* o1bf  = (__bf16*)alloc((size_t)NG*1024*2);
    __bf16* o2bf  = (__bf16*)alloc((size_t)NG*512*2);

    float* hw = xh;   // xh dead after gat_agg

    hipMemsetAsync(deg, 0, (size_t)NN*4, stream);

    // --- weight preprocessing (inputs only) ---
    emb_cast     <<<dim3((8001*112+255)/256), 256, 0, stream>>>(emb_w, embbf);
    conv_w_repack<<<dim3(1024), 256, 0, stream>>>(conv_w, convw2);
    cast_pad_bt<<<dim3((1536*1568)/256), 256, 0, stream>>>(fcg1_w, wg1, 1560, 1500, 1568, 1536);
    cast_pad_bt<<<dim3((128*1504)/256), 256, 0, stream>>>(fcg2_w, wg2, 1500, 128, 1504, 128);
    cast_pad_bt<<<dim3((128*2976)/256), 256, 0, stream>>>(fcxt_w, wxt, NF*CLEN, 128, 2976, 128);
    cast_pad_bt<<<dim3((1024*256)/256), 256, 0, stream>>>(mlp1_w, wm1, 256, 1024, 256, 1024);
    cast_pad_bt<<<dim3((512*1024)/256), 256, 0, stream>>>(mlp2_w, wm2, 1024, 512, 1024, 512);

    // --- protein conv (independent of graph branch; run early) ---
    conv_gemm2<<<dim3(NG), 512, 0, stream>>>(target, embbf, convw2, conv_b, cbuf);

    // --- GAT linear: xh = x @ gat_w (Kp=96), f32 out ---
    cast_pad_a <<<dim3((NN*96)/256), 256, 0, stream>>>(x, Abf, NN, FX, 96);
    cast_pad_bt<<<dim3((896*96)/256), 256, 0, stream>>>(gat_w, Btbf, FX, HD, 96, 896);
    gemm_mfma<false,false,false>
        <<<dim3(7, NN/128), 256, 0, stream>>>(Abf, Btbf, nullptr, xh, NN, HD, 96, HD, HD);
    attn_logits<<<dim3((NN*NH+255)/256), 256, 0, stream>>>(xh, att_s, att_d, a_src, a_dst);

    // --- CSR ---
    edge_count  <<<dim3(NT/256), 256, 0, stream>>>(ei, deg);
    scan_kernel <<<1, 1024, 0, stream>>>(deg, offs, cursor);
    edge_scatter<<<dim3(NT/256), 256, 0, stream>>>(ei, cursor, csr);
    dinv_kernel <<<dim3(NN/256), 256, 0, stream>>>(offs, dinv);

    // --- GAT aggregate -> hbf ---
    gat_agg<<<dim3(NN/4), 256, 0, stream>>>(xh, a_src, a_dst, gat_b, offs, csr, hbf);

    // --- GCN linear + aggregate ---
    cast_pad_bt<<<dim3((896*800)/256), 256, 0, stream>>>(gcn_w, Btbf, HD, HD, 800, 896);
    gemm_mfma<false,false,false>
        <<<dim3(7, NN/128), 256, 0, stream>>>(hbf, Btbf, nullptr, hw, NN, HD, 800, HD, HD);
    gcn_agg<<<dim3(NN/4), 256, 0, stream>>>(hw, dinv, gcn_b, offs, csr, g);

    // --- pooling ---
    gstart_kernel<<<3, 256, 0, stream>>>(batch, goffs);
    pool_kernel<<<NG, 256, 0, stream>>>(g, goffs, dpool);

    // --- FC stack via split-K (partial aliases hbf; dead after gcn gemm) ---
    gemm_mfma_splitk<<<dim3(12, 4, 4), 256, 0, stream>>>(dpool, wg1, partial, NG, 1568, 1536, 13);
    reduce_splitk<true><<<dim3((NG*(1504/4)+255)/256), 256, 0, stream>>>(partial, fcg1_b, d1bf, NG, 1500, 1536, 4, 1504, 1504);
    gemm_mfma_splitk<<<dim3(1, 4, 12), 256, 0, stream>>>(d1bf, wg2, partial, NG, 1504, 128, 4);
    reduce_splitk<false><<<dim3((NG*32+255)/256), 256, 0, stream>>>(partial, fcg2_b, obuf, NG, 128, 128, 12, 256, 128);
    gemm_mfma_splitk<<<dim3(1, 4, 24), 256, 0, stream>>>(cbuf, wxt, partial, NG, 2976, 128, 4);
    reduce_splitk<false><<<dim3((NG*32+255)/256), 256, 0, stream>>>(partial, fcxt_b, obuf + 128, NG, 128, 128, 24, 256, 128);
    gemm_mfma_splitk<<<dim3(8, 4, 2), 256, 0, stream>>>(obuf, wm1, partial, NG, 256, 1024, 4);
    reduce_splitk<true><<<dim3((NG*256+255)/256), 256, 0, stream>>>(partial, mlp1_b, o1bf, NG, 1024, 1024, 2, 1024, 1024);
    gemm_mfma_splitk<<<dim3(4, 4, 8), 256, 0, stream>>>(o1bf, wm2, partial, NG, 1024, 512, 4);
    reduce_splitk<true><<<dim3((NG*128+255)/256), 256, 0, stream>>>(partial, mlp2_b, o2bf, NG, 512, 512, 8, 512, 512);

    mlp3_dot<<<dim3(NG/4), 256, 0, stream>>>(o2bf, mlp3_w, mlp3_b, out);
}

// Round 7
// 417.236 us; speedup vs baseline: 6.5200x; 1.0997x over previous
//
#include <hip/hip_runtime.h>

#define NN 16384      // nodes
#define NE 65536      // edges
#define NT 81920      // edges + self loops
#define NG 512        // graphs
#define NH 10         // heads
#define FX 78         // features per head
#define HD 780        // hidden = NH*FX
#define SEQ 1000
#define EMB 100
#define NF 32
#define KS 8
#define CLEN 93

typedef __bf16 bf16x8 __attribute__((ext_vector_type(8)));
typedef float  f32x4  __attribute__((ext_vector_type(4)));

// ---------------------------------------------------------------------------
// bf16 cast + pad helpers
// ---------------------------------------------------------------------------
__global__ __launch_bounds__(256)
void cast_pad_a(const float* __restrict__ in, __bf16* __restrict__ out,
                int M, int K, int Kp)
{
    size_t idx = (size_t)blockIdx.x*256 + threadIdx.x;
    if (idx >= (size_t)M*Kp) return;
    int r = idx / Kp, c = idx % Kp;
    out[idx] = (c < K) ? (__bf16)in[(size_t)r*K + c] : (__bf16)0.f;
}

// B[K,N] -> Bt[Np][Kp] (transposed, zero-padded)
__global__ __launch_bounds__(256)
void cast_pad_bt(const float* __restrict__ B, __bf16* __restrict__ out,
                 int K, int N, int Kp, int Np)
{
    size_t idx = (size_t)blockIdx.x*256 + threadIdx.x;
    if (idx >= (size_t)Np*Kp) return;
    int n = idx / Kp, k = idx % Kp;
    out[idx] = (n < N && k < K) ? (__bf16)B[(size_t)k*N + n] : (__bf16)0.f;
}

// ---------------------------------------------------------------------------
// bf16 MFMA GEMM (full-K): C[M,ldc] = A[M,Kp] @ Bt[Np,Kp]^T
// ---------------------------------------------------------------------------
#define BKP 40
template<bool BIAS, bool RELU, bool BF16OUT>
__global__ __launch_bounds__(256)
void gemm_mfma(const __bf16* __restrict__ A, const __bf16* __restrict__ Bt,
               const float* __restrict__ bias, void* __restrict__ Cv,
               int M, int N, int Kp, int ldc, int Nz)
{
    __shared__ __align__(16) __bf16 As[128*BKP];
    __shared__ __align__(16) __bf16 Bs[128*BKP];
    const int tid = threadIdx.x;
    const int row0 = blockIdx.y*128, col0 = blockIdx.x*128;
    const int lane = tid & 63, wid = tid >> 6;
    const int wm = wid & 1, wn = wid >> 1;
    const int l15 = lane & 15, lk = lane >> 4;

    f32x4 acc[4][4];
#pragma unroll
    for (int i = 0; i < 4; i++)
#pragma unroll
        for (int j = 0; j < 4; j++) acc[i][j] = (f32x4){0.f,0.f,0.f,0.f};

    for (int k0 = 0; k0 < Kp; k0 += 32) {
        __syncthreads();
#pragma unroll
        for (int it = 0; it < 2; ++it) {
            int c = tid + it*256;
            int r = c >> 2, c16 = c & 3;
            uint4 va = *(const uint4*)(A  + (size_t)(row0+r)*Kp + k0 + c16*8);
            *(uint4*)&As[r*BKP + c16*8] = va;
            uint4 vb = *(const uint4*)(Bt + (size_t)(col0+r)*Kp + k0 + c16*8);
            *(uint4*)&Bs[r*BKP + c16*8] = vb;
        }
        __syncthreads();
        bf16x8 af[4], bfr[4];
#pragma unroll
        for (int i = 0; i < 4; i++) {
            af[i]  = *(const bf16x8*)&As[(wm*64 + i*16 + l15)*BKP + lk*8];
            bfr[i] = *(const bf16x8*)&Bs[(wn*64 + i*16 + l15)*BKP + lk*8];
        }
#pragma unroll
        for (int i = 0; i < 4; i++)
#pragma unroll
            for (int j = 0; j < 4; j++)
                acc[i][j] = __builtin_amdgcn_mfma_f32_16x16x32_bf16(af[i], bfr[j], acc[i][j], 0, 0, 0);
    }

#pragma unroll
    for (int i = 0; i < 4; i++) {
        int rbase = row0 + wm*64 + i*16 + lk*4;
#pragma unroll
        for (int j = 0; j < 4; j++) {
            int cc = col0 + wn*64 + j*16 + l15;
            if (cc >= Nz) continue;
            bool real = cc < N;
            float bv = (BIAS && real) ? bias[cc] : 0.f;
#pragma unroll
            for (int r = 0; r < 4; r++) {
                float v = real ? (acc[i][j][r] + bv) : 0.f;
                if (RELU) v = v > 0.f ? v : 0.f;
                if (BF16OUT) ((__bf16*)Cv)[(size_t)(rbase + r)*ldc + cc] = (__bf16)v;
                else         ((float*) Cv)[(size_t)(rbase + r)*ldc + cc] = v;
            }
        }
    }
}

// ---------------------------------------------------------------------------
// Split-K MFMA GEMM: partial[s][M][ldp] f32.
// ---------------------------------------------------------------------------
__global__ __launch_bounds__(256)
void gemm_mfma_splitk(const __bf16* __restrict__ A, const __bf16* __restrict__ Bt,
                      float* __restrict__ part, int M, int Kp, int ldp, int ksteps)
{
    __shared__ __align__(16) __bf16 As[128*BKP];
    __shared__ __align__(16) __bf16 Bs[128*BKP];
    const int tid = threadIdx.x;
    const int row0 = blockIdx.y*128, col0 = blockIdx.x*128;
    const int s = blockIdx.z;
    const int lane = tid & 63, wid = tid >> 6;
    const int wm = wid & 1, wn = wid >> 1;
    const int l15 = lane & 15, lk = lane >> 4;

    const int T = Kp >> 5;
    int kb = s*ksteps, ke = kb + ksteps;
    if (ke > T) ke = T;

    f32x4 acc[4][4];
#pragma unroll
    for (int i = 0; i < 4; i++)
#pragma unroll
        for (int j = 0; j < 4; j++) acc[i][j] = (f32x4){0.f,0.f,0.f,0.f};

    for (int kk = kb; kk < ke; kk++) {
        int k0 = kk*32;
        __syncthreads();
#pragma unroll
        for (int it = 0; it < 2; ++it) {
            int c = tid + it*256;
            int r = c >> 2, c16 = c & 3;
            uint4 va = *(const uint4*)(A  + (size_t)(row0+r)*Kp + k0 + c16*8);
            *(uint4*)&As[r*BKP + c16*8] = va;
            uint4 vb = *(const uint4*)(Bt + (size_t)(col0+r)*Kp + k0 + c16*8);
            *(uint4*)&Bs[r*BKP + c16*8] = vb;
        }
        __syncthreads();
        bf16x8 af[4], bfr[4];
#pragma unroll
        for (int i = 0; i < 4; i++) {
            af[i]  = *(const bf16x8*)&As[(wm*64 + i*16 + l15)*BKP + lk*8];
            bfr[i] = *(const bf16x8*)&Bs[(wn*64 + i*16 + l15)*BKP + lk*8];
        }
#pragma unroll
        for (int i = 0; i < 4; i++)
#pragma unroll
            for (int j = 0; j < 4; j++)
                acc[i][j] = __builtin_amdgcn_mfma_f32_16x16x32_bf16(af[i], bfr[j], acc[i][j], 0, 0, 0);
    }

#pragma unroll
    for (int i = 0; i < 4; i++) {
        int rbase = row0 + wm*64 + i*16 + lk*4;
#pragma unroll
        for (int j = 0; j < 4; j++) {
            int cc = col0 + wn*64 + j*16 + l15;
#pragma unroll
            for (int r = 0; r < 4; r++)
                part[((size_t)s*M + rbase + r)*ldp + cc] = acc[i][j][r];
        }
    }
}

// reduce S partials + bias (+relu) -> bf16 C (cols [N,Nz) zeroed)
template<bool RELU>
__global__ __launch_bounds__(256)
void reduce_splitk(const float* __restrict__ part, const float* __restrict__ bias,
                   __bf16* __restrict__ C, int M, int N, int ldp, int S,
                   int ldc, int Nz)
{
    int idx = blockIdx.x*256 + threadIdx.x;
    int nc4 = Nz >> 2;
    if (idx >= M*nc4) return;
    int r = idx / nc4, c = (idx - r*nc4)*4;
    float4 a = {0.f,0.f,0.f,0.f};
    for (int s = 0; s < S; s++) {
        float4 v = *(const float4*)(part + ((size_t)s*M + r)*ldp + c);
        a.x += v.x; a.y += v.y; a.z += v.z; a.w += v.w;
    }
    float vv[4] = {a.x, a.y, a.z, a.w};
    __bf16 o4[4];
#pragma unroll
    for (int j = 0; j < 4; j++) {
        float v = 0.f;
        if (c + j < N) {
            v = vv[j] + bias[c+j];
            if (RELU) v = v > 0.f ? v : 0.f;
        }
        o4[j] = (__bf16)v;
    }
    *(uint2*)&C[(size_t)r*ldc + c] = *(uint2*)o4;
}

// ---------------------------------------------------------------------------
// a_src[n,h], a_dst[n,h] from bf16 xh (stride 800)
// ---------------------------------------------------------------------------
__global__ __launch_bounds__(256)
void attn_logits(const __bf16* __restrict__ xh, const float* __restrict__ att_s,
                 const float* __restrict__ att_d,
                 float* __restrict__ a_src, float* __restrict__ a_dst)
{
    int idx = blockIdx.x*256 + threadIdx.x;
    if (idx >= NN*NH) return;
    int n = idx / NH, h = idx % NH;
    const __bf16* xr = xh + (size_t)n*800 + h*FX;
    const float* as = att_s + h*FX;
    const float* ad = att_d + h*FX;
    float s1 = 0.f, s2 = 0.f;
    for (int c = 0; c < FX; c++) {
        float v = (float)xr[c];
        s1 = fmaf(v, as[c], s1);
        s2 = fmaf(v, ad[c], s2);
    }
    a_src[idx] = s1;
    a_dst[idx] = s2;
}

// ---------------------------------------------------------------------------
// CSR build
// ---------------------------------------------------------------------------
__global__ void edge_count(const int* __restrict__ ei, int* __restrict__ deg)
{
    int e = blockIdx.x*256 + threadIdx.x;
    if (e >= NT) return;
    int dst = (e < NE) ? ei[NE + e] : (e - NE);
    atomicAdd(&deg[dst], 1);
}

__global__ __launch_bounds__(1024)
void scan_kernel(const int* __restrict__ deg, int* __restrict__ offs, int* __restrict__ cursor)
{
    __shared__ int part[1024];
    int tid = threadIdx.x;
    int base = tid*16;
    int v[16]; int ssum = 0;
#pragma unroll
    for (int j = 0; j < 16; j++) { v[j] = deg[base+j]; ssum += v[j]; }
    part[tid] = ssum;
    __syncthreads();
    for (int d = 1; d < 1024; d <<= 1) {
        int t = (tid >= d) ? part[tid-d] : 0;
        __syncthreads();
        part[tid] += t;
        __syncthreads();
    }
    int run = (tid == 0) ? 0 : part[tid-1];
#pragma unroll
    for (int j = 0; j < 16; j++) { offs[base+j] = run; cursor[base+j] = run; run += v[j]; }
    if (tid == 1023) offs[NN] = run;
}

__global__ void edge_scatter(const int* __restrict__ ei, int* __restrict__ cursor,
                             int* __restrict__ csr)
{
    int e = blockIdx.x*256 + threadIdx.x;
    if (e >= NT) return;
    int src, dst;
    if (e < NE) { src = ei[e]; dst = ei[NE + e]; }
    else        { src = e - NE; dst = e - NE; }
    int pos = atomicAdd(&cursor[dst], 1);
    csr[pos] = src;
}

__global__ void dinv_kernel(const int* __restrict__ offs, float* __restrict__ dinv)
{
    int n = blockIdx.x*256 + threadIdx.x;
    if (n >= NN) return;
    int d = offs[n+1] - offs[n];
    dinv[n] = rsqrtf((float)(d > 0 ? d : 1));
}

// ---------------------------------------------------------------------------
// GAT aggregation: bf16 xh gather -> bf16 h (stride 800, cols 780..799 zero)
// ---------------------------------------------------------------------------
__global__ __launch_bounds__(256)
void gat_agg(const __bf16* __restrict__ xh, const float* __restrict__ a_src,
             const float* __restrict__ a_dst, const float* __restrict__ gat_b,
             const int* __restrict__ offs, const int* __restrict__ csr,
             __bf16* __restrict__ hbf)
{
    int n = blockIdx.x*4 + (threadIdx.x >> 6);
    if (n >= NN) return;
    int lane = threadIdx.x & 63;
    bool act = lane < 60;
    int h   = act ? (lane / 6) : 0;
    int sub = act ? (lane % 6) : 0;
    int cbase = h*FX + sub*13;
    int off = offs[n], end = offs[n+1];
    float adn = a_dst[n*NH + h];

    float m = -3.0e38f;
    for (int i = off; i < end; i++) {
        int s = csr[i];
        float ev = a_src[s*NH + h] + adn;
        ev = ev > 0.f ? ev : 0.2f*ev;
        m = fmaxf(m, ev);
    }
    float den = 0.f;
    float acc[13];
#pragma unroll
    for (int j = 0; j < 13; j++) acc[j] = 0.f;
    for (int i = off; i < end; i++) {
        int s = csr[i];
        float ev = a_src[s*NH + h] + adn;
        ev = ev > 0.f ? ev : 0.2f*ev;
        float ee = __expf(ev - m);
        den += ee;
        const __bf16* xr = xh + (size_t)s*800 + cbase;
#pragma unroll
        for (int j = 0; j < 13; j++) acc[j] = fmaf((float)xr[j], ee, acc[j]);
    }
    if (act) {
        float inv = 1.f / den;
        const float* bb = gat_b + cbase;
        __bf16* op = hbf + (size_t)n*800 + cbase;
#pragma unroll
        for (int j = 0; j < 13; j++) {
            float v = fmaf(acc[j], inv, bb[j]);
            op[j] = (__bf16)(v > 0.f ? v : 0.f);
        }
    } else {
        __bf16* op = hbf + (size_t)n*800 + 780 + (lane - 60)*5;
#pragma unroll
        for (int j = 0; j < 5; j++) op[j] = (__bf16)0.f;
    }
}

// ---------------------------------------------------------------------------
// GCN aggregation: bf16 hw gather -> bf16 g (stride 780)
// ---------------------------------------------------------------------------
__global__ __launch_bounds__(256)
void gcn_agg(const __bf16* __restrict__ hw, const float* __restrict__ dinv,
             const float* __restrict__ gcn_b, const int* __restrict__ offs,
             const int* __restrict__ csr, __bf16* __restrict__ g)
{
    int n = blockIdx.x*4 + (threadIdx.x >> 6);
    if (n >= NN) return;
    int lane = threadIdx.x & 63;
    int off = offs[n], end = offs[n+1];
    float dn = dinv[n];
    float acc[13];
#pragma unroll
    for (int j = 0; j < 13; j++) acc[j] = 0.f;
    for (int i = off; i < end; i++) {
        int s = csr[i];
        float w = dinv[s] * dn;
        const __bf16* r = hw + (size_t)s*800;
#pragma unroll
        for (int j = 0; j < 13; j++) {
            int c = lane + 64*j;
            if (c < HD) acc[j] = fmaf((float)r[c], w, acc[j]);
        }
    }
    __bf16* op = g + (size_t)n*HD;
#pragma unroll
    for (int j = 0; j < 13; j++) {
        int c = lane + 64*j;
        if (c < HD) {
            float v = acc[j] + gcn_b[c];
            op[c] = (__bf16)(v > 0.f ? v : 0.f);
        }
    }
}

// ---------------------------------------------------------------------------
__global__ void gstart_kernel(const int* __restrict__ batch, int* __restrict__ goffs)
{
    int b = blockIdx.x*256 + threadIdx.x;
    if (b > NG) return;
    if (b == NG) { goffs[NG] = NN; return; }
    int lo = 0, hi = NN;
    while (lo < hi) { int mid = (lo+hi) >> 1; if (batch[mid] < b) lo = mid+1; else hi = mid; }
    goffs[b] = lo;
}

// pool (bf16 g) -> bf16 d[b][1568]: [0:780)=max, [780:1560)=mean, pad 0
__global__ __launch_bounds__(256)
void pool_kernel(const __bf16* __restrict__ g, const int* __restrict__ goffs,
                 __bf16* __restrict__ d)
{
    int b = blockIdx.x;
    int tid = threadIdx.x;
    int s = goffs[b], e = goffs[b+1];
    float mx[4], sm[4];
#pragma unroll
    for (int j = 0; j < 4; j++) { mx[j] = -3.0e38f; sm[j] = 0.f; }
    for (int n = s; n < e; n++) {
        const __bf16* r = g + (size_t)n*HD;
#pragma unroll
        for (int j = 0; j < 4; j++) {
            int c = tid + 256*j;
            if (c < HD) { float v = (float)r[c]; mx[j] = fmaxf(mx[j], v); sm[j] += v; }
        }
    }
    int cnt = e - s;
    float inv = 1.f / (float)(cnt > 0 ? cnt : 1);
#pragma unroll
    for (int j = 0; j < 4; j++) {
        int c = tid + 256*j;
        if (c < HD) {
            d[(size_t)b*1568 + c]      = (__bf16)mx[j];
            d[(size_t)b*1568 + HD + c] = (__bf16)(sm[j] * inv);
        }
    }
    if (tid < 8) d[(size_t)b*1568 + 1560 + tid] = (__bf16)0.f;
}

// ---------------------------------------------------------------------------
// Protein conv, fully fused per graph (53.2KB LDS -> 3 blocks/CU):
//   W'[(k*32+o), i] = conv_w[o,i,k] (k-padded to 1024)
//   P[o'=256][c] = W' @ emb_b^T via MFMA(A=emb cols staged LDS, B=W' rows)
//   c[b,o,t] = sum_k P[k*32+o][t+k] + bias   (t+k <= 99 -> P stride 104)
// tg (target row offsets) aliased into Pl mid-region (dead until epilogue).
// ---------------------------------------------------------------------------
__global__ __launch_bounds__(256)
void emb_cast(const float* __restrict__ emb_w, __bf16* __restrict__ embbf)
{
    int idx = blockIdx.x*256 + threadIdx.x;
    if (idx >= 8001*112) return;
    int r = idx / 112, c = idx - (idx/112)*112;
    float v = (r < 8000 && c < EMB) ? emb_w[(size_t)r*EMB + c] : 0.f;
    embbf[idx] = (__bf16)v;
}

__global__ __launch_bounds__(256)
void conv_w_repack(const float* __restrict__ conv_w, __bf16* __restrict__ w2)
{
    int idx = blockIdx.x*256 + threadIdx.x;   // o'*1024 + i
    if (idx >= 256*1024) return;
    int op = idx >> 10, i = idx & 1023;
    int o = op & 31, k = op >> 5;
    w2[idx] = (i < SEQ) ? (__bf16)conv_w[((size_t)o*SEQ + i)*KS + k] : (__bf16)0.f;
}

#define CP 104          // P lds col stride (cols 0..99 used)
#define SB (112*40)     // one staging buffer, elements

__global__ __launch_bounds__(512)
void conv_gemm2(const int* __restrict__ target, const __bf16* __restrict__ embbf,
                const __bf16* __restrict__ w2, const float* __restrict__ conv_b,
                __bf16* __restrict__ cbuf)
{
    __shared__ __align__(16) __bf16 Pl[256*CP];   // 53.2 KB total
    __bf16* Bs = Pl;                              // staging: [0, 8960)
    int* tg = (int*)&Pl[9088];                    // 1024 ints: [9088, 11136)
    const int b = blockIdx.x;
    const int tid = threadIdx.x;
    const int w = tid >> 6, lane = tid & 63;
    const int l15 = lane & 15, lk = lane >> 4;

    for (int i = tid; i < 1024; i += 512)
        tg[i] = ((i < SEQ) ? target[b*SEQ + i] : 8000) * 112;
    __syncthreads();

    const bool st = tid < 448;
    const int sc = tid >> 2, skq = tid & 3;   // col 0..111, k-quarter 0..3

    ushort sv[8];
    auto stage_load = [&](int p) {
        if (!st) return;
        int kb = p*32 + skq*8;
        const ushort* eb = (const ushort*)embbf;
#pragma unroll
        for (int r = 0; r < 8; r++)
            sv[r] = eb[tg[kb + r] + sc];
    };
    auto stage_write = [&](int buf) {
        if (!st) return;
        *(uint4*)&Bs[buf*SB + sc*40 + skq*8] = *(uint4*)sv;
    };

    f32x4 acc[7][2];
#pragma unroll
    for (int i = 0; i < 7; i++) {
        acc[i][0] = (f32x4){0.f,0.f,0.f,0.f};
        acc[i][1] = (f32x4){0.f,0.f,0.f,0.f};
    }

    const __bf16* w2w0 = w2 + (size_t)(w*32 + l15)*1024 + lk*8;
    const __bf16* w2w1 = w2w0 + (size_t)16*1024;

    stage_load(0);
    stage_write(0);
    int cur = 0;
    for (int p = 0; p < 32; ++p) {
        __syncthreads();
        if (p+1 < 32) stage_load(p+1);
        bf16x8 bf0 = *(const bf16x8*)(w2w0 + p*32);
        bf16x8 bf1 = *(const bf16x8*)(w2w1 + p*32);
        const __bf16* bsc = Bs + cur*SB + lk*8;
        __builtin_amdgcn_s_setprio(1);
#pragma unroll
        for (int mt = 0; mt < 7; mt++) {
            bf16x8 af = *(const bf16x8*)(bsc + (mt*16 + l15)*40);
            acc[mt][0] = __builtin_amdgcn_mfma_f32_16x16x32_bf16(af, bf0, acc[mt][0], 0, 0, 0);
            acc[mt][1] = __builtin_amdgcn_mfma_f32_16x16x32_bf16(af, bf1, acc[mt][1], 0, 0, 0);
        }
        __builtin_amdgcn_s_setprio(0);
        if (p+1 < 32) stage_write(cur^1);
        cur ^= 1;
    }

    __syncthreads();   // staging + tg dead; write P over it
#pragma unroll
    for (int mt = 0; mt < 7; mt++) {
#pragma unroll
        for (int nt = 0; nt < 2; nt++) {
            int op = w*32 + nt*16 + l15;
            int c0 = mt*16 + lk*4;
            if (c0 >= 100) continue;   // cols >= 100 never read
            __bf16 o4[4];
#pragma unroll
            for (int rr = 0; rr < 4; rr++) o4[rr] = (__bf16)acc[mt][nt][rr];
            *(uint2*)&Pl[op*CP + c0] = *(uint2*)o4;
        }
    }
    __syncthreads();

    // shift-add: thread (o = tid&31, tg16 = tid>>5): 6 t's each
    {
        int o = tid & 31, tg16 = tid >> 5;
        float cb = conv_b[o];
#pragma unroll
        for (int j = 0; j < 6; j++) {
            int t = tg16*6 + j;
            if (t >= CLEN) continue;
            float s = cb;
#pragma unroll
            for (int k = 0; k < 8; k++)
                s += (float)Pl[(k*32 + o)*CP + t + k];
            cbuf[(size_t)b*2976 + o*CLEN + t] = (__bf16)s;
        }
    }
}

// ---------------------------------------------------------------------------
// mlp3: out[r] = dot(o2bf[r,0:512], w) + b   (wave per row)
// ---------------------------------------------------------------------------
__global__ __launch_bounds__(256)
void mlp3_dot(const __bf16* __restrict__ o2, const float* __restrict__ w,
              const float* __restrict__ bias, float* __restrict__ out)
{
    int row = blockIdx.x*4 + (threadIdx.x >> 6);
    int lane = threadIdx.x & 63;
    bf16x8 v = *(const bf16x8*)(o2 + (size_t)row*512 + lane*8);
    float4 w0 = *(const float4*)(w + lane*8);
    float4 w1 = *(const float4*)(w + lane*8 + 4);
    float s = (float)v[0]*w0.x + (float)v[1]*w0.y + (float)v[2]*w0.z + (float)v[3]*w0.w
            + (float)v[4]*w1.x + (float)v[5]*w1.y + (float)v[6]*w1.z + (float)v[7]*w1.w;
#pragma unroll
    for (int off = 32; off > 0; off >>= 1) s += __shfl_down(s, off);
    if (lane == 0) out[row] = s + bias[0];
}

// ---------------------------------------------------------------------------
extern "C" void kernel_launch(void* const* d_in, const int* in_sizes, int n_in,
                              void* d_out, int out_size, void* d_ws, size_t ws_size,
                              hipStream_t stream)
{
    const float* x      = (const float*)d_in[0];
    const int*   ei     = (const int*)  d_in[1];
    const int*   batch  = (const int*)  d_in[2];
    const int*   target = (const int*)  d_in[3];
    const float* gat_w  = (const float*)d_in[4];
    const float* att_s  = (const float*)d_in[5];
    const float* att_d  = (const float*)d_in[6];
    const float* gat_b  = (const float*)d_in[7];
    const float* gcn_w  = (const float*)d_in[8];
    const float* gcn_b  = (const float*)d_in[9];
    const float* fcg1_w = (const float*)d_in[10];
    const float* fcg1_b = (const float*)d_in[11];
    const float* fcg2_w = (const float*)d_in[12];
    const float* fcg2_b = (const float*)d_in[13];
    const float* emb_w  = (const float*)d_in[14];
    const float* conv_w = (const float*)d_in[15];
    const float* conv_b = (const float*)d_in[16];
    const float* fcxt_w = (const float*)d_in[17];
    const float* fcxt_b = (const float*)d_in[18];
    const float* mlp1_w = (const float*)d_in[19];
    const float* mlp1_b = (const float*)d_in[20];
    const float* mlp2_w = (const float*)d_in[21];
    const float* mlp2_b = (const float*)d_in[22];
    const float* mlp3_w = (const float*)d_in[23];
    const float* mlp3_b = (const float*)d_in[24];
    float* out = (float*)d_out;

    char* ws = (char*)d_ws;
    size_t off = 0;
    auto alloc = [&](size_t bytes) -> char* {
        char* p = ws + off;
        off = (off + bytes + 255) & ~(size_t)255;
        return p;
    };
    __bf16* xhbf  = (__bf16*)alloc((size_t)NN*800*2);  // xh bf16, reused as hw bf16
    __bf16* g     = (__bf16*)alloc((size_t)NN*HD*2);
    char*  hbf_rg = alloc((size_t)NN*800*2);           // Abf -> hbf -> splitk partial
    __bf16* Abf   = (__bf16*)hbf_rg;
    __bf16* hbf   = (__bf16*)hbf_rg;
    float* partial= (float*)hbf_rg;                    // after hbf dead
    __bf16* Btbf  = (__bf16*)alloc((size_t)896*800*2); // gat/gcn weight (seq reuse)
    __bf16* wg1   = (__bf16*)alloc((size_t)1536*1568*2);
    __bf16* wg2   = (__bf16*)alloc((size_t)128*1504*2);
    __bf16* wxt   = (__bf16*)alloc((size_t)128*2976*2);
    __bf16* wm1   = (__bf16*)alloc((size_t)1024*256*2);
    __bf16* wm2   = (__bf16*)alloc((size_t)512*1024*2);
    __bf16* convw2= (__bf16*)alloc((size_t)256*1024*2);
    __bf16* embbf = (__bf16*)alloc((size_t)8001*112*2);
    float* a_src  = (float*)alloc((size_t)NN*NH*4);
    float* a_dst  = (float*)alloc((size_t)NN*NH*4);
    int*   deg    = (int*)alloc((size_t)NN*4);
    int*   offs   = (int*)alloc((size_t)(NN+1)*4);
    int*   cursor = (int*)alloc((size_t)NN*4);
    int*   csr    = (int*)alloc((size_t)NT*4);
    float* dinv   = (float*)alloc((size_t)NN*4);
    int*   goffs  = (int*)alloc((size_t)(NG+1)*4);
    __bf16* dpool = (__bf16*)alloc((size_t)NG*1568*2);
    __bf16* d1bf  = (__bf16*)alloc((size_t)NG*1504*2);
    __bf16* cbuf  = (__bf16*)alloc((size_t)NG*NF*CLEN*2);
    __bf16* obuf  = (__bf16*)alloc((size_t)NG*256*2);
    __bf16* o1bf  = (__bf16*)alloc((size_t)NG*1024*2);
    __bf16* o2bf  = (__bf16*)alloc((size_t)NG*512*2);

    __bf16* hwbf = xhbf;   // xh dead after gat_agg

    hipMemsetAsync(deg, 0, (size_t)NN*4, stream);

    // --- weight preprocessing (inputs only) ---
    emb_cast     <<<dim3((8001*112+255)/256), 256, 0, stream>>>(emb_w, embbf);
    conv_w_repack<<<dim3(1024), 256, 0, stream>>>(conv_w, convw2);
    cast_pad_bt<<<dim3((1536*1568)/256), 256, 0, stream>>>(fcg1_w, wg1, 1560, 1500, 1568, 1536);
    cast_pad_bt<<<dim3((128*1504)/256), 256, 0, stream>>>(fcg2_w, wg2, 1500, 128, 1504, 128);
    cast_pad_bt<<<dim3((128*2976)/256), 256, 0, stream>>>(fcxt_w, wxt, NF*CLEN, 128, 2976, 128);
    cast_pad_bt<<<dim3((1024*256)/256), 256, 0, stream>>>(mlp1_w, wm1, 256, 1024, 256, 1024);
    cast_pad_bt<<<dim3((512*1024)/256), 256, 0, stream>>>(mlp2_w, wm2, 1024, 512, 1024, 512);

    // --- protein conv (independent of graph branch; run early) ---
    conv_gemm2<<<dim3(NG), 512, 0, stream>>>(target, embbf, convw2, conv_b, cbuf);

    // --- GAT linear: xh = x @ gat_w (Kp=96), bf16 out stride 800 ---
    cast_pad_a <<<dim3((NN*96)/256), 256, 0, stream>>>(x, Abf, NN, FX, 96);
    cast_pad_bt<<<dim3((896*96)/256), 256, 0, stream>>>(gat_w, Btbf, FX, HD, 96, 896);
    gemm_mfma<false,false,true>
        <<<dim3(7, NN/128), 256, 0, stream>>>(Abf, Btbf, nullptr, xhbf, NN, HD, 96, 800, 800);
    attn_logits<<<dim3((NN*NH+255)/256), 256, 0, stream>>>(xhbf, att_s, att_d, a_src, a_dst);

    // --- CSR ---
    edge_count  <<<dim3(NT/256), 256, 0, stream>>>(ei, deg);
    scan_kernel <<<1, 1024, 0, stream>>>(deg, offs, cursor);
    edge_scatter<<<dim3(NT/256), 256, 0, stream>>>(ei, cursor, csr);
    dinv_kernel <<<dim3(NN/256), 256, 0, stream>>>(offs, dinv);

    // --- GAT aggregate -> hbf ---
    gat_agg<<<dim3(NN/4), 256, 0, stream>>>(xhbf, a_src, a_dst, gat_b, offs, csr, hbf);

    // --- GCN linear (bf16 out) + aggregate (bf16 g) ---
    cast_pad_bt<<<dim3((896*800)/256), 256, 0, stream>>>(gcn_w, Btbf, HD, HD, 800, 896);
    gemm_mfma<false,false,true>
        <<<dim3(7, NN/128), 256, 0, stream>>>(hbf, Btbf, nullptr, hwbf, NN, HD, 800, 800, 800);
    gcn_agg<<<dim3(NN/4), 256, 0, stream>>>(hwbf, dinv, gcn_b, offs, csr, g);

    // --- pooling ---
    gstart_kernel<<<3, 256, 0, stream>>>(batch, goffs);
    pool_kernel<<<NG, 256, 0, stream>>>(g, goffs, dpool);

    // --- FC stack via split-K (partial aliases hbf; dead after gcn gemm) ---
    gemm_mfma_splitk<<<dim3(12, 4, 4), 256, 0, stream>>>(dpool, wg1, partial, NG, 1568, 1536, 13);
    reduce_splitk<true><<<dim3((NG*(1504/4)+255)/256), 256, 0, stream>>>(partial, fcg1_b, d1bf, NG, 1500, 1536, 4, 1504, 1504);
    gemm_mfma_splitk<<<dim3(1, 4, 12), 256, 0, stream>>>(d1bf, wg2, partial, NG, 1504, 128, 4);
    reduce_splitk<false><<<dim3((NG*32+255)/256), 256, 0, stream>>>(partial, fcg2_b, obuf, NG, 128, 128, 12, 256, 128);
    gemm_mfma_splitk<<<dim3(1, 4, 24), 256, 0, stream>>>(cbuf, wxt, partial, NG, 2976, 128, 4);
    reduce_splitk<false><<<dim3((NG*32+255)/256), 256, 0, stream>>>(partial, fcxt_b, obuf + 128, NG, 128, 128, 24, 256, 128);
    gemm_mfma_splitk<<<dim3(8, 4, 2), 256, 0, stream>>>(obuf, wm1, partial, NG, 256, 1024, 4);
    reduce_splitk<true><<<dim3((NG*256+255)/256), 256, 0, stream>>>(partial, mlp1_b, o1bf, NG, 1024, 1024, 2, 1024, 1024);
    gemm_mfma_splitk<<<dim3(4, 4, 8), 256, 0, stream>>>(o1bf, wm2, partial, NG, 1024, 512, 4);
    reduce_splitk<true><<<dim3((NG*128+255)/256), 256, 0, stream>>>(partial, mlp2_b, o2bf, NG, 512, 512, 8, 512, 512);

    mlp3_dot<<<dim3(NG/4), 256, 0, stream>>>(o2bf, mlp3_w, mlp3_b, out);
}

// Round 8
// 382.144 us; speedup vs baseline: 7.1187x; 1.0918x over previous
//
#include <hip/hip_runtime.h>

#define NN 16384      // nodes
#define NE 65536      // edges
#define NT 81920      // edges + self loops
#define NG 512        // graphs
#define NH 10         // heads
#define FX 78         // features per head
#define HD 780        // hidden = NH*FX
#define SEQ 1000
#define EMB 100
#define NF 32
#define KS 8
#define CLEN 93

typedef __bf16 bf16x8 __attribute__((ext_vector_type(8)));
typedef float  f32x4  __attribute__((ext_vector_type(4)));

// ---------------------------------------------------------------------------
// One mega-kernel for ALL input-only transforms (casts/repacks/gstart).
// ---------------------------------------------------------------------------
__device__ inline void bt_one(const float* __restrict__ B, __bf16* __restrict__ out,
                              long idx, int K, int N, int Kp)
{
    int n = idx / Kp, k = idx - (long)(idx / Kp)*Kp;
    out[idx] = (n < N && k < K) ? (__bf16)B[(size_t)k*N + n] : (__bf16)0.f;
}

__global__ __launch_bounds__(256)
void preproc_all(const float* __restrict__ emb_w, __bf16* __restrict__ embbf,
                 const float* __restrict__ conv_w, __bf16* __restrict__ w2,
                 const float* __restrict__ fcg1_w, __bf16* __restrict__ wg1,
                 const float* __restrict__ fcg2_w, __bf16* __restrict__ wg2,
                 const float* __restrict__ fcxt_w, __bf16* __restrict__ wxt,
                 const float* __restrict__ mlp1_w, __bf16* __restrict__ wm1,
                 const float* __restrict__ mlp2_w, __bf16* __restrict__ wm2,
                 const float* __restrict__ x, __bf16* __restrict__ Abf,
                 const float* __restrict__ gat_w, __bf16* __restrict__ wgat,
                 const float* __restrict__ gcn_w, __bf16* __restrict__ wgcn,
                 const int* __restrict__ batch, int* __restrict__ goffs)
{
    long idx = (long)blockIdx.x*256 + threadIdx.x;
    // s0: emb table bf16, [8001][112], row 8000 + cols>=100 zero
    if (idx < 896112L) {
        int r = idx / 112, c = idx - (long)(idx/112)*112;
        embbf[idx] = (__bf16)((r < 8000 && c < EMB) ? emb_w[(size_t)r*EMB + c] : 0.f);
        return;
    }
    idx -= 896112L;
    // s1: conv W' repack [256][1024]
    if (idx < 262144L) {
        int op = idx >> 10, i = idx & 1023;
        int o = op & 31, k = op >> 5;
        w2[idx] = (i < SEQ) ? (__bf16)conv_w[((size_t)o*SEQ + i)*KS + k] : (__bf16)0.f;
        return;
    }
    idx -= 262144L;
    if (idx < 2408448L) { bt_one(fcg1_w, wg1, idx, 1560, 1500, 1568); return; }
    idx -= 2408448L;
    if (idx < 192512L)  { bt_one(fcg2_w, wg2, idx, 1500, 128, 1504); return; }
    idx -= 192512L;
    if (idx < 380928L)  { bt_one(fcxt_w, wxt, idx, 2976, 128, 2976); return; }
    idx -= 380928L;
    if (idx < 262144L)  { bt_one(mlp1_w, wm1, idx, 256, 1024, 256); return; }
    idx -= 262144L;
    if (idx < 524288L)  { bt_one(mlp2_w, wm2, idx, 1024, 512, 1024); return; }
    idx -= 524288L;
    // s7: A cast for gat gemm: x[NN][78] -> Abf[NN][96]
    if (idx < 1572864L) {
        int r = idx / 96, c = idx - (long)(idx/96)*96;
        Abf[idx] = (c < FX) ? (__bf16)x[(size_t)r*FX + c] : (__bf16)0.f;
        return;
    }
    idx -= 1572864L;
    if (idx < 86016L)   { bt_one(gat_w, wgat, idx, 78, 780, 96); return; }
    idx -= 86016L;
    if (idx < 716800L)  { bt_one(gcn_w, wgcn, idx, 780, 780, 800); return; }
    idx -= 716800L;
    // tail: per-graph start offsets via binary search on sorted batch
    if (idx <= NG) {
        int b = (int)idx;
        if (b == NG) { goffs[NG] = NN; return; }
        int lo = 0, hi = NN;
        while (lo < hi) { int mid = (lo+hi) >> 1; if (batch[mid] < b) lo = mid+1; else hi = mid; }
        goffs[b] = lo;
    }
}
#define PRE_TOTAL 7302256L
#define PRE_BLOCKS ((PRE_TOTAL + 513 + 255) / 256)

// ---------------------------------------------------------------------------
// bf16 MFMA GEMM (full-K): C[M,ldc] = A[M,Kp] @ Bt[Np,Kp]^T
// ---------------------------------------------------------------------------
#define BKP 40
template<bool BIAS, bool RELU, bool BF16OUT>
__global__ __launch_bounds__(256)
void gemm_mfma(const __bf16* __restrict__ A, const __bf16* __restrict__ Bt,
               const float* __restrict__ bias, void* __restrict__ Cv,
               int M, int N, int Kp, int ldc, int Nz)
{
    __shared__ __align__(16) __bf16 As[128*BKP];
    __shared__ __align__(16) __bf16 Bs[128*BKP];
    const int tid = threadIdx.x;
    const int row0 = blockIdx.y*128, col0 = blockIdx.x*128;
    const int lane = tid & 63, wid = tid >> 6;
    const int wm = wid & 1, wn = wid >> 1;
    const int l15 = lane & 15, lk = lane >> 4;

    f32x4 acc[4][4];
#pragma unroll
    for (int i = 0; i < 4; i++)
#pragma unroll
        for (int j = 0; j < 4; j++) acc[i][j] = (f32x4){0.f,0.f,0.f,0.f};

    for (int k0 = 0; k0 < Kp; k0 += 32) {
        __syncthreads();
#pragma unroll
        for (int it = 0; it < 2; ++it) {
            int c = tid + it*256;
            int r = c >> 2, c16 = c & 3;
            uint4 va = *(const uint4*)(A  + (size_t)(row0+r)*Kp + k0 + c16*8);
            *(uint4*)&As[r*BKP + c16*8] = va;
            uint4 vb = *(const uint4*)(Bt + (size_t)(col0+r)*Kp + k0 + c16*8);
            *(uint4*)&Bs[r*BKP + c16*8] = vb;
        }
        __syncthreads();
        bf16x8 af[4], bfr[4];
#pragma unroll
        for (int i = 0; i < 4; i++) {
            af[i]  = *(const bf16x8*)&As[(wm*64 + i*16 + l15)*BKP + lk*8];
            bfr[i] = *(const bf16x8*)&Bs[(wn*64 + i*16 + l15)*BKP + lk*8];
        }
#pragma unroll
        for (int i = 0; i < 4; i++)
#pragma unroll
            for (int j = 0; j < 4; j++)
                acc[i][j] = __builtin_amdgcn_mfma_f32_16x16x32_bf16(af[i], bfr[j], acc[i][j], 0, 0, 0);
    }

#pragma unroll
    for (int i = 0; i < 4; i++) {
        int rbase = row0 + wm*64 + i*16 + lk*4;
#pragma unroll
        for (int j = 0; j < 4; j++) {
            int cc = col0 + wn*64 + j*16 + l15;
            if (cc >= Nz) continue;
            bool real = cc < N;
            float bv = (BIAS && real) ? bias[cc] : 0.f;
#pragma unroll
            for (int r = 0; r < 4; r++) {
                float v = real ? (acc[i][j][r] + bv) : 0.f;
                if (RELU) v = v > 0.f ? v : 0.f;
                if (BF16OUT) ((__bf16*)Cv)[(size_t)(rbase + r)*ldc + cc] = (__bf16)v;
                else         ((float*) Cv)[(size_t)(rbase + r)*ldc + cc] = v;
            }
        }
    }
}

// ---------------------------------------------------------------------------
// Split-K MFMA GEMM: partial[s][M][ldp] f32.
// ---------------------------------------------------------------------------
__global__ __launch_bounds__(256)
void gemm_mfma_splitk(const __bf16* __restrict__ A, const __bf16* __restrict__ Bt,
                      float* __restrict__ part, int M, int Kp, int ldp, int ksteps)
{
    __shared__ __align__(16) __bf16 As[128*BKP];
    __shared__ __align__(16) __bf16 Bs[128*BKP];
    const int tid = threadIdx.x;
    const int row0 = blockIdx.y*128, col0 = blockIdx.x*128;
    const int s = blockIdx.z;
    const int lane = tid & 63, wid = tid >> 6;
    const int wm = wid & 1, wn = wid >> 1;
    const int l15 = lane & 15, lk = lane >> 4;

    const int T = Kp >> 5;
    int kb = s*ksteps, ke = kb + ksteps;
    if (ke > T) ke = T;

    f32x4 acc[4][4];
#pragma unroll
    for (int i = 0; i < 4; i++)
#pragma unroll
        for (int j = 0; j < 4; j++) acc[i][j] = (f32x4){0.f,0.f,0.f,0.f};

    for (int kk = kb; kk < ke; kk++) {
        int k0 = kk*32;
        __syncthreads();
#pragma unroll
        for (int it = 0; it < 2; ++it) {
            int c = tid + it*256;
            int r = c >> 2, c16 = c & 3;
            uint4 va = *(const uint4*)(A  + (size_t)(row0+r)*Kp + k0 + c16*8);
            *(uint4*)&As[r*BKP + c16*8] = va;
            uint4 vb = *(const uint4*)(Bt + (size_t)(col0+r)*Kp + k0 + c16*8);
            *(uint4*)&Bs[r*BKP + c16*8] = vb;
        }
        __syncthreads();
        bf16x8 af[4], bfr[4];
#pragma unroll
        for (int i = 0; i < 4; i++) {
            af[i]  = *(const bf16x8*)&As[(wm*64 + i*16 + l15)*BKP + lk*8];
            bfr[i] = *(const bf16x8*)&Bs[(wn*64 + i*16 + l15)*BKP + lk*8];
        }
#pragma unroll
        for (int i = 0; i < 4; i++)
#pragma unroll
            for (int j = 0; j < 4; j++)
                acc[i][j] = __builtin_amdgcn_mfma_f32_16x16x32_bf16(af[i], bfr[j], acc[i][j], 0, 0, 0);
    }

#pragma unroll
    for (int i = 0; i < 4; i++) {
        int rbase = row0 + wm*64 + i*16 + lk*4;
#pragma unroll
        for (int j = 0; j < 4; j++) {
            int cc = col0 + wn*64 + j*16 + l15;
#pragma unroll
            for (int r = 0; r < 4; r++)
                part[((size_t)s*M + rbase + r)*ldp + cc] = acc[i][j][r];
        }
    }
}

// reduce S partials + bias (+relu) -> bf16 C (cols [N,Nz) zeroed)
template<bool RELU>
__global__ __launch_bounds__(256)
void reduce_splitk(const float* __restrict__ part, const float* __restrict__ bias,
                   __bf16* __restrict__ C, int M, int N, int ldp, int S,
                   int ldc, int Nz)
{
    int idx = blockIdx.x*256 + threadIdx.x;
    int nc4 = Nz >> 2;
    if (idx >= M*nc4) return;
    int r = idx / nc4, c = (idx - r*nc4)*4;
    float4 a = {0.f,0.f,0.f,0.f};
    for (int s = 0; s < S; s++) {
        float4 v = *(const float4*)(part + ((size_t)s*M + r)*ldp + c);
        a.x += v.x; a.y += v.y; a.z += v.z; a.w += v.w;
    }
    float vv[4] = {a.x, a.y, a.z, a.w};
    __bf16 o4[4];
#pragma unroll
    for (int j = 0; j < 4; j++) {
        float v = 0.f;
        if (c + j < N) {
            v = vv[j] + bias[c+j];
            if (RELU) v = v > 0.f ? v : 0.f;
        }
        o4[j] = (__bf16)v;
    }
    *(uint2*)&C[(size_t)r*ldc + c] = *(uint2*)o4;
}

// ---------------------------------------------------------------------------
// a_src[n,h], a_dst[n,h] from bf16 xh (stride 800)
// ---------------------------------------------------------------------------
__global__ __launch_bounds__(256)
void attn_logits(const __bf16* __restrict__ xh, const float* __restrict__ att_s,
                 const float* __restrict__ att_d,
                 float* __restrict__ a_src, float* __restrict__ a_dst)
{
    int idx = blockIdx.x*256 + threadIdx.x;
    if (idx >= NN*NH) return;
    int n = idx / NH, h = idx % NH;
    const __bf16* xr = xh + (size_t)n*800 + h*FX;
    const float* as = att_s + h*FX;
    const float* ad = att_d + h*FX;
    float s1 = 0.f, s2 = 0.f;
    for (int c = 0; c < FX; c++) {
        float v = (float)xr[c];
        s1 = fmaf(v, as[c], s1);
        s2 = fmaf(v, ad[c], s2);
    }
    a_src[idx] = s1;
    a_dst[idx] = s2;
}

// ---------------------------------------------------------------------------
// CSR build
// ---------------------------------------------------------------------------
__global__ void edge_count(const int* __restrict__ ei, int* __restrict__ deg)
{
    int e = blockIdx.x*256 + threadIdx.x;
    if (e >= NT) return;
    int dst = (e < NE) ? ei[NE + e] : (e - NE);
    atomicAdd(&deg[dst], 1);
}

__global__ __launch_bounds__(1024)
void scan_kernel(const int* __restrict__ deg, int* __restrict__ offs,
                 int* __restrict__ cursor, float* __restrict__ dinv)
{
    __shared__ int part[1024];
    int tid = threadIdx.x;
    int base = tid*16;
    int v[16]; int ssum = 0;
#pragma unroll
    for (int j = 0; j < 16; j++) {
        v[j] = deg[base+j];
        dinv[base+j] = rsqrtf((float)(v[j] > 0 ? v[j] : 1));
        ssum += v[j];
    }
    part[tid] = ssum;
    __syncthreads();
    for (int d = 1; d < 1024; d <<= 1) {
        int t = (tid >= d) ? part[tid-d] : 0;
        __syncthreads();
        part[tid] += t;
        __syncthreads();
    }
    int run = (tid == 0) ? 0 : part[tid-1];
#pragma unroll
    for (int j = 0; j < 16; j++) { offs[base+j] = run; cursor[base+j] = run; run += v[j]; }
    if (tid == 1023) offs[NN] = run;
}

__global__ void edge_scatter(const int* __restrict__ ei, int* __restrict__ cursor,
                             int* __restrict__ csr)
{
    int e = blockIdx.x*256 + threadIdx.x;
    if (e >= NT) return;
    int src, dst;
    if (e < NE) { src = ei[e]; dst = ei[NE + e]; }
    else        { src = e - NE; dst = e - NE; }
    int pos = atomicAdd(&cursor[dst], 1);
    csr[pos] = src;
}

// ---------------------------------------------------------------------------
// GAT aggregation: bf16 xh gather -> bf16 h (stride 800, cols 780..799 zero)
// ---------------------------------------------------------------------------
__global__ __launch_bounds__(256)
void gat_agg(const __bf16* __restrict__ xh, const float* __restrict__ a_src,
             const float* __restrict__ a_dst, const float* __restrict__ gat_b,
             const int* __restrict__ offs, const int* __restrict__ csr,
             __bf16* __restrict__ hbf)
{
    int n = blockIdx.x*4 + (threadIdx.x >> 6);
    if (n >= NN) return;
    int lane = threadIdx.x & 63;
    bool act = lane < 60;
    int h   = act ? (lane / 6) : 0;
    int sub = act ? (lane % 6) : 0;
    int cbase = h*FX + sub*13;
    int off = offs[n], end = offs[n+1];
    float adn = a_dst[n*NH + h];

    float m = -3.0e38f;
    for (int i = off; i < end; i++) {
        int s = csr[i];
        float ev = a_src[s*NH + h] + adn;
        ev = ev > 0.f ? ev : 0.2f*ev;
        m = fmaxf(m, ev);
    }
    float den = 0.f;
    float acc[13];
#pragma unroll
    for (int j = 0; j < 13; j++) acc[j] = 0.f;
    for (int i = off; i < end; i++) {
        int s = csr[i];
        float ev = a_src[s*NH + h] + adn;
        ev = ev > 0.f ? ev : 0.2f*ev;
        float ee = __expf(ev - m);
        den += ee;
        const __bf16* xr = xh + (size_t)s*800 + cbase;
#pragma unroll
        for (int j = 0; j < 13; j++) acc[j] = fmaf((float)xr[j], ee, acc[j]);
    }
    if (act) {
        float inv = 1.f / den;
        const float* bb = gat_b + cbase;
        __bf16* op = hbf + (size_t)n*800 + cbase;
#pragma unroll
        for (int j = 0; j < 13; j++) {
            float v = fmaf(acc[j], inv, bb[j]);
            op[j] = (__bf16)(v > 0.f ? v : 0.f);
        }
    } else {
        __bf16* op = hbf + (size_t)n*800 + 780 + (lane - 60)*5;
#pragma unroll
        for (int j = 0; j < 5; j++) op[j] = (__bf16)0.f;
    }
}

// ---------------------------------------------------------------------------
// GCN aggregation: bf16 hw gather -> bf16 g (stride 780)
// ---------------------------------------------------------------------------
__global__ __launch_bounds__(256)
void gcn_agg(const __bf16* __restrict__ hw, const float* __restrict__ dinv,
             const float* __restrict__ gcn_b, const int* __restrict__ offs,
             const int* __restrict__ csr, __bf16* __restrict__ g)
{
    int n = blockIdx.x*4 + (threadIdx.x >> 6);
    if (n >= NN) return;
    int lane = threadIdx.x & 63;
    int off = offs[n], end = offs[n+1];
    float dn = dinv[n];
    float acc[13];
#pragma unroll
    for (int j = 0; j < 13; j++) acc[j] = 0.f;
    for (int i = off; i < end; i++) {
        int s = csr[i];
        float w = dinv[s] * dn;
        const __bf16* r = hw + (size_t)s*800;
#pragma unroll
        for (int j = 0; j < 13; j++) {
            int c = lane + 64*j;
            if (c < HD) acc[j] = fmaf((float)r[c], w, acc[j]);
        }
    }
    __bf16* op = g + (size_t)n*HD;
#pragma unroll
    for (int j = 0; j < 13; j++) {
        int c = lane + 64*j;
        if (c < HD) {
            float v = acc[j] + gcn_b[c];
            op[c] = (__bf16)(v > 0.f ? v : 0.f);
        }
    }
}

// pool (bf16 g) -> bf16 d[b][1568]: [0:780)=max, [780:1560)=mean, pad 0
__global__ __launch_bounds__(256)
void pool_kernel(const __bf16* __restrict__ g, const int* __restrict__ goffs,
                 __bf16* __restrict__ d)
{
    int b = blockIdx.x;
    int tid = threadIdx.x;
    int s = goffs[b], e = goffs[b+1];
    float mx[4], sm[4];
#pragma unroll
    for (int j = 0; j < 4; j++) { mx[j] = -3.0e38f; sm[j] = 0.f; }
    for (int n = s; n < e; n++) {
        const __bf16* r = g + (size_t)n*HD;
#pragma unroll
        for (int j = 0; j < 4; j++) {
            int c = tid + 256*j;
            if (c < HD) { float v = (float)r[c]; mx[j] = fmaxf(mx[j], v); sm[j] += v; }
        }
    }
    int cnt = e - s;
    float inv = 1.f / (float)(cnt > 0 ? cnt : 1);
#pragma unroll
    for (int j = 0; j < 4; j++) {
        int c = tid + 256*j;
        if (c < HD) {
            d[(size_t)b*1568 + c]      = (__bf16)mx[j];
            d[(size_t)b*1568 + HD + c] = (__bf16)(sm[j] * inv);
        }
    }
    if (tid < 8) d[(size_t)b*1568 + 1560 + tid] = (__bf16)0.f;
}

// ---------------------------------------------------------------------------
// Protein conv, fully fused per graph.
// Staging v2 (TA-friendly): thread (sr = tid&31, sch = tid>>5 < 14) loads ONE
// uint4 = 8 contiguous bf16 of emb row tg[p*32+sr], cols sch*8..+7 (7 vmem
// instrs/block-phase instead of 56 scalar gathers), then 8 transposed
// ds_write_u16 into Bs[col][k] (stride 40). MFMA reads unchanged.
// ---------------------------------------------------------------------------
#define CP 104          // P lds col stride (cols 0..99 used)
#define SB (112*40)     // one staging buffer, elements

__global__ __launch_bounds__(512)
void conv_gemm2(const int* __restrict__ target, const __bf16* __restrict__ embbf,
                const __bf16* __restrict__ w2, const float* __restrict__ conv_b,
                __bf16* __restrict__ cbuf)
{
    __shared__ __align__(16) __bf16 Pl[256*CP];   // 53.2 KB total
    __bf16* Bs = Pl;                              // staging: elems [0, 8960)
    int* tg = (int*)&Pl[2*SB];                    // 1024 ints: elems [8960,11008)
    const int b = blockIdx.x;
    const int tid = threadIdx.x;
    const int w = tid >> 6, lane = tid & 63;
    const int l15 = lane & 15, lk = lane >> 4;

    for (int i = tid; i < 1024; i += 512)
        tg[i] = ((i < SEQ) ? target[b*SEQ + i] : 8000) * 112;
    __syncthreads();

    const bool st = tid < 448;
    const int sr  = tid & 31;    // k-row within 32-tile
    const int sch = tid >> 5;    // col chunk 0..13 (8 cols each)

    uint4 sv;
    auto stage_load = [&](int p) {
        if (!st) return;
        sv = *(const uint4*)((const ushort*)embbf + tg[p*32 + sr] + sch*8);
    };
    auto stage_write = [&](int buf) {
        if (!st) return;
        const __bf16* s8 = (const __bf16*)&sv;
        __bf16* base = &Bs[buf*SB + (sch*8)*40 + sr];
#pragma unroll
        for (int j = 0; j < 8; j++) base[j*40] = s8[j];
    };

    f32x4 acc[7][2];
#pragma unroll
    for (int i = 0; i < 7; i++) {
        acc[i][0] = (f32x4){0.f,0.f,0.f,0.f};
        acc[i][1] = (f32x4){0.f,0.f,0.f,0.f};
    }

    const __bf16* w2w0 = w2 + (size_t)(w*32 + l15)*1024 + lk*8;
    const __bf16* w2w1 = w2w0 + (size_t)16*1024;

    stage_load(0);
    stage_write(0);
    int cur = 0;
    for (int p = 0; p < 32; ++p) {
        __syncthreads();
        if (p+1 < 32) stage_load(p+1);
        bf16x8 bf0 = *(const bf16x8*)(w2w0 + p*32);
        bf16x8 bf1 = *(const bf16x8*)(w2w1 + p*32);
        const __bf16* bsc = Bs + cur*SB + lk*8;
        __builtin_amdgcn_s_setprio(1);
#pragma unroll
        for (int mt = 0; mt < 7; mt++) {
            bf16x8 af = *(const bf16x8*)(bsc + (mt*16 + l15)*40);
            acc[mt][0] = __builtin_amdgcn_mfma_f32_16x16x32_bf16(af, bf0, acc[mt][0], 0, 0, 0);
            acc[mt][1] = __builtin_amdgcn_mfma_f32_16x16x32_bf16(af, bf1, acc[mt][1], 0, 0, 0);
        }
        __builtin_amdgcn_s_setprio(0);
        if (p+1 < 32) stage_write(cur^1);
        cur ^= 1;
    }

    __syncthreads();   // staging + tg dead; write P over it
#pragma unroll
    for (int mt = 0; mt < 7; mt++) {
#pragma unroll
        for (int nt = 0; nt < 2; nt++) {
            int op = w*32 + nt*16 + l15;
            int c0 = mt*16 + lk*4;
            if (c0 >= 100) continue;   // cols >= 100 never read
            __bf16 o4[4];
#pragma unroll
            for (int rr = 0; rr < 4; rr++) o4[rr] = (__bf16)acc[mt][nt][rr];
            *(uint2*)&Pl[op*CP + c0] = *(uint2*)o4;
        }
    }
    __syncthreads();

    // shift-add: thread (o = tid&31, tg16 = tid>>5): 6 t's each
    {
        int o = tid & 31, tg16 = tid >> 5;
        float cb = conv_b[o];
#pragma unroll
        for (int j = 0; j < 6; j++) {
            int t = tg16*6 + j;
            if (t >= CLEN) continue;
            float s = cb;
#pragma unroll
            for (int k = 0; k < 8; k++)
                s += (float)Pl[(k*32 + o)*CP + t + k];
            cbuf[(size_t)b*2976 + o*CLEN + t] = (__bf16)s;
        }
    }
}

// ---------------------------------------------------------------------------
// mlp3: out[r] = dot(o2bf[r,0:512], w) + b   (wave per row)
// ---------------------------------------------------------------------------
__global__ __launch_bounds__(256)
void mlp3_dot(const __bf16* __restrict__ o2, const float* __restrict__ w,
              const float* __restrict__ bias, float* __restrict__ out)
{
    int row = blockIdx.x*4 + (threadIdx.x >> 6);
    int lane = threadIdx.x & 63;
    bf16x8 v = *(const bf16x8*)(o2 + (size_t)row*512 + lane*8);
    float4 w0 = *(const float4*)(w + lane*8);
    float4 w1 = *(const float4*)(w + lane*8 + 4);
    float s = (float)v[0]*w0.x + (float)v[1]*w0.y + (float)v[2]*w0.z + (float)v[3]*w0.w
            + (float)v[4]*w1.x + (float)v[5]*w1.y + (float)v[6]*w1.z + (float)v[7]*w1.w;
#pragma unroll
    for (int off = 32; off > 0; off >>= 1) s += __shfl_down(s, off);
    if (lane == 0) out[row] = s + bias[0];
}

// ---------------------------------------------------------------------------
extern "C" void kernel_launch(void* const* d_in, const int* in_sizes, int n_in,
                              void* d_out, int out_size, void* d_ws, size_t ws_size,
                              hipStream_t stream)
{
    const float* x      = (const float*)d_in[0];
    const int*   ei     = (const int*)  d_in[1];
    const int*   batch  = (const int*)  d_in[2];
    const int*   target = (const int*)  d_in[3];
    const float* gat_w  = (const float*)d_in[4];
    const float* att_s  = (const float*)d_in[5];
    const float* att_d  = (const float*)d_in[6];
    const float* gat_b  = (const float*)d_in[7];
    const float* gcn_w  = (const float*)d_in[8];
    const float* gcn_b  = (const float*)d_in[9];
    const float* fcg1_w = (const float*)d_in[10];
    const float* fcg1_b = (const float*)d_in[11];
    const float* fcg2_w = (const float*)d_in[12];
    const float* fcg2_b = (const float*)d_in[13];
    const float* emb_w  = (const float*)d_in[14];
    const float* conv_w = (const float*)d_in[15];
    const float* conv_b = (const float*)d_in[16];
    const float* fcxt_w = (const float*)d_in[17];
    const float* fcxt_b = (const float*)d_in[18];
    const float* mlp1_w = (const float*)d_in[19];
    const float* mlp1_b = (const float*)d_in[20];
    const float* mlp2_w = (const float*)d_in[21];
    const float* mlp2_b = (const float*)d_in[22];
    const float* mlp3_w = (const float*)d_in[23];
    const float* mlp3_b = (const float*)d_in[24];
    float* out = (float*)d_out;

    char* ws = (char*)d_ws;
    size_t off = 0;
    auto alloc = [&](size_t bytes) -> char* {
        char* p = ws + off;
        off = (off + bytes + 255) & ~(size_t)255;
        return p;
    };
    __bf16* xhbf  = (__bf16*)alloc((size_t)NN*800*2);  // xh bf16, reused as hw bf16
    __bf16* g     = (__bf16*)alloc((size_t)NN*HD*2);
    char*  hbf_rg = alloc((size_t)NN*800*2);           // Abf -> hbf -> splitk partial
    __bf16* Abf   = (__bf16*)hbf_rg;
    __bf16* hbf   = (__bf16*)hbf_rg;
    float* partial= (float*)hbf_rg;                    // after hbf dead
    __bf16* wgat  = (__bf16*)alloc((size_t)896*96*2);
    __bf16* wgcn  = (__bf16*)alloc((size_t)896*800*2);
    __bf16* wg1   = (__bf16*)alloc((size_t)1536*1568*2);
    __bf16* wg2   = (__bf16*)alloc((size_t)128*1504*2);
    __bf16* wxt   = (__bf16*)alloc((size_t)128*2976*2);
    __bf16* wm1   = (__bf16*)alloc((size_t)1024*256*2);
    __bf16* wm2   = (__bf16*)alloc((size_t)512*1024*2);
    __bf16* convw2= (__bf16*)alloc((size_t)256*1024*2);
    __bf16* embbf = (__bf16*)alloc((size_t)8001*112*2);
    float* a_src  = (float*)alloc((size_t)NN*NH*4);
    float* a_dst  = (float*)alloc((size_t)NN*NH*4);
    int*   deg    = (int*)alloc((size_t)NN*4);
    int*   offs   = (int*)alloc((size_t)(NN+1)*4);
    int*   cursor = (int*)alloc((size_t)NN*4);
    int*   csr    = (int*)alloc((size_t)NT*4);
    float* dinv   = (float*)alloc((size_t)NN*4);
    int*   goffs  = (int*)alloc((size_t)(NG+1)*4);
    __bf16* dpool = (__bf16*)alloc((size_t)NG*1568*2);
    __bf16* d1bf  = (__bf16*)alloc((size_t)NG*1504*2);
    __bf16* cbuf  = (__bf16*)alloc((size_t)NG*NF*CLEN*2);
    __bf16* obuf  = (__bf16*)alloc((size_t)NG*256*2);
    __bf16* o1bf  = (__bf16*)alloc((size_t)NG*1024*2);
    __bf16* o2bf  = (__bf16*)alloc((size_t)NG*512*2);

    __bf16* hwbf = xhbf;   // xh dead after gat_agg

    hipMemsetAsync(deg, 0, (size_t)NN*4, stream);

    // --- ALL input-only transforms in one launch ---
    preproc_all<<<dim3((unsigned)PRE_BLOCKS), 256, 0, stream>>>(
        emb_w, embbf, conv_w, convw2, fcg1_w, wg1, fcg2_w, wg2, fcxt_w, wxt,
        mlp1_w, wm1, mlp2_w, wm2, x, Abf, gat_w, wgat, gcn_w, wgcn, batch, goffs);

    // --- protein conv (independent of graph branch; run early) ---
    conv_gemm2<<<dim3(NG), 512, 0, stream>>>(target, embbf, convw2, conv_b, cbuf);

    // --- GAT linear: xh = x @ gat_w (Kp=96), bf16 out stride 800 ---
    gemm_mfma<false,false,true>
        <<<dim3(7, NN/128), 256, 0, stream>>>(Abf, wgat, nullptr, xhbf, NN, HD, 96, 800, 800);
    attn_logits<<<dim3((NN*NH+255)/256), 256, 0, stream>>>(xhbf, att_s, att_d, a_src, a_dst);

    // --- CSR (dinv folded into scan) ---
    edge_count  <<<dim3(NT/256), 256, 0, stream>>>(ei, deg);
    scan_kernel <<<1, 1024, 0, stream>>>(deg, offs, cursor, dinv);
    edge_scatter<<<dim3(NT/256), 256, 0, stream>>>(ei, cursor, csr);

    // --- GAT aggregate -> hbf (overwrites Abf; Abf dead) ---
    gat_agg<<<dim3(NN/4), 256, 0, stream>>>(xhbf, a_src, a_dst, gat_b, offs, csr, hbf);

    // --- GCN linear (bf16 out) + aggregate (bf16 g) ---
    gemm_mfma<false,false,true>
        <<<dim3(7, NN/128), 256, 0, stream>>>(hbf, wgcn, nullptr, hwbf, NN, HD, 800, 800, 800);
    gcn_agg<<<dim3(NN/4), 256, 0, stream>>>(hwbf, dinv, gcn_b, offs, csr, g);

    // --- pooling (goffs from preproc) ---
    pool_kernel<<<NG, 256, 0, stream>>>(g, goffs, dpool);

    // --- FC stack via split-K (partial aliases hbf; dead after gcn gemm) ---
    gemm_mfma_splitk<<<dim3(12, 4, 4), 256, 0, stream>>>(dpool, wg1, partial, NG, 1568, 1536, 13);
    reduce_splitk<true><<<dim3((NG*(1504/4)+255)/256), 256, 0, stream>>>(partial, fcg1_b, d1bf, NG, 1500, 1536, 4, 1504, 1504);
    gemm_mfma_splitk<<<dim3(1, 4, 12), 256, 0, stream>>>(d1bf, wg2, partial, NG, 1504, 128, 4);
    reduce_splitk<false><<<dim3((NG*32+255)/256), 256, 0, stream>>>(partial, fcg2_b, obuf, NG, 128, 128, 12, 256, 128);
    gemm_mfma_splitk<<<dim3(1, 4, 24), 256, 0, stream>>>(cbuf, wxt, partial, NG, 2976, 128, 4);
    reduce_splitk<false><<<dim3((NG*32+255)/256), 256, 0, stream>>>(partial, fcxt_b, obuf + 128, NG, 128, 128, 24, 256, 128);
    gemm_mfma_splitk<<<dim3(8, 4, 2), 256, 0, stream>>>(obuf, wm1, partial, NG, 256, 1024, 4);
    reduce_splitk<true><<<dim3((NG*256+255)/256), 256, 0, stream>>>(partial, mlp1_b, o1bf, NG, 1024, 1024, 2, 1024, 1024);
    gemm_mfma_splitk<<<dim3(4, 4, 8), 256, 0, stream>>>(o1bf, wm2, partial, NG, 1024, 512, 4);
    reduce_splitk<true><<<dim3((NG*128+255)/256), 256, 0, stream>>>(partial, mlp2_b, o2bf, NG, 512, 512, 8, 512, 512);

    mlp3_dot<<<dim3(NG/4), 256, 0, stream>>>(o2bf, mlp3_w, mlp3_b, out);
}

// Round 9
// 371.788 us; speedup vs baseline: 7.3170x; 1.0279x over previous
//
#include <hip/hip_runtime.h>

#define NN 16384      // nodes
#define NE 65536      // edges
#define NT 81920      // edges + self loops
#define NG 512        // graphs
#define NH 10         // heads
#define FX 78         // features per head
#define HD 780        // hidden = NH*FX
#define SEQ 1000
#define EMB 100
#define NF 32
#define KS 8
#define CLEN 93

typedef __bf16 bf16x8 __attribute__((ext_vector_type(8)));
typedef float  f32x4  __attribute__((ext_vector_type(4)));

// ---------------------------------------------------------------------------
// One mega-kernel for ALL input-only transforms (casts/repacks/gstart).
// ---------------------------------------------------------------------------
__device__ inline void bt_one(const float* __restrict__ B, __bf16* __restrict__ out,
                              long idx, int K, int N, int Kp)
{
    int n = idx / Kp, k = idx - (long)(idx / Kp)*Kp;
    out[idx] = (n < N && k < K) ? (__bf16)B[(size_t)k*N + n] : (__bf16)0.f;
}

__global__ __launch_bounds__(256)
void preproc_all(const float* __restrict__ emb_w, __bf16* __restrict__ embbf,
                 const float* __restrict__ conv_w, __bf16* __restrict__ w2,
                 const float* __restrict__ fcg1_w, __bf16* __restrict__ wg1,
                 const float* __restrict__ fcg2_w, __bf16* __restrict__ wg2,
                 const float* __restrict__ fcxt_w, __bf16* __restrict__ wxt,
                 const float* __restrict__ mlp1_w, __bf16* __restrict__ wm1,
                 const float* __restrict__ mlp2_w, __bf16* __restrict__ wm2,
                 const float* __restrict__ x, __bf16* __restrict__ Abf,
                 const float* __restrict__ gat_w, __bf16* __restrict__ wgat,
                 const float* __restrict__ gcn_w, __bf16* __restrict__ wgcn,
                 const int* __restrict__ batch, int* __restrict__ goffs)
{
    long idx = (long)blockIdx.x*256 + threadIdx.x;
    if (idx < 896112L) {
        int r = idx / 112, c = idx - (long)(idx/112)*112;
        embbf[idx] = (__bf16)((r < 8000 && c < EMB) ? emb_w[(size_t)r*EMB + c] : 0.f);
        return;
    }
    idx -= 896112L;
    if (idx < 262144L) {
        int op = idx >> 10, i = idx & 1023;
        int o = op & 31, k = op >> 5;
        w2[idx] = (i < SEQ) ? (__bf16)conv_w[((size_t)o*SEQ + i)*KS + k] : (__bf16)0.f;
        return;
    }
    idx -= 262144L;
    if (idx < 2408448L) { bt_one(fcg1_w, wg1, idx, 1560, 1500, 1568); return; }
    idx -= 2408448L;
    if (idx < 192512L)  { bt_one(fcg2_w, wg2, idx, 1500, 128, 1504); return; }
    idx -= 192512L;
    if (idx < 380928L)  { bt_one(fcxt_w, wxt, idx, 2976, 128, 2976); return; }
    idx -= 380928L;
    if (idx < 262144L)  { bt_one(mlp1_w, wm1, idx, 256, 1024, 256); return; }
    idx -= 262144L;
    if (idx < 524288L)  { bt_one(mlp2_w, wm2, idx, 1024, 512, 1024); return; }
    idx -= 524288L;
    if (idx < 1572864L) {
        int r = idx / 96, c = idx - (long)(idx/96)*96;
        Abf[idx] = (c < FX) ? (__bf16)x[(size_t)r*FX + c] : (__bf16)0.f;
        return;
    }
    idx -= 1572864L;
    if (idx < 86016L)   { bt_one(gat_w, wgat, idx, 78, 780, 96); return; }
    idx -= 86016L;
    if (idx < 716800L)  { bt_one(gcn_w, wgcn, idx, 780, 780, 800); return; }
    idx -= 716800L;
    if (idx <= NG) {
        int b = (int)idx;
        if (b == NG) { goffs[NG] = NN; return; }
        int lo = 0, hi = NN;
        while (lo < hi) { int mid = (lo+hi) >> 1; if (batch[mid] < b) lo = mid+1; else hi = mid; }
        goffs[b] = lo;
    }
}
#define PRE_TOTAL 7302256L
#define PRE_BLOCKS ((PRE_TOTAL + 513 + 255) / 256)

// ---------------------------------------------------------------------------
// bf16 MFMA GEMM (full-K): C[M,ldc] = A[M,Kp] @ Bt[Np,Kp]^T
// XCD-aware block swizzle: all column-blocks of one A-row-panel land on the
// SAME XCD so the A panel is fetched to one L2 only (requires nwg % 8 == 0).
// ---------------------------------------------------------------------------
#define BKP 40
template<bool BIAS, bool RELU, bool BF16OUT>
__global__ __launch_bounds__(256)
void gemm_mfma(const __bf16* __restrict__ A, const __bf16* __restrict__ Bt,
               const float* __restrict__ bias, void* __restrict__ Cv,
               int M, int N, int Kp, int ldc, int Nz)
{
    __shared__ __align__(16) __bf16 As[128*BKP];
    __shared__ __align__(16) __bf16 Bs[128*BKP];
    const int tid = threadIdx.x;
    // bijective XCD swizzle (nwg = gridDim.x*gridDim.y, divisible by 8)
    const int nbx = gridDim.x;
    const int lin = blockIdx.y * nbx + blockIdx.x;
    const int per = (nbx * gridDim.y) >> 3;
    const int logical = (lin & 7) * per + (lin >> 3);
    const int row0 = (logical / nbx) * 128, col0 = (logical % nbx) * 128;
    const int lane = tid & 63, wid = tid >> 6;
    const int wm = wid & 1, wn = wid >> 1;
    const int l15 = lane & 15, lk = lane >> 4;

    f32x4 acc[4][4];
#pragma unroll
    for (int i = 0; i < 4; i++)
#pragma unroll
        for (int j = 0; j < 4; j++) acc[i][j] = (f32x4){0.f,0.f,0.f,0.f};

    for (int k0 = 0; k0 < Kp; k0 += 32) {
        __syncthreads();
#pragma unroll
        for (int it = 0; it < 2; ++it) {
            int c = tid + it*256;
            int r = c >> 2, c16 = c & 3;
            uint4 va = *(const uint4*)(A  + (size_t)(row0+r)*Kp + k0 + c16*8);
            *(uint4*)&As[r*BKP + c16*8] = va;
            uint4 vb = *(const uint4*)(Bt + (size_t)(col0+r)*Kp + k0 + c16*8);
            *(uint4*)&Bs[r*BKP + c16*8] = vb;
        }
        __syncthreads();
        bf16x8 af[4], bfr[4];
#pragma unroll
        for (int i = 0; i < 4; i++) {
            af[i]  = *(const bf16x8*)&As[(wm*64 + i*16 + l15)*BKP + lk*8];
            bfr[i] = *(const bf16x8*)&Bs[(wn*64 + i*16 + l15)*BKP + lk*8];
        }
#pragma unroll
        for (int i = 0; i < 4; i++)
#pragma unroll
            for (int j = 0; j < 4; j++)
                acc[i][j] = __builtin_amdgcn_mfma_f32_16x16x32_bf16(af[i], bfr[j], acc[i][j], 0, 0, 0);
    }

#pragma unroll
    for (int i = 0; i < 4; i++) {
        int rbase = row0 + wm*64 + i*16 + lk*4;
#pragma unroll
        for (int j = 0; j < 4; j++) {
            int cc = col0 + wn*64 + j*16 + l15;
            if (cc >= Nz) continue;
            bool real = cc < N;
            float bv = (BIAS && real) ? bias[cc] : 0.f;
#pragma unroll
            for (int r = 0; r < 4; r++) {
                float v = real ? (acc[i][j][r] + bv) : 0.f;
                if (RELU) v = v > 0.f ? v : 0.f;
                if (BF16OUT) ((__bf16*)Cv)[(size_t)(rbase + r)*ldc + cc] = (__bf16)v;
                else         ((float*) Cv)[(size_t)(rbase + r)*ldc + cc] = v;
            }
        }
    }
}

// ---------------------------------------------------------------------------
// Split-K MFMA GEMM: partial[s][M][ldp] f32.
// ---------------------------------------------------------------------------
__global__ __launch_bounds__(256)
void gemm_mfma_splitk(const __bf16* __restrict__ A, const __bf16* __restrict__ Bt,
                      float* __restrict__ part, int M, int Kp, int ldp, int ksteps)
{
    __shared__ __align__(16) __bf16 As[128*BKP];
    __shared__ __align__(16) __bf16 Bs[128*BKP];
    const int tid = threadIdx.x;
    const int row0 = blockIdx.y*128, col0 = blockIdx.x*128;
    const int s = blockIdx.z;
    const int lane = tid & 63, wid = tid >> 6;
    const int wm = wid & 1, wn = wid >> 1;
    const int l15 = lane & 15, lk = lane >> 4;

    const int T = Kp >> 5;
    int kb = s*ksteps, ke = kb + ksteps;
    if (ke > T) ke = T;

    f32x4 acc[4][4];
#pragma unroll
    for (int i = 0; i < 4; i++)
#pragma unroll
        for (int j = 0; j < 4; j++) acc[i][j] = (f32x4){0.f,0.f,0.f,0.f};

    for (int kk = kb; kk < ke; kk++) {
        int k0 = kk*32;
        __syncthreads();
#pragma unroll
        for (int it = 0; it < 2; ++it) {
            int c = tid + it*256;
            int r = c >> 2, c16 = c & 3;
            uint4 va = *(const uint4*)(A  + (size_t)(row0+r)*Kp + k0 + c16*8);
            *(uint4*)&As[r*BKP + c16*8] = va;
            uint4 vb = *(const uint4*)(Bt + (size_t)(col0+r)*Kp + k0 + c16*8);
            *(uint4*)&Bs[r*BKP + c16*8] = vb;
        }
        __syncthreads();
        bf16x8 af[4], bfr[4];
#pragma unroll
        for (int i = 0; i < 4; i++) {
            af[i]  = *(const bf16x8*)&As[(wm*64 + i*16 + l15)*BKP + lk*8];
            bfr[i] = *(const bf16x8*)&Bs[(wn*64 + i*16 + l15)*BKP + lk*8];
        }
#pragma unroll
        for (int i = 0; i < 4; i++)
#pragma unroll
            for (int j = 0; j < 4; j++)
                acc[i][j] = __builtin_amdgcn_mfma_f32_16x16x32_bf16(af[i], bfr[j], acc[i][j], 0, 0, 0);
    }

#pragma unroll
    for (int i = 0; i < 4; i++) {
        int rbase = row0 + wm*64 + i*16 + lk*4;
#pragma unroll
        for (int j = 0; j < 4; j++) {
            int cc = col0 + wn*64 + j*16 + l15;
#pragma unroll
            for (int r = 0; r < 4; r++)
                part[((size_t)s*M + rbase + r)*ldp + cc] = acc[i][j][r];
        }
    }
}

// reduce S partials + bias (+relu) -> bf16 C (cols [N,Nz) zeroed)
template<bool RELU>
__global__ __launch_bounds__(256)
void reduce_splitk(const float* __restrict__ part, const float* __restrict__ bias,
                   __bf16* __restrict__ C, int M, int N, int ldp, int S,
                   int ldc, int Nz)
{
    int idx = blockIdx.x*256 + threadIdx.x;
    int nc4 = Nz >> 2;
    if (idx >= M*nc4) return;
    int r = idx / nc4, c = (idx - r*nc4)*4;
    float4 a = {0.f,0.f,0.f,0.f};
    for (int s = 0; s < S; s++) {
        float4 v = *(const float4*)(part + ((size_t)s*M + r)*ldp + c);
        a.x += v.x; a.y += v.y; a.z += v.z; a.w += v.w;
    }
    float vv[4] = {a.x, a.y, a.z, a.w};
    __bf16 o4[4];
#pragma unroll
    for (int j = 0; j < 4; j++) {
        float v = 0.f;
        if (c + j < N) {
            v = vv[j] + bias[c+j];
            if (RELU) v = v > 0.f ? v : 0.f;
        }
        o4[j] = (__bf16)v;
    }
    *(uint2*)&C[(size_t)r*ldc + c] = *(uint2*)o4;
}

// ---------------------------------------------------------------------------
// a_src[n,h], a_dst[n,h] from bf16 xh (stride 800)
// ---------------------------------------------------------------------------
__global__ __launch_bounds__(256)
void attn_logits(const __bf16* __restrict__ xh, const float* __restrict__ att_s,
                 const float* __restrict__ att_d,
                 float* __restrict__ a_src, float* __restrict__ a_dst)
{
    int idx = blockIdx.x*256 + threadIdx.x;
    if (idx >= NN*NH) return;
    int n = idx / NH, h = idx % NH;
    const __bf16* xr = xh + (size_t)n*800 + h*FX;
    const float* as = att_s + h*FX;
    const float* ad = att_d + h*FX;
    float s1 = 0.f, s2 = 0.f;
    for (int c = 0; c < FX; c++) {
        float v = (float)xr[c];
        s1 = fmaf(v, as[c], s1);
        s2 = fmaf(v, ad[c], s2);
    }
    a_src[idx] = s1;
    a_dst[idx] = s2;
}

// ---------------------------------------------------------------------------
// CSR build
// ---------------------------------------------------------------------------
__global__ void edge_count(const int* __restrict__ ei, int* __restrict__ deg)
{
    int e = blockIdx.x*256 + threadIdx.x;
    if (e >= NT) return;
    int dst = (e < NE) ? ei[NE + e] : (e - NE);
    atomicAdd(&deg[dst], 1);
}

__global__ __launch_bounds__(1024)
void scan_kernel(const int* __restrict__ deg, int* __restrict__ offs,
                 int* __restrict__ cursor, float* __restrict__ dinv)
{
    __shared__ int part[1024];
    int tid = threadIdx.x;
    int base = tid*16;
    int v[16]; int ssum = 0;
#pragma unroll
    for (int j = 0; j < 16; j++) {
        v[j] = deg[base+j];
        dinv[base+j] = rsqrtf((float)(v[j] > 0 ? v[j] : 1));
        ssum += v[j];
    }
    part[tid] = ssum;
    __syncthreads();
    for (int d = 1; d < 1024; d <<= 1) {
        int t = (tid >= d) ? part[tid-d] : 0;
        __syncthreads();
        part[tid] += t;
        __syncthreads();
    }
    int run = (tid == 0) ? 0 : part[tid-1];
#pragma unroll
    for (int j = 0; j < 16; j++) { offs[base+j] = run; cursor[base+j] = run; run += v[j]; }
    if (tid == 1023) offs[NN] = run;
}

__global__ void edge_scatter(const int* __restrict__ ei, int* __restrict__ cursor,
                             int* __restrict__ csr)
{
    int e = blockIdx.x*256 + threadIdx.x;
    if (e >= NT) return;
    int src, dst;
    if (e < NE) { src = ei[e]; dst = ei[NE + e]; }
    else        { src = e - NE; dst = e - NE; }
    int pos = atomicAdd(&cursor[dst], 1);
    csr[pos] = src;
}

// ---------------------------------------------------------------------------
// GAT aggregation: bf16 xh gather -> bf16 h (stride 800, cols 780..799 zero)
// ---------------------------------------------------------------------------
__global__ __launch_bounds__(256)
void gat_agg(const __bf16* __restrict__ xh, const float* __restrict__ a_src,
             const float* __restrict__ a_dst, const float* __restrict__ gat_b,
             const int* __restrict__ offs, const int* __restrict__ csr,
             __bf16* __restrict__ hbf)
{
    int n = blockIdx.x*4 + (threadIdx.x >> 6);
    if (n >= NN) return;
    int lane = threadIdx.x & 63;
    bool act = lane < 60;
    int h   = act ? (lane / 6) : 0;
    int sub = act ? (lane % 6) : 0;
    int cbase = h*FX + sub*13;
    int off = offs[n], end = offs[n+1];
    float adn = a_dst[n*NH + h];

    float m = -3.0e38f;
    for (int i = off; i < end; i++) {
        int s = csr[i];
        float ev = a_src[s*NH + h] + adn;
        ev = ev > 0.f ? ev : 0.2f*ev;
        m = fmaxf(m, ev);
    }
    float den = 0.f;
    float acc[13];
#pragma unroll
    for (int j = 0; j < 13; j++) acc[j] = 0.f;
    for (int i = off; i < end; i++) {
        int s = csr[i];
        float ev = a_src[s*NH + h] + adn;
        ev = ev > 0.f ? ev : 0.2f*ev;
        float ee = __expf(ev - m);
        den += ee;
        const __bf16* xr = xh + (size_t)s*800 + cbase;
#pragma unroll
        for (int j = 0; j < 13; j++) acc[j] = fmaf((float)xr[j], ee, acc[j]);
    }
    if (act) {
        float inv = 1.f / den;
        const float* bb = gat_b + cbase;
        __bf16* op = hbf + (size_t)n*800 + cbase;
#pragma unroll
        for (int j = 0; j < 13; j++) {
            float v = fmaf(acc[j], inv, bb[j]);
            op[j] = (__bf16)(v > 0.f ? v : 0.f);
        }
    } else {
        __bf16* op = hbf + (size_t)n*800 + 780 + (lane - 60)*5;
#pragma unroll
        for (int j = 0; j < 5; j++) op[j] = (__bf16)0.f;
    }
}

// ---------------------------------------------------------------------------
// GCN aggregation: bf16 hw gather -> bf16 g (stride 780)
// ---------------------------------------------------------------------------
__global__ __launch_bounds__(256)
void gcn_agg(const __bf16* __restrict__ hw, const float* __restrict__ dinv,
             const float* __restrict__ gcn_b, const int* __restrict__ offs,
             const int* __restrict__ csr, __bf16* __restrict__ g)
{
    int n = blockIdx.x*4 + (threadIdx.x >> 6);
    if (n >= NN) return;
    int lane = threadIdx.x & 63;
    int off = offs[n], end = offs[n+1];
    float dn = dinv[n];
    float acc[13];
#pragma unroll
    for (int j = 0; j < 13; j++) acc[j] = 0.f;
    for (int i = off; i < end; i++) {
        int s = csr[i];
        float w = dinv[s] * dn;
        const __bf16* r = hw + (size_t)s*800;
#pragma unroll
        for (int j = 0; j < 13; j++) {
            int c = lane + 64*j;
            if (c < HD) acc[j] = fmaf((float)r[c], w, acc[j]);
        }
    }
    __bf16* op = g + (size_t)n*HD;
#pragma unroll
    for (int j = 0; j < 13; j++) {
        int c = lane + 64*j;
        if (c < HD) {
            float v = acc[j] + gcn_b[c];
            op[c] = (__bf16)(v > 0.f ? v : 0.f);
        }
    }
}

// pool (bf16 g) -> bf16 d[b][1568]: [0:780)=max, [780:1560)=mean, pad 0
__global__ __launch_bounds__(256)
void pool_kernel(const __bf16* __restrict__ g, const int* __restrict__ goffs,
                 __bf16* __restrict__ d)
{
    int b = blockIdx.x;
    int tid = threadIdx.x;
    int s = goffs[b], e = goffs[b+1];
    float mx[4], sm[4];
#pragma unroll
    for (int j = 0; j < 4; j++) { mx[j] = -3.0e38f; sm[j] = 0.f; }
    for (int n = s; n < e; n++) {
        const __bf16* r = g + (size_t)n*HD;
#pragma unroll
        for (int j = 0; j < 4; j++) {
            int c = tid + 256*j;
            if (c < HD) { float v = (float)r[c]; mx[j] = fmaxf(mx[j], v); sm[j] += v; }
        }
    }
    int cnt = e - s;
    float inv = 1.f / (float)(cnt > 0 ? cnt : 1);
#pragma unroll
    for (int j = 0; j < 4; j++) {
        int c = tid + 256*j;
        if (c < HD) {
            d[(size_t)b*1568 + c]      = (__bf16)mx[j];
            d[(size_t)b*1568 + HD + c] = (__bf16)(sm[j] * inv);
        }
    }
    if (tid < 8) d[(size_t)b*1568 + 1560 + tid] = (__bf16)0.f;
}

// ---------------------------------------------------------------------------
// Protein conv, fully fused per graph (vectorized staging, v2).
// ---------------------------------------------------------------------------
#define CP 104          // P lds col stride (cols 0..99 used)
#define SB (112*40)     // one staging buffer, elements

__global__ __launch_bounds__(512)
void conv_gemm2(const int* __restrict__ target, const __bf16* __restrict__ embbf,
                const __bf16* __restrict__ w2, const float* __restrict__ conv_b,
                __bf16* __restrict__ cbuf)
{
    __shared__ __align__(16) __bf16 Pl[256*CP];   // 53.2 KB total
    __bf16* Bs = Pl;                              // staging: elems [0, 8960)
    int* tg = (int*)&Pl[2*SB];                    // 1024 ints: elems [8960,11008)
    const int b = blockIdx.x;
    const int tid = threadIdx.x;
    const int w = tid >> 6, lane = tid & 63;
    const int l15 = lane & 15, lk = lane >> 4;

    for (int i = tid; i < 1024; i += 512)
        tg[i] = ((i < SEQ) ? target[b*SEQ + i] : 8000) * 112;
    __syncthreads();

    const bool st = tid < 448;
    const int sr  = tid & 31;    // k-row within 32-tile
    const int sch = tid >> 5;    // col chunk 0..13 (8 cols each)

    uint4 sv;
    auto stage_load = [&](int p) {
        if (!st) return;
        sv = *(const uint4*)((const ushort*)embbf + tg[p*32 + sr] + sch*8);
    };
    auto stage_write = [&](int buf) {
        if (!st) return;
        const __bf16* s8 = (const __bf16*)&sv;
        __bf16* base = &Bs[buf*SB + (sch*8)*40 + sr];
#pragma unroll
        for (int j = 0; j < 8; j++) base[j*40] = s8[j];
    };

    f32x4 acc[7][2];
#pragma unroll
    for (int i = 0; i < 7; i++) {
        acc[i][0] = (f32x4){0.f,0.f,0.f,0.f};
        acc[i][1] = (f32x4){0.f,0.f,0.f,0.f};
    }

    const __bf16* w2w0 = w2 + (size_t)(w*32 + l15)*1024 + lk*8;
    const __bf16* w2w1 = w2w0 + (size_t)16*1024;

    stage_load(0);
    stage_write(0);
    int cur = 0;
    for (int p = 0; p < 32; ++p) {
        __syncthreads();
        if (p+1 < 32) stage_load(p+1);
        bf16x8 bf0 = *(const bf16x8*)(w2w0 + p*32);
        bf16x8 bf1 = *(const bf16x8*)(w2w1 + p*32);
        const __bf16* bsc = Bs + cur*SB + lk*8;
        __builtin_amdgcn_s_setprio(1);
#pragma unroll
        for (int mt = 0; mt < 7; mt++) {
            bf16x8 af = *(const bf16x8*)(bsc + (mt*16 + l15)*40);
            acc[mt][0] = __builtin_amdgcn_mfma_f32_16x16x32_bf16(af, bf0, acc[mt][0], 0, 0, 0);
            acc[mt][1] = __builtin_amdgcn_mfma_f32_16x16x32_bf16(af, bf1, acc[mt][1], 0, 0, 0);
        }
        __builtin_amdgcn_s_setprio(0);
        if (p+1 < 32) stage_write(cur^1);
        cur ^= 1;
    }

    __syncthreads();   // staging + tg dead; write P over it
#pragma unroll
    for (int mt = 0; mt < 7; mt++) {
#pragma unroll
        for (int nt = 0; nt < 2; nt++) {
            int op = w*32 + nt*16 + l15;
            int c0 = mt*16 + lk*4;
            if (c0 >= 100) continue;   // cols >= 100 never read
            __bf16 o4[4];
#pragma unroll
            for (int rr = 0; rr < 4; rr++) o4[rr] = (__bf16)acc[mt][nt][rr];
            *(uint2*)&Pl[op*CP + c0] = *(uint2*)o4;
        }
    }
    __syncthreads();

    // shift-add: thread (o = tid&31, tg16 = tid>>5): 6 t's each
    {
        int o = tid & 31, tg16 = tid >> 5;
        float cb = conv_b[o];
#pragma unroll
        for (int j = 0; j < 6; j++) {
            int t = tg16*6 + j;
            if (t >= CLEN) continue;
            float s = cb;
#pragma unroll
            for (int k = 0; k < 8; k++)
                s += (float)Pl[(k*32 + o)*CP + t + k];
            cbuf[(size_t)b*2976 + o*CLEN + t] = (__bf16)s;
        }
    }
}

// ---------------------------------------------------------------------------
// mlp3: out[r] = dot(o2bf[r,0:512], w) + b   (wave per row)
// ---------------------------------------------------------------------------
__global__ __launch_bounds__(256)
void mlp3_dot(const __bf16* __restrict__ o2, const float* __restrict__ w,
              const float* __restrict__ bias, float* __restrict__ out)
{
    int row = blockIdx.x*4 + (threadIdx.x >> 6);
    int lane = threadIdx.x & 63;
    bf16x8 v = *(const bf16x8*)(o2 + (size_t)row*512 + lane*8);
    float4 w0 = *(const float4*)(w + lane*8);
    float4 w1 = *(const float4*)(w + lane*8 + 4);
    float s = (float)v[0]*w0.x + (float)v[1]*w0.y + (float)v[2]*w0.z + (float)v[3]*w0.w
            + (float)v[4]*w1.x + (float)v[5]*w1.y + (float)v[6]*w1.z + (float)v[7]*w1.w;
#pragma unroll
    for (int off = 32; off > 0; off >>= 1) s += __shfl_down(s, off);
    if (lane == 0) out[row] = s + bias[0];
}

// ---------------------------------------------------------------------------
extern "C" void kernel_launch(void* const* d_in, const int* in_sizes, int n_in,
                              void* d_out, int out_size, void* d_ws, size_t ws_size,
                              hipStream_t stream)
{
    const float* x      = (const float*)d_in[0];
    const int*   ei     = (const int*)  d_in[1];
    const int*   batch  = (const int*)  d_in[2];
    const int*   target = (const int*)  d_in[3];
    const float* gat_w  = (const float*)d_in[4];
    const float* att_s  = (const float*)d_in[5];
    const float* att_d  = (const float*)d_in[6];
    const float* gat_b  = (const float*)d_in[7];
    const float* gcn_w  = (const float*)d_in[8];
    const float* gcn_b  = (const float*)d_in[9];
    const float* fcg1_w = (const float*)d_in[10];
    const float* fcg1_b = (const float*)d_in[11];
    const float* fcg2_w = (const float*)d_in[12];
    const float* fcg2_b = (const float*)d_in[13];
    const float* emb_w  = (const float*)d_in[14];
    const float* conv_w = (const float*)d_in[15];
    const float* conv_b = (const float*)d_in[16];
    const float* fcxt_w = (const float*)d_in[17];
    const float* fcxt_b = (const float*)d_in[18];
    const float* mlp1_w = (const float*)d_in[19];
    const float* mlp1_b = (const float*)d_in[20];
    const float* mlp2_w = (const float*)d_in[21];
    const float* mlp2_b = (const float*)d_in[22];
    const float* mlp3_w = (const float*)d_in[23];
    const float* mlp3_b = (const float*)d_in[24];
    float* out = (float*)d_out;

    char* ws = (char*)d_ws;
    size_t off = 0;
    auto alloc = [&](size_t bytes) -> char* {
        char* p = ws + off;
        off = (off + bytes + 255) & ~(size_t)255;
        return p;
    };
    __bf16* xhbf  = (__bf16*)alloc((size_t)NN*800*2);  // xh bf16, reused as hw bf16
    __bf16* g     = (__bf16*)alloc((size_t)NN*HD*2);
    char*  hbf_rg = alloc((size_t)NN*800*2);           // Abf -> hbf -> splitk partial
    __bf16* Abf   = (__bf16*)hbf_rg;
    __bf16* hbf   = (__bf16*)hbf_rg;
    float* partial= (float*)hbf_rg;                    // after hbf dead
    __bf16* wgat  = (__bf16*)alloc((size_t)896*96*2);
    __bf16* wgcn  = (__bf16*)alloc((size_t)896*800*2);
    __bf16* wg1   = (__bf16*)alloc((size_t)1536*1568*2);
    __bf16* wg2   = (__bf16*)alloc((size_t)128*1504*2);
    __bf16* wxt   = (__bf16*)alloc((size_t)128*2976*2);
    __bf16* wm1   = (__bf16*)alloc((size_t)1024*256*2);
    __bf16* wm2   = (__bf16*)alloc((size_t)512*1024*2);
    __bf16* convw2= (__bf16*)alloc((size_t)256*1024*2);
    __bf16* embbf = (__bf16*)alloc((size_t)8001*112*2);
    float* a_src  = (float*)alloc((size_t)NN*NH*4);
    float* a_dst  = (float*)alloc((size_t)NN*NH*4);
    int*   deg    = (int*)alloc((size_t)NN*4);
    int*   offs   = (int*)alloc((size_t)(NN+1)*4);
    int*   cursor = (int*)alloc((size_t)NN*4);
    int*   csr    = (int*)alloc((size_t)NT*4);
    float* dinv   = (float*)alloc((size_t)NN*4);
    int*   goffs  = (int*)alloc((size_t)(NG+1)*4);
    __bf16* dpool = (__bf16*)alloc((size_t)NG*1568*2);
    __bf16* d1bf  = (__bf16*)alloc((size_t)NG*1504*2);
    __bf16* cbuf  = (__bf16*)alloc((size_t)NG*NF*CLEN*2);
    __bf16* obuf  = (__bf16*)alloc((size_t)NG*256*2);
    __bf16* o1bf  = (__bf16*)alloc((size_t)NG*1024*2);
    __bf16* o2bf  = (__bf16*)alloc((size_t)NG*512*2);

    __bf16* hwbf = xhbf;   // xh dead after gat_agg

    hipMemsetAsync(deg, 0, (size_t)NN*4, stream);

    // --- ALL input-only transforms in one launch ---
    preproc_all<<<dim3((unsigned)PRE_BLOCKS), 256, 0, stream>>>(
        emb_w, embbf, conv_w, convw2, fcg1_w, wg1, fcg2_w, wg2, fcxt_w, wxt,
        mlp1_w, wm1, mlp2_w, wm2, x, Abf, gat_w, wgat, gcn_w, wgcn, batch, goffs);

    // --- protein conv (independent of graph branch; run early) ---
    conv_gemm2<<<dim3(NG), 512, 0, stream>>>(target, embbf, convw2, conv_b, cbuf);

    // --- GAT linear: xh = x @ gat_w (Kp=96), bf16 out stride 800 ---
    gemm_mfma<false,false,true>
        <<<dim3(7, NN/128), 256, 0, stream>>>(Abf, wgat, nullptr, xhbf, NN, HD, 96, 800, 800);
    attn_logits<<<dim3((NN*NH+255)/256), 256, 0, stream>>>(xhbf, att_s, att_d, a_src, a_dst);

    // --- CSR (dinv folded into scan) ---
    edge_count  <<<dim3(NT/256), 256, 0, stream>>>(ei, deg);
    scan_kernel <<<1, 1024, 0, stream>>>(deg, offs, cursor, dinv);
    edge_scatter<<<dim3(NT/256), 256, 0, stream>>>(ei, cursor, csr);

    // --- GAT aggregate -> hbf (overwrites Abf; Abf dead) ---
    gat_agg<<<dim3(NN/4), 256, 0, stream>>>(xhbf, a_src, a_dst, gat_b, offs, csr, hbf);

    // --- GCN linear (bf16 out) + aggregate (bf16 g) ---
    gemm_mfma<false,false,true>
        <<<dim3(7, NN/128), 256, 0, stream>>>(hbf, wgcn, nullptr, hwbf, NN, HD, 800, 800, 800);
    gcn_agg<<<dim3(NN/4), 256, 0, stream>>>(hwbf, dinv, gcn_b, offs, csr, g);

    // --- pooling (goffs from preproc) ---
    pool_kernel<<<NG, 256, 0, stream>>>(g, goffs, dpool);

    // --- FC stack via split-K (partial aliases hbf; dead after gcn gemm) ---
    gemm_mfma_splitk<<<dim3(12, 4, 4), 256, 0, stream>>>(dpool, wg1, partial, NG, 1568, 1536, 13);
    reduce_splitk<true><<<dim3((NG*(1504/4)+255)/256), 256, 0, stream>>>(partial, fcg1_b, d1bf, NG, 1500, 1536, 4, 1504, 1504);
    gemm_mfma_splitk<<<dim3(1, 4, 12), 256, 0, stream>>>(d1bf, wg2, partial, NG, 1504, 128, 4);
    reduce_splitk<false><<<dim3((NG*32+255)/256), 256, 0, stream>>>(partial, fcg2_b, obuf, NG, 128, 128, 12, 256, 128);
    gemm_mfma_splitk<<<dim3(1, 4, 24), 256, 0, stream>>>(cbuf, wxt, partial, NG, 2976, 128, 4);
    reduce_splitk<false><<<dim3((NG*32+255)/256), 256, 0, stream>>>(partial, fcxt_b, obuf + 128, NG, 128, 128, 24, 256, 128);
    gemm_mfma_splitk<<<dim3(8, 4, 2), 256, 0, stream>>>(obuf, wm1, partial, NG, 256, 1024, 4);
    reduce_splitk<true><<<dim3((NG*256+255)/256), 256, 0, stream>>>(partial, mlp1_b, o1bf, NG, 1024, 1024, 2, 1024, 1024);
    gemm_mfma_splitk<<<dim3(4, 4, 8), 256, 0, stream>>>(o1bf, wm2, partial, NG, 1024, 512, 4);
    reduce_splitk<true><<<dim3((NG*128+255)/256), 256, 0, stream>>>(partial, mlp2_b, o2bf, NG, 512, 512, 8, 512, 512);

    mlp3_dot<<<dim3(NG/4), 256, 0, stream>>>(o2bf, mlp3_w, mlp3_b, out);
}